// Round 2
// 659.306 us; speedup vs baseline: 1.1383x; 1.1383x over previous
//
#include <hip/hip_runtime.h>
#include <hip/hip_bf16.h>

// Problem dims (fixed by setup_inputs)
constexpr int kNS = 16384;   // support rows
constexpr int kNQ = 8192;    // query rows
constexpr int kD  = 256;     // feature dim
constexpr int kC  = 64;      // classes

// R16 PASSED (750 us, main kernel 155 us, MfmaUtil 18.5%).
// R17 theory: main kernel is L2-BW bound — all 4 waves load IDENTICAL Sh
// fragments (4 GB through L2 ~= 116 us at 34.5 TB/s). Fix: LDS-stage each
// 32 KB s-chunk once per block via global_load_lds (layout is already
// fragment-major => linear copy), ds_read_b128 from LDS. Newton widened to
// 1024 thr split-k. Epilogue folded to exp2(min(fma,0)).
// R18: R17 bench was an infra failure (container died twice, no counters);
// resubmitting identical kernel + explicit __launch_bounds__(1024) on Newton.

// ---------------- workspace layout (float offsets into d_ws), ~24.4 MB ----
constexpr size_t OFF_PSUM  = 0;
constexpr size_t OFF_PCNT  = 16384;
constexpr size_t OFF_MUSUM = 16448;
constexpr size_t OFF_XTX   = 16704;
constexpr size_t OFF_HIST  = 82240;
constexpr size_t OFF_SSUM  = 84288;
constexpr size_t ZERO_FLOATS = 84352;
constexpr size_t OFF_PROTO = 84352;
constexpr size_t OFF_MU    = 100736;
constexpr size_t OFF_COV   = 100992;
constexpr size_t OFF_ROWS  = 166528;
constexpr size_t OFF_C     = 166784;
constexpr size_t OFF_Y     = 166800;     // Newton X ping
constexpr size_t OFF_T     = 297872;     // Newton T
constexpr size_t OFF_Y2    = 363408;     // Newton X pong
constexpr size_t OFF_S2    = 560016;
constexpr size_t OFF_Q2P   = 576400;
constexpr size_t OFF_PART  = 584592;
constexpr size_t OFF_G     = 846736;     // 8192*256 f32
constexpr size_t OFF_SH    = 2943888;    // 16384*256 bf16 swizzled
constexpr size_t OFF_GH    = 5041040;    // 8192*256 bf16 swizzled

typedef __attribute__((ext_vector_type(8))) short bf16x8;
typedef __attribute__((ext_vector_type(4))) float f32x4;

__device__ __forceinline__ unsigned short f2bf(float f) {
  unsigned int w; __builtin_memcpy(&w, &f, 4);
  unsigned int r = (w + 0x7FFFu + ((w >> 16) & 1u)) >> 16;
  return (unsigned short)r;
}

__device__ __forceinline__ float waveReduceSum(float v) {
#pragma unroll
  for (int off = 32; off > 0; off >>= 1) v += __shfl_xor(v, off);
  return v;
}
__device__ __forceinline__ float waveReduceMax(float v) {
#pragma unroll
  for (int off = 32; off > 0; off >>= 1) v = fmaxf(v, __shfl_xor(v, off));
  return v;
}
__device__ __forceinline__ void fma16(float acc[4][4], float4 a, float4 b) {
  acc[0][0] += a.x*b.x; acc[0][1] += a.x*b.y; acc[0][2] += a.x*b.z; acc[0][3] += a.x*b.w;
  acc[1][0] += a.y*b.x; acc[1][1] += a.y*b.y; acc[1][2] += a.y*b.z; acc[1][3] += a.y*b.w;
  acc[2][0] += a.z*b.x; acc[2][1] += a.z*b.y; acc[2][2] += a.z*b.z; acc[2][3] += a.z*b.w;
  acc[3][0] += a.w*b.x; acc[3][1] += a.w*b.y; acc[3][2] += a.w*b.z; acc[3][3] += a.w*b.w;
}

// async global -> LDS, 16 B per lane
__device__ __forceinline__ void gload_lds16(const void* g, void* l) {
  __builtin_amdgcn_global_load_lds(
      (const __attribute__((address_space(1))) unsigned int*)g,
      (__attribute__((address_space(3))) unsigned int*)l, 16, 0, 0);
}

__global__ void k_zero_r16(float* __restrict__ ws) {
  size_t i = (size_t)blockIdx.x * 256 + threadIdx.x;
  if (i < ZERO_FLOATS) ws[i] = 0.f;
}

// f32 [rows x 256] -> bf16 fragment-major swizzle (one block per 16-row group)
__global__ void k_swz_r16(const float* __restrict__ in, unsigned short* __restrict__ out) {
  int g = blockIdx.x, t = threadIdx.x;
  int ks = t >> 5;
  size_t gbase = (size_t)g * 4096;
#pragma unroll
  for (int f = 0; f < 2; ++f) {
    int lane = (2 * t + f) & 63;
    int q = lane >> 4, r = lane & 15;
    const float* src = &in[(size_t)(g * 16 + r) * kD + ks * 32 + q * 8];
    float4 v0 = *(const float4*)src;
    float4 v1 = *(const float4*)(src + 4);
    ushort4 o0, o1;
    o0.x = f2bf(v0.x); o0.y = f2bf(v0.y); o0.z = f2bf(v0.z); o0.w = f2bf(v0.w);
    o1.x = f2bf(v1.x); o1.y = f2bf(v1.y); o1.z = f2bf(v1.z); o1.w = f2bf(v1.w);
    unsigned short* dst = &out[gbase + (size_t)ks * 512 + (size_t)lane * 8];
    *(ushort4*)dst = o0;
    *(ushort4*)(dst + 4) = o1;
  }
}

// ---------------- classification path ----------------
__global__ void k_proto_accum_r16(const float* __restrict__ X, const int* __restrict__ lab,
                                  float* __restrict__ psum, float* __restrict__ pcnt) {
  int w = threadIdx.x >> 6, lane = threadIdx.x & 63;
  int row = blockIdx.x * 4 + w;
  float4 v = *(const float4*)&X[(size_t)row * kD + lane * 4];
  float ss = waveReduceSum(v.x*v.x + v.y*v.y + v.z*v.z + v.w*v.w);
  float inv = 1.0f / fmaxf(sqrtf(ss), 1e-8f);
  int l = lab[row];
  float* p = psum + (size_t)l * kD + lane * 4;
  atomicAdd(p + 0, v.x * inv); atomicAdd(p + 1, v.y * inv);
  atomicAdd(p + 2, v.z * inv); atomicAdd(p + 3, v.w * inv);
  if (lane == 0) atomicAdd(&pcnt[l], 1.0f);
}

__global__ void k_proto_fin_r16(const float* __restrict__ psum, const float* __restrict__ pcnt,
                                float* __restrict__ protos) {
  int c = blockIdx.x, lane = threadIdx.x;
  float4 v = *(const float4*)&psum[(size_t)c * kD + lane * 4];
  float cnt = fmaxf(pcnt[c], 1.0f);
  v.x /= cnt; v.y /= cnt; v.z /= cnt; v.w /= cnt;
  float ss = waveReduceSum(v.x*v.x + v.y*v.y + v.z*v.z + v.w*v.w);
  float inv = 1.0f / fmaxf(sqrtf(ss), 1e-8f);
  float4 o = {v.x*inv, v.y*inv, v.z*inv, v.w*inv};
  *(float4*)&protos[(size_t)c * kD + lane * 4] = o;
}

__global__ void k_logits_r16(const float* __restrict__ Q, const float* __restrict__ protos,
                             float* __restrict__ out0) {
  __shared__ alignas(16) float qs[kD];
  __shared__ float lg[kC];
  __shared__ float wred[4];
  __shared__ float qis;
  int t = threadIdx.x, w = t >> 6, lane = t & 63;
  int qi = blockIdx.x;
  float myv = Q[(size_t)qi * kD + t];
  qs[t] = myv;
  float ss = waveReduceSum(myv * myv);
  if (lane == 0) wred[w] = ss;
  __syncthreads();
  if (t == 0) qis = 1.0f / fmaxf(sqrtf(wred[0] + wred[1] + wred[2] + wred[3]), 1e-8f);
  __syncthreads();
  float4 qv = *(const float4*)&qs[lane * 4];
  for (int cc = w * 16; cc < w * 16 + 16; ++cc) {
    float4 pv = *(const float4*)&protos[(size_t)cc * kD + lane * 4];
    float d = waveReduceSum(qv.x*pv.x + qv.y*pv.y + qv.z*pv.z + qv.w*pv.w);
    if (lane == 0) lg[cc] = d * qis;
  }
  __syncthreads();
  if (t < 64) {
    float v = lg[t];
    float m = waveReduceMax(v);
    float e = expf(v - m);
    float s = waveReduceSum(e);
    float lse = m + logf(s);
    out0[(size_t)qi * kC + t] = v - lse;
  }
}

// ---------------- regression path ----------------
__global__ void k_colsum_r16(const float* __restrict__ X, float* __restrict__ musum) {
  int t = threadIdx.x;
  int r0 = blockIdx.x * 64;
  float s = 0.f;
  for (int r = 0; r < 64; ++r) s += X[(size_t)(r0 + r) * kD + t];
  atomicAdd(&musum[t], s);
}
__global__ void k_mufin_r16(const float* __restrict__ musum, float* __restrict__ mu) {
  int t = threadIdx.x;
  mu[t] = musum[t] * (1.0f / (float)kNS);
}

__global__ void k_xtx_r16(const float* __restrict__ X, float* __restrict__ xtx) {
  __shared__ alignas(16) float As[16][68];
  __shared__ alignas(16) float Bs[16][68];
  int t = threadIdx.x, tx = t & 15, ty = t >> 4;
  int ab = (blockIdx.x >> 2) * 64, bb = (blockIdx.x & 3) * 64;
  int k0b = blockIdx.y * 1024;
  float acc[4][4] = {};
  for (int k0 = 0; k0 < 1024; k0 += 16) {
    __syncthreads();
    int j = t & 63, kr0 = t >> 6;
#pragma unroll
    for (int p = 0; p < 4; ++p) {
      int kr = kr0 + p * 4;
      size_t base = (size_t)(k0b + k0 + kr) * kD;
      As[kr][j] = X[base + ab + j];
      Bs[kr][j] = X[base + bb + j];
    }
    __syncthreads();
#pragma unroll
    for (int k = 0; k < 16; ++k) {
      float4 a = *(const float4*)&As[k][ty * 4];
      float4 b = *(const float4*)&Bs[k][tx * 4];
      fma16(acc, a, b);
    }
  }
#pragma unroll
  for (int r = 0; r < 4; ++r)
#pragma unroll
    for (int c = 0; c < 4; ++c)
      atomicAdd(&xtx[(size_t)(ab + ty * 4 + r) * kD + bb + tx * 4 + c], acc[r][c]);
}

__global__ void k_cov_r16(const float* __restrict__ xtx, const float* __restrict__ mu,
                          float* __restrict__ cov) {
  int i = blockIdx.x, j = threadIdx.x;
  float v = (xtx[(size_t)i * kD + j] - (float)kNS * mu[i] * mu[j]) * (1.0f / (float)(kNS - 1));
  if (i == j) v += 1e-4f;
  cov[(size_t)i * kD + j] = v;
}

__global__ void k_rowabs_r16(const float* __restrict__ cov, float* __restrict__ rows) {
  int row = blockIdx.x, lane = threadIdx.x;
  float4 v = *(const float4*)&cov[(size_t)row * kD + lane * 4];
  float s = waveReduceSum(fabsf(v.x) + fabsf(v.y) + fabsf(v.z) + fabsf(v.w));
  if (lane == 0) rows[row] = s;
}
__global__ void k_cnorm_r16(const float* __restrict__ rows, float* __restrict__ cptr) {
  int lane = threadIdx.x;
  float m = fmaxf(fmaxf(rows[lane], rows[lane + 64]),
                  fmaxf(rows[lane + 128], rows[lane + 192]));
  m = waveReduceMax(m);
  if (lane == 0) cptr[0] = m;
}
// X0 = I / c
__global__ void k_newt_init_r16(const float* __restrict__ cptr, float* __restrict__ X) {
  int i = blockIdx.x, j = threadIdx.x;
  X[(size_t)i * kD + j] = (i == j) ? (1.0f / cptr[0]) : 0.0f;
}

// R17: one 256x256 matmul step, 1024 threads (4-way split-k + LDS reduce).
// isT=1: Out = 2I - A @ Xin.  isT=0: Out = A @ Xin  (A indexed by row).
__global__ void __launch_bounds__(1024)
k_newt_mm_r17(const float* __restrict__ A, const float* __restrict__ Xin,
              float* __restrict__ Out, int isT) {
  __shared__ float a_s[256];
  __shared__ float red[3][256];
  int i = blockIdx.x, t = threadIdx.x;
  int j = t & 255, kq = t >> 8;
  if (t < 256) a_s[t] = A[(size_t)i * kD + t];
  __syncthreads();
  int k0 = kq * 64;
  const float* Xp = &Xin[(size_t)k0 * kD + j];
  float s0 = 0.f, s1 = 0.f, s2 = 0.f, s3 = 0.f;
#pragma unroll 4
  for (int k = 0; k < 64; k += 4) {
    s0 = fmaf(a_s[k0 + k + 0], Xp[0 * kD], s0);
    s1 = fmaf(a_s[k0 + k + 1], Xp[1 * kD], s1);
    s2 = fmaf(a_s[k0 + k + 2], Xp[2 * kD], s2);
    s3 = fmaf(a_s[k0 + k + 3], Xp[3 * kD], s3);
    Xp += 4 * kD;
  }
  float s = (s0 + s1) + (s2 + s3);
  if (kq) red[kq - 1][j] = s;
  __syncthreads();
  if (t < 256) {
    float tot = s + red[0][j] + red[1][j] + red[2][j];
    float o = isT ? ((i == j ? 2.0f : 0.0f) - tot) : tot;
    Out[(size_t)i * kD + j] = o;
  }
}

// G = (Q - mu) @ M
__global__ void k_G_r16(const float* __restrict__ Q, const float* __restrict__ mu,
                        const float* __restrict__ M, float* __restrict__ G) {
  __shared__ alignas(16) float As[16][68];
  __shared__ alignas(16) float Bs[16][68];
  int t = threadIdx.x, tx = t & 15, ty = t >> 4;
  int nb = blockIdx.x * 64;
  int mb = blockIdx.y * 64;
  float acc[4][4] = {};
  for (int k0 = 0; k0 < 256; k0 += 16) {
    __syncthreads();
    {
      int kk = t & 15, m0 = t >> 4;
      float muk = mu[k0 + kk];
#pragma unroll
      for (int p = 0; p < 4; ++p) {
        int m = m0 + p * 16;
        As[kk][m] = Q[(size_t)(mb + m) * kD + k0 + kk] - muk;
      }
      int j = t & 63, kr0 = t >> 6;
#pragma unroll
      for (int p = 0; p < 4; ++p) {
        int kr = kr0 + p * 4;
        Bs[kr][j] = M[(size_t)(k0 + kr) * kD + nb + j];
      }
    }
    __syncthreads();
#pragma unroll
    for (int k = 0; k < 16; ++k) {
      float4 a = *(const float4*)&As[k][ty * 4];
      float4 b = *(const float4*)&Bs[k][tx * 4];
      fma16(acc, a, b);
    }
  }
#pragma unroll
  for (int r = 0; r < 4; ++r) {
    int gi = mb + ty * 4 + r;
    float4 o = {acc[r][0], acc[r][1], acc[r][2], acc[r][3]};
    *(float4*)&G[(size_t)gi * kD + nb + tx * 4] = o;
  }
}

// q2p[i] = G_i . (Q_i + mu)
__global__ void k_q2p_r16(const float* __restrict__ G, const float* __restrict__ Q,
                          const float* __restrict__ mu, float* __restrict__ q2p) {
  int w = threadIdx.x >> 6, lane = threadIdx.x & 63;
  int row = blockIdx.x * 4 + w;
  float4 g = *(const float4*)&G[(size_t)row * kD + lane * 4];
  float4 q = *(const float4*)&Q[(size_t)row * kD + lane * 4];
  float4 m = *(const float4*)&mu[lane * 4];
  float ss = waveReduceSum(g.x*(q.x+m.x) + g.y*(q.y+m.y) + g.z*(q.z+m.z) + g.w*(q.w+m.w));
  if (lane == 0) q2p[row] = ss;
}

// s2[j] = (S_j - mu) M (S_j - mu), per 64-row chunk
__global__ void k_s2_r16(const float* __restrict__ S, const float* __restrict__ mu,
                         const float* __restrict__ M, float* __restrict__ s2) {
  __shared__ alignas(16) float As[16][68];
  __shared__ alignas(16) float Bs[16][68];
  __shared__ float red[64][17];
  int t = threadIdx.x, tx = t & 15, ty = t >> 4;
  int mb = blockIdx.x * 64;
  float partial[4] = {0.f, 0.f, 0.f, 0.f};
  for (int ntile = 0; ntile < 4; ++ntile) {
    int nb = ntile * 64;
    float acc[4][4] = {};
    for (int k0 = 0; k0 < 256; k0 += 16) {
      __syncthreads();
      {
        int kk = t & 15, m0 = t >> 4;
        float muk = mu[k0 + kk];
#pragma unroll
        for (int p = 0; p < 4; ++p) {
          int m = m0 + p * 16;
          As[kk][m] = S[(size_t)(mb + m) * kD + k0 + kk] - muk;
        }
        int j = t & 63, kr0 = t >> 6;
#pragma unroll
        for (int p = 0; p < 4; ++p) {
          int kr = kr0 + p * 4;
          Bs[kr][j] = M[(size_t)(k0 + kr) * kD + nb + j];
        }
      }
      __syncthreads();
#pragma unroll
      for (int k = 0; k < 16; ++k) {
        float4 a = *(const float4*)&As[k][ty * 4];
        float4 b = *(const float4*)&Bs[k][tx * 4];
        fma16(acc, a, b);
      }
    }
#pragma unroll
    for (int r = 0; r < 4; ++r) {
      int gi = mb + ty * 4 + r;
#pragma unroll
      for (int c = 0; c < 4; ++c) {
        int gj = nb + tx * 4 + c;
        partial[r] += acc[r][c] * (S[(size_t)gi * kD + gj] - mu[gj]);
      }
    }
  }
  __syncthreads();
#pragma unroll
  for (int r = 0; r < 4; ++r) red[ty * 4 + r][tx] = partial[r];
  __syncthreads();
  if (t < 64) {
    float s = 0.f;
#pragma unroll
    for (int x = 0; x < 16; ++x) s += red[t][x];
    s2[mb + t] = s;
  }
}

// GEMM-tiled sampled-median histogram
__global__ void k_median_r16(const float* __restrict__ G, const float* __restrict__ S,
                             const float* __restrict__ q2p, const float* __restrict__ s2,
                             unsigned int* __restrict__ hist, float* __restrict__ ssum) {
  __shared__ alignas(16) float As[16][68];
  __shared__ alignas(16) float Bs[16][68];
  __shared__ unsigned int h[2048];
  __shared__ float fred[4];
  int t = threadIdx.x, tx = t & 15, ty = t >> 4;
  int stile = blockIdx.x, qtile = blockIdx.y;
  for (int i = t; i < 2048; i += 256) h[i] = 0u;

  float acc[4][4] = {};
  for (int k0 = 0; k0 < 256; k0 += 16) {
    __syncthreads();
    {
      int kk = t & 15, m0 = t >> 4;
#pragma unroll
      for (int p = 0; p < 4; ++p) {
        int m = m0 + p * 16;
        As[kk][m] = G[(size_t)((qtile * 64 + m) * 8) * kD + k0 + kk];
        Bs[kk][m] = S[(size_t)((stile * 64 + m) * 8) * kD + k0 + kk];
      }
    }
    __syncthreads();
#pragma unroll
    for (int k = 0; k < 16; ++k) {
      float4 a = *(const float4*)&As[k][ty * 4];
      float4 b = *(const float4*)&Bs[k][tx * 4];
      fma16(acc, a, b);
    }
  }
  float fsum = 0.f;
#pragma unroll
  for (int r = 0; r < 4; ++r) {
    int qi = (qtile * 64 + ty * 4 + r) * 8;
    float q2v = q2p[qi];
#pragma unroll
    for (int c = 0; c < 4; ++c) {
      int sj = (stile * 64 + tx * 4 + c) * 8;
      float d2 = fmaxf(q2v + s2[sj] - 2.0f * acc[r][c], 0.0f);
      fsum += d2;
      int bin = (int)(d2 * 2.0f);
      bin = bin > 2047 ? 2047 : bin;
      atomicAdd(&h[bin], 1u);
    }
  }
  float wsum = waveReduceSum(fsum);
  if ((t & 63) == 0) fred[t >> 6] = wsum;
  __syncthreads();
  if (t == 0) atomicAdd(ssum, fred[0] + fred[1] + fred[2] + fred[3]);
  for (int i = t; i < 2048; i += 256)
    if (h[i]) atomicAdd(&hist[i], h[i]);
}

// Parallel median + gamma: 256 threads x 8 bins, LDS scan.
__global__ void k_gamma_r16(const unsigned int* __restrict__ hist,
                            const float* __restrict__ ssum, float* __restrict__ gptr) {
  __shared__ unsigned int ps[256];
  __shared__ float v0s, v1s;
  int t = threadIdx.x;
  unsigned int mine[8];
  unsigned int c = 0;
#pragma unroll
  for (int j = 0; j < 8; ++j) { mine[j] = hist[t * 8 + j]; c += mine[j]; }
  ps[t] = c;
  __syncthreads();
  // Hillis-Steele inclusive scan
  for (int off = 1; off < 256; off <<= 1) {
    unsigned int v = (t >= off) ? ps[t - off] : 0u;
    __syncthreads();
    ps[t] += v;
    __syncthreads();
  }
  unsigned int total = ps[255];
  unsigned int before = ps[t] - c;      // exclusive prefix for my 8 bins
  if (t == 0) { v0s = 0.f; v1s = 0.f; }
  __syncthreads();
  unsigned int rr0 = (total - 1) / 2, rr1 = total / 2;
  unsigned int cum = before;
#pragma unroll
  for (int j = 0; j < 8; ++j) {
    unsigned int cc = mine[j];
    if (cc > 0) {
      int bin = t * 8 + j;
      if (cum <= rr0 && rr0 < cum + cc) {
        float frac = (float)(rr0 - cum) + 0.5f;
        v0s = ((float)bin + frac / (float)cc) * 0.5f;
      }
      if (cum <= rr1 && rr1 < cum + cc) {
        float frac = (float)(rr1 - cum) + 0.5f;
        v1s = ((float)bin + frac / (float)cc) * 0.5f;
      }
    }
    cum += cc;
  }
  __syncthreads();
  if (t == 0) {
    float med = 0.5f * (v0s + v1s);
    float mean = (total > 0) ? (ssum[0] / (float)total) : 1.0f;
    float g = (med > 0.f) ? 1.0f / (med + 1e-6f) : 1.0f / (mean + 1e-6f);
    gptr[0] = g;
  }
}

// MAIN (MFMA, swizzled operands, R17 LDS-staged B): grid (128 q-tiles, 16 s-chunks).
// Per block: stage 64 s-rows (32 KB, already fragment-major -> linear copy) into
// LDS once; all 4 waves ds_read_b128 from it (was: 4x redundant L2 reads).
__global__ void PrototypicalHead_6210522710389_kernel(
    const unsigned short* __restrict__ Gh, const unsigned short* __restrict__ Sh,
    const float* __restrict__ q2p, const float* __restrict__ s2,
    const float* __restrict__ svals, const float* __restrict__ gptr,
    float* __restrict__ part) {
  __shared__ unsigned short Bs[16384];   // 32 KB -> 5 blocks/CU
  int t = threadIdx.x;
  int w = t >> 6, lane = t & 63;
  int l15 = lane & 15, quad = lane >> 4;
  int qt = blockIdx.x, sc = blockIdx.y;
  int qbase = qt * 64;
  float gamma = gptr[0];
  const float LOG2E = 1.44269504f;
  float c2 = 2.0f * gamma * LOG2E;       // exp2 folding: e^{-g*d2} = 2^{c2*a + cq + cs}

  size_t agrp = (size_t)(qt * 4 + w) * 4096;
  bf16x8 afrag[8];
#pragma unroll
  for (int ks = 0; ks < 8; ++ks)
    afrag[ks] = *(const bf16x8*)&Gh[agrp + (size_t)ks * 512 + (size_t)lane * 8];

  float cqv[4];
#pragma unroll
  for (int r = 0; r < 4; ++r)
    cqv[r] = -gamma * LOG2E * q2p[qbase + w * 16 + quad * 4 + r];

  float dAcc[4] = {0.f, 0.f, 0.f, 0.f}, nAcc[4] = {0.f, 0.f, 0.f, 0.f};

  for (int st = 0; st < 16; ++st) {
    int sbase = sc * 1024 + st * 64;
    const char* src = (const char*)&Sh[(size_t)(sbase >> 4) * 4096];
    __syncthreads();   // previous tile's LDS reads done before overwrite
#pragma unroll
    for (int i = 0; i < 8; ++i) {
      int c = i * 256 + t;               // 2048 chunks x 16 B = 32 KB, linear
      gload_lds16(src + (size_t)c * 16, (char*)Bs + (size_t)c * 16);
    }
    __syncthreads();   // drains vmcnt -> LDS tile ready

    f32x4 acc0 = {0.f, 0.f, 0.f, 0.f};
    f32x4 acc1 = {0.f, 0.f, 0.f, 0.f};
    f32x4 acc2 = {0.f, 0.f, 0.f, 0.f};
    f32x4 acc3 = {0.f, 0.f, 0.f, 0.f};
    const unsigned short* B0 = &Bs[lane * 8];
#pragma unroll
    for (int ks = 0; ks < 8; ++ks) {
      bf16x8 f0 = *(const bf16x8*)(B0 + ks * 512);
      bf16x8 f1 = *(const bf16x8*)(B0 + 4096 + ks * 512);
      bf16x8 f2 = *(const bf16x8*)(B0 + 8192 + ks * 512);
      bf16x8 f3 = *(const bf16x8*)(B0 + 12288 + ks * 512);
      acc0 = __builtin_amdgcn_mfma_f32_16x16x32_bf16(afrag[ks], f0, acc0, 0, 0, 0);
      acc1 = __builtin_amdgcn_mfma_f32_16x16x32_bf16(afrag[ks], f1, acc1, 0, 0, 0);
      acc2 = __builtin_amdgcn_mfma_f32_16x16x32_bf16(afrag[ks], f2, acc2, 0, 0, 0);
      acc3 = __builtin_amdgcn_mfma_f32_16x16x32_bf16(afrag[ks], f3, acc3, 0, 0, 0);
    }
#pragma unroll
    for (int nt = 0; nt < 4; ++nt) {
      f32x4 a = (nt == 0) ? acc0 : (nt == 1) ? acc1 : (nt == 2) ? acc2 : acc3;
      int scol = sbase + nt * 16 + l15;
      float cs = -gamma * LOG2E * s2[scol];
      float sv = svals[scol];
#pragma unroll
      for (int r = 0; r < 4; ++r) {
        // exponent = log2e * -(gamma*(q2+s2-2a)); min(...,0) == the d2>=0 clamp
        float ex = exp2f(fminf(fmaf(c2, a[r], cqv[r] + cs), 0.0f));
        dAcc[r] += ex;
        nAcc[r] = fmaf(ex, sv, nAcc[r]);
      }
    }
  }
#pragma unroll
  for (int off = 8; off >= 1; off >>= 1) {
#pragma unroll
    for (int r = 0; r < 4; ++r) {
      dAcc[r] += __shfl_xor(dAcc[r], off);
      nAcc[r] += __shfl_xor(nAcc[r], off);
    }
  }
  if (l15 == 0) {
#pragma unroll
    for (int r = 0; r < 4; ++r) {
      size_t q = (size_t)qbase + w * 16 + quad * 4 + r;
      part[(q * 16 + sc) * 2 + 0] = dAcc[r];
      part[(q * 16 + sc) * 2 + 1] = nAcc[r];
    }
  }
}

__global__ void k_final_r16(const float* __restrict__ part, float* __restrict__ out1) {
  int q = blockIdx.x * 256 + threadIdx.x;
  const float* p = part + (size_t)q * 32;
  float d = 0.f, n = 0.f;
#pragma unroll
  for (int i = 0; i < 16; ++i) { d += p[2 * i]; n += p[2 * i + 1]; }
  out1[q] = n / d;
}

extern "C" void kernel_launch(void* const* d_in, const int* in_sizes, int n_in,
                              void* d_out, int out_size, void* d_ws, size_t ws_size,
                              hipStream_t stream) {
  (void)in_sizes; (void)n_in; (void)out_size; (void)ws_size;
  const float* SF = (const float*)d_in[0];   // fp32
  const int*   SL = (const int*)d_in[1];     // int32
  const float* SV = (const float*)d_in[2];   // fp32
  const float* QF = (const float*)d_in[3];   // fp32

  float* ws = (float*)d_ws;
  float* psum  = ws + OFF_PSUM;
  float* pcnt  = ws + OFF_PCNT;
  float* musum = ws + OFF_MUSUM;
  float* xtx   = ws + OFF_XTX;
  unsigned int* hist = (unsigned int*)(ws + OFF_HIST);
  float* ssum  = ws + OFF_SSUM;
  float* protos= ws + OFF_PROTO;
  float* mu    = ws + OFF_MU;
  float* cov   = ws + OFF_COV;
  float* rows  = ws + OFF_ROWS;
  float* cptr  = ws + OFF_C;
  float* gptr  = ws + OFF_C + 1;
  float* X1 = ws + OFF_Y;  float* T = ws + OFF_T;  float* X2 = ws + OFF_Y2;
  float* s2 = ws + OFF_S2; float* q2p = ws + OFF_Q2P;
  float* part = ws + OFF_PART;
  float* G = ws + OFF_G;
  unsigned short* Sh = (unsigned short*)(ws + OFF_SH);
  unsigned short* Gh = (unsigned short*)(ws + OFF_GH);

  float* out0 = (float*)d_out;                   // f32 log_probs [8192 x 64]
  float* out1 = out0 + (size_t)kNQ * kC;         // f32 predictions [8192]

  k_zero_r16<<<(int)((ZERO_FLOATS + 255) / 256), 256, 0, stream>>>(ws);

  // swizzled bf16 copy of support features
  k_swz_r16<<<kNS / 16, 256, 0, stream>>>(SF, Sh);

  // classification
  k_proto_accum_r16<<<kNS / 4, 256, 0, stream>>>(SF, SL, psum, pcnt);
  k_proto_fin_r16<<<kC, 64, 0, stream>>>(psum, pcnt, protos);
  k_logits_r16<<<kNQ, 256, 0, stream>>>(QF, protos, out0);

  // regression: mean, cov
  k_colsum_r16<<<kNS / 64, 256, 0, stream>>>(SF, musum);
  k_mufin_r16<<<1, 256, 0, stream>>>(musum, mu);
  k_xtx_r16<<<dim3(16, 16), 256, 0, stream>>>(SF, xtx);
  k_cov_r16<<<256, 256, 0, stream>>>(xtx, mu, cov);

  // Newton matrix inverse: X <- X (2I - cov X), X0 = I/c, 6 iterations
  // R17: 1024-thread split-k matmul steps (was 256 thr, 1 wave/SIMD).
  k_rowabs_r16<<<256, 64, 0, stream>>>(cov, rows);
  k_cnorm_r16<<<1, 64, 0, stream>>>(rows, cptr);
  k_newt_init_r16<<<256, 256, 0, stream>>>(cptr, X1);
  float *Xc = X1, *Xn = X2;
  for (int it = 0; it < 6; ++it) {
    k_newt_mm_r17<<<256, 1024, 0, stream>>>(cov, Xc, T, 1);
    k_newt_mm_r17<<<256, 1024, 0, stream>>>(Xc, T, Xn, 0);
    float* tmp = Xc; Xc = Xn; Xn = tmp;
  }
  float* M = Xc;   // cov^-1

  // G = (Q - mu) @ M, swizzled bf16 copy, scalar row terms
  k_G_r16<<<dim3(4, kNQ / 64), 256, 0, stream>>>(QF, mu, M, G);
  k_swz_r16<<<kNQ / 16, 256, 0, stream>>>(G, Gh);
  k_q2p_r16<<<kNQ / 4, 256, 0, stream>>>(G, QF, mu, q2p);
  k_s2_r16<<<kNS / 64, 256, 0, stream>>>(SF, mu, M, s2);

  // sampled median -> gamma (parallel)
  k_median_r16<<<dim3(32, 16), 256, 0, stream>>>(G, SF, q2p, s2, hist, ssum);
  k_gamma_r16<<<1, 256, 0, stream>>>(hist, ssum, gptr);

  // MFMA fused cdist^2 + softmax numer/denom, then finalize
  PrototypicalHead_6210522710389_kernel<<<dim3(128, 16), 256, 0, stream>>>(
      Gh, Sh, q2p, s2, SV, gptr, part);
  k_final_r16<<<kNQ / 256, 256, 0, stream>>>(part, out1);
}

// Round 3
// 540.440 us; speedup vs baseline: 1.3887x; 1.2199x over previous
//
#include <hip/hip_runtime.h>
#include <hip/hip_bf16.h>

// Problem dims (fixed by setup_inputs)
constexpr int kNS = 16384;   // support rows
constexpr int kNQ = 8192;    // query rows
constexpr int kD  = 256;     // feature dim
constexpr int kC  = 64;      // classes

// R18 PASSED (659 us). Top dispatch now k_proto_accum (150 us): 4.2M global
// atomicAdds onto 16K addresses (256-way collision, WRITE_SIZE 66MB for a
// 64KB output). R19: atomic-free privatized segment-sum — k_rnorm (wave/row
// inv-norms) + k_paccum (thread-owns-dim, LDS acc[c][t], zero atomics,
// 128 blocks x 128 rows) + k_proto_fin_r19 (reduce 128 partials). Partials
// reuse the G region (written later), counts reuse the part region.

// ---------------- workspace layout (float offsets into d_ws), ~24.4 MB ----
constexpr size_t OFF_PSUM  = 0;          // r19: rnorm[16384]
constexpr size_t OFF_PCNT  = 16384;
constexpr size_t OFF_MUSUM = 16448;
constexpr size_t OFF_XTX   = 16704;
constexpr size_t OFF_HIST  = 82240;
constexpr size_t OFF_SSUM  = 84288;
constexpr size_t ZERO_FLOATS = 84352;
constexpr size_t OFF_PROTO = 84352;
constexpr size_t OFF_MU    = 100736;
constexpr size_t OFF_COV   = 100992;
constexpr size_t OFF_ROWS  = 166528;
constexpr size_t OFF_C     = 166784;
constexpr size_t OFF_Y     = 166800;     // Newton X ping
constexpr size_t OFF_T     = 297872;     // Newton T
constexpr size_t OFF_Y2    = 363408;     // Newton X pong
constexpr size_t OFF_S2    = 560016;
constexpr size_t OFF_Q2P   = 576400;
constexpr size_t OFF_PART  = 584592;     // r19: also cntpart[128*64] (proto phase)
constexpr size_t OFF_G     = 846736;     // 8192*256 f32; r19: also proto partials
constexpr size_t OFF_SH    = 2943888;    // 16384*256 bf16 swizzled
constexpr size_t OFF_GH    = 5041040;    // 8192*256 bf16 swizzled

typedef __attribute__((ext_vector_type(8))) short bf16x8;
typedef __attribute__((ext_vector_type(4))) float f32x4;

__device__ __forceinline__ unsigned short f2bf(float f) {
  unsigned int w; __builtin_memcpy(&w, &f, 4);
  unsigned int r = (w + 0x7FFFu + ((w >> 16) & 1u)) >> 16;
  return (unsigned short)r;
}

__device__ __forceinline__ float waveReduceSum(float v) {
#pragma unroll
  for (int off = 32; off > 0; off >>= 1) v += __shfl_xor(v, off);
  return v;
}
__device__ __forceinline__ float waveReduceMax(float v) {
#pragma unroll
  for (int off = 32; off > 0; off >>= 1) v = fmaxf(v, __shfl_xor(v, off));
  return v;
}
__device__ __forceinline__ void fma16(float acc[4][4], float4 a, float4 b) {
  acc[0][0] += a.x*b.x; acc[0][1] += a.x*b.y; acc[0][2] += a.x*b.z; acc[0][3] += a.x*b.w;
  acc[1][0] += a.y*b.x; acc[1][1] += a.y*b.y; acc[1][2] += a.y*b.z; acc[1][3] += a.y*b.w;
  acc[2][0] += a.z*b.x; acc[2][1] += a.z*b.y; acc[2][2] += a.z*b.z; acc[2][3] += a.z*b.w;
  acc[3][0] += a.w*b.x; acc[3][1] += a.w*b.y; acc[3][2] += a.w*b.z; acc[3][3] += a.w*b.w;
}

// async global -> LDS, 16 B per lane
__device__ __forceinline__ void gload_lds16(const void* g, void* l) {
  __builtin_amdgcn_global_load_lds(
      (const __attribute__((address_space(1))) unsigned int*)g,
      (__attribute__((address_space(3))) unsigned int*)l, 16, 0, 0);
}

__global__ void k_zero_r16(float* __restrict__ ws) {
  size_t i = (size_t)blockIdx.x * 256 + threadIdx.x;
  if (i < ZERO_FLOATS) ws[i] = 0.f;
}

// f32 [rows x 256] -> bf16 fragment-major swizzle (one block per 16-row group)
__global__ void k_swz_r16(const float* __restrict__ in, unsigned short* __restrict__ out) {
  int g = blockIdx.x, t = threadIdx.x;
  int ks = t >> 5;
  size_t gbase = (size_t)g * 4096;
#pragma unroll
  for (int f = 0; f < 2; ++f) {
    int lane = (2 * t + f) & 63;
    int q = lane >> 4, r = lane & 15;
    const float* src = &in[(size_t)(g * 16 + r) * kD + ks * 32 + q * 8];
    float4 v0 = *(const float4*)src;
    float4 v1 = *(const float4*)(src + 4);
    ushort4 o0, o1;
    o0.x = f2bf(v0.x); o0.y = f2bf(v0.y); o0.z = f2bf(v0.z); o0.w = f2bf(v0.w);
    o1.x = f2bf(v1.x); o1.y = f2bf(v1.y); o1.z = f2bf(v1.z); o1.w = f2bf(v1.w);
    unsigned short* dst = &out[gbase + (size_t)ks * 512 + (size_t)lane * 8];
    *(ushort4*)dst = o0;
    *(ushort4*)(dst + 4) = o1;
  }
}

// ---------------- classification path (R19: atomic-free) ----------------
// wave per row: rnorm[i] = 1 / max(||X_i||, 1e-8)
__global__ void k_rnorm_r19(const float* __restrict__ X, float* __restrict__ rnorm) {
  int w = threadIdx.x >> 6, lane = threadIdx.x & 63;
  int row = blockIdx.x * 4 + w;
  float4 v = *(const float4*)&X[(size_t)row * kD + lane * 4];
  float ss = waveReduceSum(v.x*v.x + v.y*v.y + v.z*v.z + v.w*v.w);
  if (lane == 0) rnorm[row] = 1.0f / fmaxf(sqrtf(ss), 1e-8f);
}

// thread t owns dim t; LDS acc[64][256], no atomics. 128 blocks x 128 rows.
__global__ void k_paccum_r19(const float* __restrict__ X, const int* __restrict__ lab,
                             const float* __restrict__ rnorm,
                             float* __restrict__ partial, float* __restrict__ cntpart) {
  __shared__ float acc[kC * kD];   // 64 KB
  int t = threadIdx.x, b = blockIdx.x;
  for (int i = t; i < kC * kD; i += 256) acc[i] = 0.f;
  __syncthreads();
  int r0 = b * 128;
  float myCnt = 0.f;
  for (int r = 0; r < 128; r += 8) {
    int row = r0 + r;
    int   c0 = lab[row + 0], c1 = lab[row + 1], c2 = lab[row + 2], c3 = lab[row + 3];
    int   c4 = lab[row + 4], c5 = lab[row + 5], c6 = lab[row + 6], c7 = lab[row + 7];
    float n0 = rnorm[row + 0], n1 = rnorm[row + 1], n2 = rnorm[row + 2], n3 = rnorm[row + 3];
    float n4 = rnorm[row + 4], n5 = rnorm[row + 5], n6 = rnorm[row + 6], n7 = rnorm[row + 7];
    float x0 = X[(size_t)(row + 0) * kD + t];
    float x1 = X[(size_t)(row + 1) * kD + t];
    float x2 = X[(size_t)(row + 2) * kD + t];
    float x3 = X[(size_t)(row + 3) * kD + t];
    float x4 = X[(size_t)(row + 4) * kD + t];
    float x5 = X[(size_t)(row + 5) * kD + t];
    float x6 = X[(size_t)(row + 6) * kD + t];
    float x7 = X[(size_t)(row + 7) * kD + t];
    acc[c0 * kD + t] += x0 * n0;
    acc[c1 * kD + t] += x1 * n1;
    acc[c2 * kD + t] += x2 * n2;
    acc[c3 * kD + t] += x3 * n3;
    acc[c4 * kD + t] += x4 * n4;
    acc[c5 * kD + t] += x5 * n5;
    acc[c6 * kD + t] += x6 * n6;
    acc[c7 * kD + t] += x7 * n7;
    myCnt += (t == c0) ? 1.f : 0.f; myCnt += (t == c1) ? 1.f : 0.f;
    myCnt += (t == c2) ? 1.f : 0.f; myCnt += (t == c3) ? 1.f : 0.f;
    myCnt += (t == c4) ? 1.f : 0.f; myCnt += (t == c5) ? 1.f : 0.f;
    myCnt += (t == c6) ? 1.f : 0.f; myCnt += (t == c7) ? 1.f : 0.f;
  }
  __syncthreads();
  float* pb = partial + (size_t)b * (kC * kD);
  for (int c = 0; c < kC; ++c) pb[c * kD + t] = acc[c * kD + t];
  if (t < kC) cntpart[b * kC + t] = myCnt;
}

// one block per class: reduce 128 partials, divide by count, L2-normalize
__global__ void k_proto_fin_r19(const float* __restrict__ partial,
                                const float* __restrict__ cntpart,
                                float* __restrict__ protos) {
  __shared__ float cs[128];
  __shared__ float wred[4];
  __shared__ float cntS, invS;
  int c = blockIdx.x, t = threadIdx.x;
  if (t < 128) cs[t] = cntpart[t * kC + c];
  __syncthreads();
  float s = 0.f;
  const float* p = partial + (size_t)c * kD + t;
  for (int b = 0; b < 128; ++b) s += p[(size_t)b * (kC * kD)];
  if (t < 64) {
    float cv = cs[t] + cs[t + 64];
    cv = waveReduceSum(cv);
    if (t == 0) cntS = fmaxf(cv, 1.0f);
  }
  __syncthreads();
  float v = s / cntS;
  float ss = waveReduceSum(v * v);
  if ((t & 63) == 0) wred[t >> 6] = ss;
  __syncthreads();
  if (t == 0) invS = 1.0f / fmaxf(sqrtf(wred[0] + wred[1] + wred[2] + wred[3]), 1e-8f);
  __syncthreads();
  protos[(size_t)c * kD + t] = v * invS;
}

__global__ void k_logits_r16(const float* __restrict__ Q, const float* __restrict__ protos,
                             float* __restrict__ out0) {
  __shared__ alignas(16) float qs[kD];
  __shared__ float lg[kC];
  __shared__ float wred[4];
  __shared__ float qis;
  int t = threadIdx.x, w = t >> 6, lane = t & 63;
  int qi = blockIdx.x;
  float myv = Q[(size_t)qi * kD + t];
  qs[t] = myv;
  float ss = waveReduceSum(myv * myv);
  if (lane == 0) wred[w] = ss;
  __syncthreads();
  if (t == 0) qis = 1.0f / fmaxf(sqrtf(wred[0] + wred[1] + wred[2] + wred[3]), 1e-8f);
  __syncthreads();
  float4 qv = *(const float4*)&qs[lane * 4];
  for (int cc = w * 16; cc < w * 16 + 16; ++cc) {
    float4 pv = *(const float4*)&protos[(size_t)cc * kD + lane * 4];
    float d = waveReduceSum(qv.x*pv.x + qv.y*pv.y + qv.z*pv.z + qv.w*pv.w);
    if (lane == 0) lg[cc] = d * qis;
  }
  __syncthreads();
  if (t < 64) {
    float v = lg[t];
    float m = waveReduceMax(v);
    float e = expf(v - m);
    float s = waveReduceSum(e);
    float lse = m + logf(s);
    out0[(size_t)qi * kC + t] = v - lse;
  }
}

// ---------------- regression path ----------------
__global__ void k_colsum_r16(const float* __restrict__ X, float* __restrict__ musum) {
  int t = threadIdx.x;
  int r0 = blockIdx.x * 64;
  float s = 0.f;
  for (int r = 0; r < 64; ++r) s += X[(size_t)(r0 + r) * kD + t];
  atomicAdd(&musum[t], s);
}
__global__ void k_mufin_r16(const float* __restrict__ musum, float* __restrict__ mu) {
  int t = threadIdx.x;
  mu[t] = musum[t] * (1.0f / (float)kNS);
}

__global__ void k_xtx_r16(const float* __restrict__ X, float* __restrict__ xtx) {
  __shared__ alignas(16) float As[16][68];
  __shared__ alignas(16) float Bs[16][68];
  int t = threadIdx.x, tx = t & 15, ty = t >> 4;
  int ab = (blockIdx.x >> 2) * 64, bb = (blockIdx.x & 3) * 64;
  int k0b = blockIdx.y * 1024;
  float acc[4][4] = {};
  for (int k0 = 0; k0 < 1024; k0 += 16) {
    __syncthreads();
    int j = t & 63, kr0 = t >> 6;
#pragma unroll
    for (int p = 0; p < 4; ++p) {
      int kr = kr0 + p * 4;
      size_t base = (size_t)(k0b + k0 + kr) * kD;
      As[kr][j] = X[base + ab + j];
      Bs[kr][j] = X[base + bb + j];
    }
    __syncthreads();
#pragma unroll
    for (int k = 0; k < 16; ++k) {
      float4 a = *(const float4*)&As[k][ty * 4];
      float4 b = *(const float4*)&Bs[k][tx * 4];
      fma16(acc, a, b);
    }
  }
#pragma unroll
  for (int r = 0; r < 4; ++r)
#pragma unroll
    for (int c = 0; c < 4; ++c)
      atomicAdd(&xtx[(size_t)(ab + ty * 4 + r) * kD + bb + tx * 4 + c], acc[r][c]);
}

__global__ void k_cov_r16(const float* __restrict__ xtx, const float* __restrict__ mu,
                          float* __restrict__ cov) {
  int i = blockIdx.x, j = threadIdx.x;
  float v = (xtx[(size_t)i * kD + j] - (float)kNS * mu[i] * mu[j]) * (1.0f / (float)(kNS - 1));
  if (i == j) v += 1e-4f;
  cov[(size_t)i * kD + j] = v;
}

__global__ void k_rowabs_r16(const float* __restrict__ cov, float* __restrict__ rows) {
  int row = blockIdx.x, lane = threadIdx.x;
  float4 v = *(const float4*)&cov[(size_t)row * kD + lane * 4];
  float s = waveReduceSum(fabsf(v.x) + fabsf(v.y) + fabsf(v.z) + fabsf(v.w));
  if (lane == 0) rows[row] = s;
}
__global__ void k_cnorm_r16(const float* __restrict__ rows, float* __restrict__ cptr) {
  int lane = threadIdx.x;
  float m = fmaxf(fmaxf(rows[lane], rows[lane + 64]),
                  fmaxf(rows[lane + 128], rows[lane + 192]));
  m = waveReduceMax(m);
  if (lane == 0) cptr[0] = m;
}
// X0 = I / c
__global__ void k_newt_init_r16(const float* __restrict__ cptr, float* __restrict__ X) {
  int i = blockIdx.x, j = threadIdx.x;
  X[(size_t)i * kD + j] = (i == j) ? (1.0f / cptr[0]) : 0.0f;
}

// one 256x256 matmul step, 1024 threads (4-way split-k + LDS reduce).
// isT=1: Out = 2I - A @ Xin.  isT=0: Out = A @ Xin  (A indexed by row).
__global__ void __launch_bounds__(1024)
k_newt_mm_r17(const float* __restrict__ A, const float* __restrict__ Xin,
              float* __restrict__ Out, int isT) {
  __shared__ float a_s[256];
  __shared__ float red[3][256];
  int i = blockIdx.x, t = threadIdx.x;
  int j = t & 255, kq = t >> 8;
  if (t < 256) a_s[t] = A[(size_t)i * kD + t];
  __syncthreads();
  int k0 = kq * 64;
  const float* Xp = &Xin[(size_t)k0 * kD + j];
  float s0 = 0.f, s1 = 0.f, s2 = 0.f, s3 = 0.f;
#pragma unroll 4
  for (int k = 0; k < 64; k += 4) {
    s0 = fmaf(a_s[k0 + k + 0], Xp[0 * kD], s0);
    s1 = fmaf(a_s[k0 + k + 1], Xp[1 * kD], s1);
    s2 = fmaf(a_s[k0 + k + 2], Xp[2 * kD], s2);
    s3 = fmaf(a_s[k0 + k + 3], Xp[3 * kD], s3);
    Xp += 4 * kD;
  }
  float s = (s0 + s1) + (s2 + s3);
  if (kq) red[kq - 1][j] = s;
  __syncthreads();
  if (t < 256) {
    float tot = s + red[0][j] + red[1][j] + red[2][j];
    float o = isT ? ((i == j ? 2.0f : 0.0f) - tot) : tot;
    Out[(size_t)i * kD + j] = o;
  }
}

// G = (Q - mu) @ M
__global__ void k_G_r16(const float* __restrict__ Q, const float* __restrict__ mu,
                        const float* __restrict__ M, float* __restrict__ G) {
  __shared__ alignas(16) float As[16][68];
  __shared__ alignas(16) float Bs[16][68];
  int t = threadIdx.x, tx = t & 15, ty = t >> 4;
  int nb = blockIdx.x * 64;
  int mb = blockIdx.y * 64;
  float acc[4][4] = {};
  for (int k0 = 0; k0 < 256; k0 += 16) {
    __syncthreads();
    {
      int kk = t & 15, m0 = t >> 4;
      float muk = mu[k0 + kk];
#pragma unroll
      for (int p = 0; p < 4; ++p) {
        int m = m0 + p * 16;
        As[kk][m] = Q[(size_t)(mb + m) * kD + k0 + kk] - muk;
      }
      int j = t & 63, kr0 = t >> 6;
#pragma unroll
      for (int p = 0; p < 4; ++p) {
        int kr = kr0 + p * 4;
        Bs[kr][j] = M[(size_t)(k0 + kr) * kD + nb + j];
      }
    }
    __syncthreads();
#pragma unroll
    for (int k = 0; k < 16; ++k) {
      float4 a = *(const float4*)&As[k][ty * 4];
      float4 b = *(const float4*)&Bs[k][tx * 4];
      fma16(acc, a, b);
    }
  }
#pragma unroll
  for (int r = 0; r < 4; ++r) {
    int gi = mb + ty * 4 + r;
    float4 o = {acc[r][0], acc[r][1], acc[r][2], acc[r][3]};
    *(float4*)&G[(size_t)gi * kD + nb + tx * 4] = o;
  }
}

// q2p[i] = G_i . (Q_i + mu)
__global__ void k_q2p_r16(const float* __restrict__ G, const float* __restrict__ Q,
                          const float* __restrict__ mu, float* __restrict__ q2p) {
  int w = threadIdx.x >> 6, lane = threadIdx.x & 63;
  int row = blockIdx.x * 4 + w;
  float4 g = *(const float4*)&G[(size_t)row * kD + lane * 4];
  float4 q = *(const float4*)&Q[(size_t)row * kD + lane * 4];
  float4 m = *(const float4*)&mu[lane * 4];
  float ss = waveReduceSum(g.x*(q.x+m.x) + g.y*(q.y+m.y) + g.z*(q.z+m.z) + g.w*(q.w+m.w));
  if (lane == 0) q2p[row] = ss;
}

// s2[j] = (S_j - mu) M (S_j - mu), per 64-row chunk
__global__ void k_s2_r16(const float* __restrict__ S, const float* __restrict__ mu,
                         const float* __restrict__ M, float* __restrict__ s2) {
  __shared__ alignas(16) float As[16][68];
  __shared__ alignas(16) float Bs[16][68];
  __shared__ float red[64][17];
  int t = threadIdx.x, tx = t & 15, ty = t >> 4;
  int mb = blockIdx.x * 64;
  float partial[4] = {0.f, 0.f, 0.f, 0.f};
  for (int ntile = 0; ntile < 4; ++ntile) {
    int nb = ntile * 64;
    float acc[4][4] = {};
    for (int k0 = 0; k0 < 256; k0 += 16) {
      __syncthreads();
      {
        int kk = t & 15, m0 = t >> 4;
        float muk = mu[k0 + kk];
#pragma unroll
        for (int p = 0; p < 4; ++p) {
          int m = m0 + p * 16;
          As[kk][m] = S[(size_t)(mb + m) * kD + k0 + kk] - muk;
        }
        int j = t & 63, kr0 = t >> 6;
#pragma unroll
        for (int p = 0; p < 4; ++p) {
          int kr = kr0 + p * 4;
          Bs[kr][j] = M[(size_t)(k0 + kr) * kD + nb + j];
        }
      }
      __syncthreads();
#pragma unroll
      for (int k = 0; k < 16; ++k) {
        float4 a = *(const float4*)&As[k][ty * 4];
        float4 b = *(const float4*)&Bs[k][tx * 4];
        fma16(acc, a, b);
      }
    }
#pragma unroll
    for (int r = 0; r < 4; ++r) {
      int gi = mb + ty * 4 + r;
#pragma unroll
      for (int c = 0; c < 4; ++c) {
        int gj = nb + tx * 4 + c;
        partial[r] += acc[r][c] * (S[(size_t)gi * kD + gj] - mu[gj]);
      }
    }
  }
  __syncthreads();
#pragma unroll
  for (int r = 0; r < 4; ++r) red[ty * 4 + r][tx] = partial[r];
  __syncthreads();
  if (t < 64) {
    float s = 0.f;
#pragma unroll
    for (int x = 0; x < 16; ++x) s += red[t][x];
    s2[mb + t] = s;
  }
}

// GEMM-tiled sampled-median histogram
__global__ void k_median_r16(const float* __restrict__ G, const float* __restrict__ S,
                             const float* __restrict__ q2p, const float* __restrict__ s2,
                             unsigned int* __restrict__ hist, float* __restrict__ ssum) {
  __shared__ alignas(16) float As[16][68];
  __shared__ alignas(16) float Bs[16][68];
  __shared__ unsigned int h[2048];
  __shared__ float fred[4];
  int t = threadIdx.x, tx = t & 15, ty = t >> 4;
  int stile = blockIdx.x, qtile = blockIdx.y;
  for (int i = t; i < 2048; i += 256) h[i] = 0u;

  float acc[4][4] = {};
  for (int k0 = 0; k0 < 256; k0 += 16) {
    __syncthreads();
    {
      int kk = t & 15, m0 = t >> 4;
#pragma unroll
      for (int p = 0; p < 4; ++p) {
        int m = m0 + p * 16;
        As[kk][m] = G[(size_t)((qtile * 64 + m) * 8) * kD + k0 + kk];
        Bs[kk][m] = S[(size_t)((stile * 64 + m) * 8) * kD + k0 + kk];
      }
    }
    __syncthreads();
#pragma unroll
    for (int k = 0; k < 16; ++k) {
      float4 a = *(const float4*)&As[k][ty * 4];
      float4 b = *(const float4*)&Bs[k][tx * 4];
      fma16(acc, a, b);
    }
  }
  float fsum = 0.f;
#pragma unroll
  for (int r = 0; r < 4; ++r) {
    int qi = (qtile * 64 + ty * 4 + r) * 8;
    float q2v = q2p[qi];
#pragma unroll
    for (int c = 0; c < 4; ++c) {
      int sj = (stile * 64 + tx * 4 + c) * 8;
      float d2 = fmaxf(q2v + s2[sj] - 2.0f * acc[r][c], 0.0f);
      fsum += d2;
      int bin = (int)(d2 * 2.0f);
      bin = bin > 2047 ? 2047 : bin;
      atomicAdd(&h[bin], 1u);
    }
  }
  float wsum = waveReduceSum(fsum);
  if ((t & 63) == 0) fred[t >> 6] = wsum;
  __syncthreads();
  if (t == 0) atomicAdd(ssum, fred[0] + fred[1] + fred[2] + fred[3]);
  for (int i = t; i < 2048; i += 256)
    if (h[i]) atomicAdd(&hist[i], h[i]);
}

// Parallel median + gamma: 256 threads x 8 bins, LDS scan.
__global__ void k_gamma_r16(const unsigned int* __restrict__ hist,
                            const float* __restrict__ ssum, float* __restrict__ gptr) {
  __shared__ unsigned int ps[256];
  __shared__ float v0s, v1s;
  int t = threadIdx.x;
  unsigned int mine[8];
  unsigned int c = 0;
#pragma unroll
  for (int j = 0; j < 8; ++j) { mine[j] = hist[t * 8 + j]; c += mine[j]; }
  ps[t] = c;
  __syncthreads();
  // Hillis-Steele inclusive scan
  for (int off = 1; off < 256; off <<= 1) {
    unsigned int v = (t >= off) ? ps[t - off] : 0u;
    __syncthreads();
    ps[t] += v;
    __syncthreads();
  }
  unsigned int total = ps[255];
  unsigned int before = ps[t] - c;      // exclusive prefix for my 8 bins
  if (t == 0) { v0s = 0.f; v1s = 0.f; }
  __syncthreads();
  unsigned int rr0 = (total - 1) / 2, rr1 = total / 2;
  unsigned int cum = before;
#pragma unroll
  for (int j = 0; j < 8; ++j) {
    unsigned int cc = mine[j];
    if (cc > 0) {
      int bin = t * 8 + j;
      if (cum <= rr0 && rr0 < cum + cc) {
        float frac = (float)(rr0 - cum) + 0.5f;
        v0s = ((float)bin + frac / (float)cc) * 0.5f;
      }
      if (cum <= rr1 && rr1 < cum + cc) {
        float frac = (float)(rr1 - cum) + 0.5f;
        v1s = ((float)bin + frac / (float)cc) * 0.5f;
      }
    }
    cum += cc;
  }
  __syncthreads();
  if (t == 0) {
    float med = 0.5f * (v0s + v1s);
    float mean = (total > 0) ? (ssum[0] / (float)total) : 1.0f;
    float g = (med > 0.f) ? 1.0f / (med + 1e-6f) : 1.0f / (mean + 1e-6f);
    gptr[0] = g;
  }
}

// MAIN (MFMA, swizzled operands, LDS-staged B): grid (128 q-tiles, 16 s-chunks).
__global__ void PrototypicalHead_6210522710389_kernel(
    const unsigned short* __restrict__ Gh, const unsigned short* __restrict__ Sh,
    const float* __restrict__ q2p, const float* __restrict__ s2,
    const float* __restrict__ svals, const float* __restrict__ gptr,
    float* __restrict__ part) {
  __shared__ unsigned short Bs[16384];   // 32 KB -> 5 blocks/CU
  int t = threadIdx.x;
  int w = t >> 6, lane = t & 63;
  int l15 = lane & 15, quad = lane >> 4;
  int qt = blockIdx.x, sc = blockIdx.y;
  int qbase = qt * 64;
  float gamma = gptr[0];
  const float LOG2E = 1.44269504f;
  float c2 = 2.0f * gamma * LOG2E;       // exp2 folding: e^{-g*d2} = 2^{c2*a + cq + cs}

  size_t agrp = (size_t)(qt * 4 + w) * 4096;
  bf16x8 afrag[8];
#pragma unroll
  for (int ks = 0; ks < 8; ++ks)
    afrag[ks] = *(const bf16x8*)&Gh[agrp + (size_t)ks * 512 + (size_t)lane * 8];

  float cqv[4];
#pragma unroll
  for (int r = 0; r < 4; ++r)
    cqv[r] = -gamma * LOG2E * q2p[qbase + w * 16 + quad * 4 + r];

  float dAcc[4] = {0.f, 0.f, 0.f, 0.f}, nAcc[4] = {0.f, 0.f, 0.f, 0.f};

  for (int st = 0; st < 16; ++st) {
    int sbase = sc * 1024 + st * 64;
    const char* src = (const char*)&Sh[(size_t)(sbase >> 4) * 4096];
    __syncthreads();   // previous tile's LDS reads done before overwrite
#pragma unroll
    for (int i = 0; i < 8; ++i) {
      int c = i * 256 + t;               // 2048 chunks x 16 B = 32 KB, linear
      gload_lds16(src + (size_t)c * 16, (char*)Bs + (size_t)c * 16);
    }
    __syncthreads();   // drains vmcnt -> LDS tile ready

    f32x4 acc0 = {0.f, 0.f, 0.f, 0.f};
    f32x4 acc1 = {0.f, 0.f, 0.f, 0.f};
    f32x4 acc2 = {0.f, 0.f, 0.f, 0.f};
    f32x4 acc3 = {0.f, 0.f, 0.f, 0.f};
    const unsigned short* B0 = &Bs[lane * 8];
#pragma unroll
    for (int ks = 0; ks < 8; ++ks) {
      bf16x8 f0 = *(const bf16x8*)(B0 + ks * 512);
      bf16x8 f1 = *(const bf16x8*)(B0 + 4096 + ks * 512);
      bf16x8 f2 = *(const bf16x8*)(B0 + 8192 + ks * 512);
      bf16x8 f3 = *(const bf16x8*)(B0 + 12288 + ks * 512);
      acc0 = __builtin_amdgcn_mfma_f32_16x16x32_bf16(afrag[ks], f0, acc0, 0, 0, 0);
      acc1 = __builtin_amdgcn_mfma_f32_16x16x32_bf16(afrag[ks], f1, acc1, 0, 0, 0);
      acc2 = __builtin_amdgcn_mfma_f32_16x16x32_bf16(afrag[ks], f2, acc2, 0, 0, 0);
      acc3 = __builtin_amdgcn_mfma_f32_16x16x32_bf16(afrag[ks], f3, acc3, 0, 0, 0);
    }
#pragma unroll
    for (int nt = 0; nt < 4; ++nt) {
      f32x4 a = (nt == 0) ? acc0 : (nt == 1) ? acc1 : (nt == 2) ? acc2 : acc3;
      int scol = sbase + nt * 16 + l15;
      float cs = -gamma * LOG2E * s2[scol];
      float sv = svals[scol];
#pragma unroll
      for (int r = 0; r < 4; ++r) {
        // exponent = log2e * -(gamma*(q2+s2-2a)); min(...,0) == the d2>=0 clamp
        float ex = exp2f(fminf(fmaf(c2, a[r], cqv[r] + cs), 0.0f));
        dAcc[r] += ex;
        nAcc[r] = fmaf(ex, sv, nAcc[r]);
      }
    }
  }
#pragma unroll
  for (int off = 8; off >= 1; off >>= 1) {
#pragma unroll
    for (int r = 0; r < 4; ++r) {
      dAcc[r] += __shfl_xor(dAcc[r], off);
      nAcc[r] += __shfl_xor(nAcc[r], off);
    }
  }
  if (l15 == 0) {
#pragma unroll
    for (int r = 0; r < 4; ++r) {
      size_t q = (size_t)qbase + w * 16 + quad * 4 + r;
      part[(q * 16 + sc) * 2 + 0] = dAcc[r];
      part[(q * 16 + sc) * 2 + 1] = nAcc[r];
    }
  }
}

__global__ void k_final_r16(const float* __restrict__ part, float* __restrict__ out1) {
  int q = blockIdx.x * 256 + threadIdx.x;
  const float* p = part + (size_t)q * 32;
  float d = 0.f, n = 0.f;
#pragma unroll
  for (int i = 0; i < 16; ++i) { d += p[2 * i]; n += p[2 * i + 1]; }
  out1[q] = n / d;
}

extern "C" void kernel_launch(void* const* d_in, const int* in_sizes, int n_in,
                              void* d_out, int out_size, void* d_ws, size_t ws_size,
                              hipStream_t stream) {
  (void)in_sizes; (void)n_in; (void)out_size; (void)ws_size;
  const float* SF = (const float*)d_in[0];   // fp32
  const int*   SL = (const int*)d_in[1];     // int32
  const float* SV = (const float*)d_in[2];   // fp32
  const float* QF = (const float*)d_in[3];   // fp32

  float* ws = (float*)d_ws;
  float* rnorm = ws + OFF_PSUM;              // r19: 16384 row inv-norms
  float* musum = ws + OFF_MUSUM;
  float* xtx   = ws + OFF_XTX;
  unsigned int* hist = (unsigned int*)(ws + OFF_HIST);
  float* ssum  = ws + OFF_SSUM;
  float* protos= ws + OFF_PROTO;
  float* mu    = ws + OFF_MU;
  float* cov   = ws + OFF_COV;
  float* rows  = ws + OFF_ROWS;
  float* cptr  = ws + OFF_C;
  float* gptr  = ws + OFF_C + 1;
  float* X1 = ws + OFF_Y;  float* T = ws + OFF_T;  float* X2 = ws + OFF_Y2;
  float* s2 = ws + OFF_S2; float* q2p = ws + OFF_Q2P;
  float* part = ws + OFF_PART;
  float* G = ws + OFF_G;
  unsigned short* Sh = (unsigned short*)(ws + OFF_SH);
  unsigned short* Gh = (unsigned short*)(ws + OFF_GH);
  // r19 proto-phase aliases (lifetimes end before G / part are written):
  float* pppart  = G;                        // 128*64*256 = 2,097,152 floats
  float* cntpart = part;                     // 128*64 floats

  float* out0 = (float*)d_out;                   // f32 log_probs [8192 x 64]
  float* out1 = out0 + (size_t)kNQ * kC;         // f32 predictions [8192]

  k_zero_r16<<<(int)((ZERO_FLOATS + 255) / 256), 256, 0, stream>>>(ws);

  // swizzled bf16 copy of support features
  k_swz_r16<<<kNS / 16, 256, 0, stream>>>(SF, Sh);

  // classification (R19 atomic-free)
  k_rnorm_r19<<<kNS / 4, 256, 0, stream>>>(SF, rnorm);
  k_paccum_r19<<<128, 256, 0, stream>>>(SF, SL, rnorm, pppart, cntpart);
  k_proto_fin_r19<<<kC, 256, 0, stream>>>(pppart, cntpart, protos);
  k_logits_r16<<<kNQ, 256, 0, stream>>>(QF, protos, out0);

  // regression: mean, cov
  k_colsum_r16<<<kNS / 64, 256, 0, stream>>>(SF, musum);
  k_mufin_r16<<<1, 256, 0, stream>>>(musum, mu);
  k_xtx_r16<<<dim3(16, 16), 256, 0, stream>>>(SF, xtx);
  k_cov_r16<<<256, 256, 0, stream>>>(xtx, mu, cov);

  // Newton matrix inverse: X <- X (2I - cov X), X0 = I/c, 6 iterations
  k_rowabs_r16<<<256, 64, 0, stream>>>(cov, rows);
  k_cnorm_r16<<<1, 64, 0, stream>>>(rows, cptr);
  k_newt_init_r16<<<256, 256, 0, stream>>>(cptr, X1);
  float *Xc = X1, *T_ = T, *Xn = X2;
  for (int it = 0; it < 6; ++it) {
    k_newt_mm_r17<<<256, 1024, 0, stream>>>(cov, Xc, T_, 1);
    k_newt_mm_r17<<<256, 1024, 0, stream>>>(Xc, T_, Xn, 0);
    float* tmp = Xc; Xc = Xn; Xn = tmp;
  }
  float* M = Xc;   // cov^-1

  // G = (Q - mu) @ M, swizzled bf16 copy, scalar row terms
  k_G_r16<<<dim3(4, kNQ / 64), 256, 0, stream>>>(QF, mu, M, G);
  k_swz_r16<<<kNQ / 16, 256, 0, stream>>>(G, Gh);
  k_q2p_r16<<<kNQ / 4, 256, 0, stream>>>(G, QF, mu, q2p);
  k_s2_r16<<<kNS / 64, 256, 0, stream>>>(SF, mu, M, s2);

  // sampled median -> gamma (parallel)
  k_median_r16<<<dim3(32, 16), 256, 0, stream>>>(G, SF, q2p, s2, hist, ssum);
  k_gamma_r16<<<1, 256, 0, stream>>>(hist, ssum, gptr);

  // MFMA fused cdist^2 + softmax numer/denom, then finalize
  PrototypicalHead_6210522710389_kernel<<<dim3(128, 16), 256, 0, stream>>>(
      Gh, Sh, q2p, s2, SV, gptr, part);
  k_final_r16<<<kNQ / 256, 256, 0, stream>>>(part, out1);
}

// Round 4
// 530.412 us; speedup vs baseline: 1.4149x; 1.0189x over previous
//
#include <hip/hip_runtime.h>
#include <hip/hip_bf16.h>

// Problem dims (fixed by setup_inputs)
constexpr int kNS = 16384;   // support rows
constexpr int kNQ = 8192;    // query rows
constexpr int kD  = 256;     // feature dim
constexpr int kC  = 64;      // classes

// R19 PASSED (540 us, main 104 us: MfmaUtil 29%, VALUBusy 55%).
// Pipe math: MFMA 33 us, LDS-read 55 us (each wave reads the whole 32 KB
// B-tile; ds_read:MFMA = 1:1). R20: 32 q-rows per wave (2 A-frag sets,
// block = 128 rows, grid qt 128->64) -> each ds_read feeds 2 MFMAs, LDS
// traffic halves (4.19 GB -> 2.1 GB ~= 27 us < 33 us MFMA floor).

// ---------------- workspace layout (float offsets into d_ws), ~24.4 MB ----
constexpr size_t OFF_PSUM  = 0;          // r19: rnorm[16384]
constexpr size_t OFF_PCNT  = 16384;
constexpr size_t OFF_MUSUM = 16448;
constexpr size_t OFF_XTX   = 16704;
constexpr size_t OFF_HIST  = 82240;
constexpr size_t OFF_SSUM  = 84288;
constexpr size_t ZERO_FLOATS = 84352;
constexpr size_t OFF_PROTO = 84352;
constexpr size_t OFF_MU    = 100736;
constexpr size_t OFF_COV   = 100992;
constexpr size_t OFF_ROWS  = 166528;
constexpr size_t OFF_C     = 166784;
constexpr size_t OFF_Y     = 166800;     // Newton X ping
constexpr size_t OFF_T     = 297872;     // Newton T
constexpr size_t OFF_Y2    = 363408;     // Newton X pong
constexpr size_t OFF_S2    = 560016;
constexpr size_t OFF_Q2P   = 576400;
constexpr size_t OFF_PART  = 584592;     // r19: also cntpart[128*64] (proto phase)
constexpr size_t OFF_G     = 846736;     // 8192*256 f32; r19: also proto partials
constexpr size_t OFF_SH    = 2943888;    // 16384*256 bf16 swizzled
constexpr size_t OFF_GH    = 5041040;    // 8192*256 bf16 swizzled

typedef __attribute__((ext_vector_type(8))) short bf16x8;
typedef __attribute__((ext_vector_type(4))) float f32x4;

__device__ __forceinline__ unsigned short f2bf(float f) {
  unsigned int w; __builtin_memcpy(&w, &f, 4);
  unsigned int r = (w + 0x7FFFu + ((w >> 16) & 1u)) >> 16;
  return (unsigned short)r;
}

__device__ __forceinline__ float waveReduceSum(float v) {
#pragma unroll
  for (int off = 32; off > 0; off >>= 1) v += __shfl_xor(v, off);
  return v;
}
__device__ __forceinline__ float waveReduceMax(float v) {
#pragma unroll
  for (int off = 32; off > 0; off >>= 1) v = fmaxf(v, __shfl_xor(v, off));
  return v;
}
__device__ __forceinline__ void fma16(float acc[4][4], float4 a, float4 b) {
  acc[0][0] += a.x*b.x; acc[0][1] += a.x*b.y; acc[0][2] += a.x*b.z; acc[0][3] += a.x*b.w;
  acc[1][0] += a.y*b.x; acc[1][1] += a.y*b.y; acc[1][2] += a.y*b.z; acc[1][3] += a.y*b.w;
  acc[2][0] += a.z*b.x; acc[2][1] += a.z*b.y; acc[2][2] += a.z*b.z; acc[2][3] += a.z*b.w;
  acc[3][0] += a.w*b.x; acc[3][1] += a.w*b.y; acc[3][2] += a.w*b.z; acc[3][3] += a.w*b.w;
}

// async global -> LDS, 16 B per lane
__device__ __forceinline__ void gload_lds16(const void* g, void* l) {
  __builtin_amdgcn_global_load_lds(
      (const __attribute__((address_space(1))) unsigned int*)g,
      (__attribute__((address_space(3))) unsigned int*)l, 16, 0, 0);
}

__global__ void k_zero_r16(float* __restrict__ ws) {
  size_t i = (size_t)blockIdx.x * 256 + threadIdx.x;
  if (i < ZERO_FLOATS) ws[i] = 0.f;
}

// f32 [rows x 256] -> bf16 fragment-major swizzle (one block per 16-row group)
__global__ void k_swz_r16(const float* __restrict__ in, unsigned short* __restrict__ out) {
  int g = blockIdx.x, t = threadIdx.x;
  int ks = t >> 5;
  size_t gbase = (size_t)g * 4096;
#pragma unroll
  for (int f = 0; f < 2; ++f) {
    int lane = (2 * t + f) & 63;
    int q = lane >> 4, r = lane & 15;
    const float* src = &in[(size_t)(g * 16 + r) * kD + ks * 32 + q * 8];
    float4 v0 = *(const float4*)src;
    float4 v1 = *(const float4*)(src + 4);
    ushort4 o0, o1;
    o0.x = f2bf(v0.x); o0.y = f2bf(v0.y); o0.z = f2bf(v0.z); o0.w = f2bf(v0.w);
    o1.x = f2bf(v1.x); o1.y = f2bf(v1.y); o1.z = f2bf(v1.z); o1.w = f2bf(v1.w);
    unsigned short* dst = &out[gbase + (size_t)ks * 512 + (size_t)lane * 8];
    *(ushort4*)dst = o0;
    *(ushort4*)(dst + 4) = o1;
  }
}

// ---------------- classification path (atomic-free) ----------------
// wave per row: rnorm[i] = 1 / max(||X_i||, 1e-8)
__global__ void k_rnorm_r19(const float* __restrict__ X, float* __restrict__ rnorm) {
  int w = threadIdx.x >> 6, lane = threadIdx.x & 63;
  int row = blockIdx.x * 4 + w;
  float4 v = *(const float4*)&X[(size_t)row * kD + lane * 4];
  float ss = waveReduceSum(v.x*v.x + v.y*v.y + v.z*v.z + v.w*v.w);
  if (lane == 0) rnorm[row] = 1.0f / fmaxf(sqrtf(ss), 1e-8f);
}

// thread t owns dim t; LDS acc[64][256], no atomics. 128 blocks x 128 rows.
__global__ void k_paccum_r19(const float* __restrict__ X, const int* __restrict__ lab,
                             const float* __restrict__ rnorm,
                             float* __restrict__ partial, float* __restrict__ cntpart) {
  __shared__ float acc[kC * kD];   // 64 KB
  int t = threadIdx.x, b = blockIdx.x;
  for (int i = t; i < kC * kD; i += 256) acc[i] = 0.f;
  __syncthreads();
  int r0 = b * 128;
  float myCnt = 0.f;
  for (int r = 0; r < 128; r += 8) {
    int row = r0 + r;
    int   c0 = lab[row + 0], c1 = lab[row + 1], c2 = lab[row + 2], c3 = lab[row + 3];
    int   c4 = lab[row + 4], c5 = lab[row + 5], c6 = lab[row + 6], c7 = lab[row + 7];
    float n0 = rnorm[row + 0], n1 = rnorm[row + 1], n2 = rnorm[row + 2], n3 = rnorm[row + 3];
    float n4 = rnorm[row + 4], n5 = rnorm[row + 5], n6 = rnorm[row + 6], n7 = rnorm[row + 7];
    float x0 = X[(size_t)(row + 0) * kD + t];
    float x1 = X[(size_t)(row + 1) * kD + t];
    float x2 = X[(size_t)(row + 2) * kD + t];
    float x3 = X[(size_t)(row + 3) * kD + t];
    float x4 = X[(size_t)(row + 4) * kD + t];
    float x5 = X[(size_t)(row + 5) * kD + t];
    float x6 = X[(size_t)(row + 6) * kD + t];
    float x7 = X[(size_t)(row + 7) * kD + t];
    acc[c0 * kD + t] += x0 * n0;
    acc[c1 * kD + t] += x1 * n1;
    acc[c2 * kD + t] += x2 * n2;
    acc[c3 * kD + t] += x3 * n3;
    acc[c4 * kD + t] += x4 * n4;
    acc[c5 * kD + t] += x5 * n5;
    acc[c6 * kD + t] += x6 * n6;
    acc[c7 * kD + t] += x7 * n7;
    myCnt += (t == c0) ? 1.f : 0.f; myCnt += (t == c1) ? 1.f : 0.f;
    myCnt += (t == c2) ? 1.f : 0.f; myCnt += (t == c3) ? 1.f : 0.f;
    myCnt += (t == c4) ? 1.f : 0.f; myCnt += (t == c5) ? 1.f : 0.f;
    myCnt += (t == c6) ? 1.f : 0.f; myCnt += (t == c7) ? 1.f : 0.f;
  }
  __syncthreads();
  float* pb = partial + (size_t)b * (kC * kD);
  for (int c = 0; c < kC; ++c) pb[c * kD + t] = acc[c * kD + t];
  if (t < kC) cntpart[b * kC + t] = myCnt;
}

// one block per class: reduce 128 partials, divide by count, L2-normalize
__global__ void k_proto_fin_r19(const float* __restrict__ partial,
                                const float* __restrict__ cntpart,
                                float* __restrict__ protos) {
  __shared__ float cs[128];
  __shared__ float wred[4];
  __shared__ float cntS, invS;
  int c = blockIdx.x, t = threadIdx.x;
  if (t < 128) cs[t] = cntpart[t * kC + c];
  __syncthreads();
  float s = 0.f;
  const float* p = partial + (size_t)c * kD + t;
  for (int b = 0; b < 128; ++b) s += p[(size_t)b * (kC * kD)];
  if (t < 64) {
    float cv = cs[t] + cs[t + 64];
    cv = waveReduceSum(cv);
    if (t == 0) cntS = fmaxf(cv, 1.0f);
  }
  __syncthreads();
  float v = s / cntS;
  float ss = waveReduceSum(v * v);
  if ((t & 63) == 0) wred[t >> 6] = ss;
  __syncthreads();
  if (t == 0) invS = 1.0f / fmaxf(sqrtf(wred[0] + wred[1] + wred[2] + wred[3]), 1e-8f);
  __syncthreads();
  protos[(size_t)c * kD + t] = v * invS;
}

__global__ void k_logits_r16(const float* __restrict__ Q, const float* __restrict__ protos,
                             float* __restrict__ out0) {
  __shared__ alignas(16) float qs[kD];
  __shared__ float lg[kC];
  __shared__ float wred[4];
  __shared__ float qis;
  int t = threadIdx.x, w = t >> 6, lane = t & 63;
  int qi = blockIdx.x;
  float myv = Q[(size_t)qi * kD + t];
  qs[t] = myv;
  float ss = waveReduceSum(myv * myv);
  if (lane == 0) wred[w] = ss;
  __syncthreads();
  if (t == 0) qis = 1.0f / fmaxf(sqrtf(wred[0] + wred[1] + wred[2] + wred[3]), 1e-8f);
  __syncthreads();
  float4 qv = *(const float4*)&qs[lane * 4];
  for (int cc = w * 16; cc < w * 16 + 16; ++cc) {
    float4 pv = *(const float4*)&protos[(size_t)cc * kD + lane * 4];
    float d = waveReduceSum(qv.x*pv.x + qv.y*pv.y + qv.z*pv.z + qv.w*pv.w);
    if (lane == 0) lg[cc] = d * qis;
  }
  __syncthreads();
  if (t < 64) {
    float v = lg[t];
    float m = waveReduceMax(v);
    float e = expf(v - m);
    float s = waveReduceSum(e);
    float lse = m + logf(s);
    out0[(size_t)qi * kC + t] = v - lse;
  }
}

// ---------------- regression path ----------------
__global__ void k_colsum_r16(const float* __restrict__ X, float* __restrict__ musum) {
  int t = threadIdx.x;
  int r0 = blockIdx.x * 64;
  float s = 0.f;
  for (int r = 0; r < 64; ++r) s += X[(size_t)(r0 + r) * kD + t];
  atomicAdd(&musum[t], s);
}
__global__ void k_mufin_r16(const float* __restrict__ musum, float* __restrict__ mu) {
  int t = threadIdx.x;
  mu[t] = musum[t] * (1.0f / (float)kNS);
}

__global__ void k_xtx_r16(const float* __restrict__ X, float* __restrict__ xtx) {
  __shared__ alignas(16) float As[16][68];
  __shared__ alignas(16) float Bs[16][68];
  int t = threadIdx.x, tx = t & 15, ty = t >> 4;
  int ab = (blockIdx.x >> 2) * 64, bb = (blockIdx.x & 3) * 64;
  int k0b = blockIdx.y * 1024;
  float acc[4][4] = {};
  for (int k0 = 0; k0 < 1024; k0 += 16) {
    __syncthreads();
    int j = t & 63, kr0 = t >> 6;
#pragma unroll
    for (int p = 0; p < 4; ++p) {
      int kr = kr0 + p * 4;
      size_t base = (size_t)(k0b + k0 + kr) * kD;
      As[kr][j] = X[base + ab + j];
      Bs[kr][j] = X[base + bb + j];
    }
    __syncthreads();
#pragma unroll
    for (int k = 0; k < 16; ++k) {
      float4 a = *(const float4*)&As[k][ty * 4];
      float4 b = *(const float4*)&Bs[k][tx * 4];
      fma16(acc, a, b);
    }
  }
#pragma unroll
  for (int r = 0; r < 4; ++r)
#pragma unroll
    for (int c = 0; c < 4; ++c)
      atomicAdd(&xtx[(size_t)(ab + ty * 4 + r) * kD + bb + tx * 4 + c], acc[r][c]);
}

__global__ void k_cov_r16(const float* __restrict__ xtx, const float* __restrict__ mu,
                          float* __restrict__ cov) {
  int i = blockIdx.x, j = threadIdx.x;
  float v = (xtx[(size_t)i * kD + j] - (float)kNS * mu[i] * mu[j]) * (1.0f / (float)(kNS - 1));
  if (i == j) v += 1e-4f;
  cov[(size_t)i * kD + j] = v;
}

__global__ void k_rowabs_r16(const float* __restrict__ cov, float* __restrict__ rows) {
  int row = blockIdx.x, lane = threadIdx.x;
  float4 v = *(const float4*)&cov[(size_t)row * kD + lane * 4];
  float s = waveReduceSum(fabsf(v.x) + fabsf(v.y) + fabsf(v.z) + fabsf(v.w));
  if (lane == 0) rows[row] = s;
}
__global__ void k_cnorm_r16(const float* __restrict__ rows, float* __restrict__ cptr) {
  int lane = threadIdx.x;
  float m = fmaxf(fmaxf(rows[lane], rows[lane + 64]),
                  fmaxf(rows[lane + 128], rows[lane + 192]));
  m = waveReduceMax(m);
  if (lane == 0) cptr[0] = m;
}
// X0 = I / c
__global__ void k_newt_init_r16(const float* __restrict__ cptr, float* __restrict__ X) {
  int i = blockIdx.x, j = threadIdx.x;
  X[(size_t)i * kD + j] = (i == j) ? (1.0f / cptr[0]) : 0.0f;
}

// one 256x256 matmul step, 1024 threads (4-way split-k + LDS reduce).
// isT=1: Out = 2I - A @ Xin.  isT=0: Out = A @ Xin  (A indexed by row).
__global__ void __launch_bounds__(1024)
k_newt_mm_r17(const float* __restrict__ A, const float* __restrict__ Xin,
              float* __restrict__ Out, int isT) {
  __shared__ float a_s[256];
  __shared__ float red[3][256];
  int i = blockIdx.x, t = threadIdx.x;
  int j = t & 255, kq = t >> 8;
  if (t < 256) a_s[t] = A[(size_t)i * kD + t];
  __syncthreads();
  int k0 = kq * 64;
  const float* Xp = &Xin[(size_t)k0 * kD + j];
  float s0 = 0.f, s1 = 0.f, s2 = 0.f, s3 = 0.f;
#pragma unroll 4
  for (int k = 0; k < 64; k += 4) {
    s0 = fmaf(a_s[k0 + k + 0], Xp[0 * kD], s0);
    s1 = fmaf(a_s[k0 + k + 1], Xp[1 * kD], s1);
    s2 = fmaf(a_s[k0 + k + 2], Xp[2 * kD], s2);
    s3 = fmaf(a_s[k0 + k + 3], Xp[3 * kD], s3);
    Xp += 4 * kD;
  }
  float s = (s0 + s1) + (s2 + s3);
  if (kq) red[kq - 1][j] = s;
  __syncthreads();
  if (t < 256) {
    float tot = s + red[0][j] + red[1][j] + red[2][j];
    float o = isT ? ((i == j ? 2.0f : 0.0f) - tot) : tot;
    Out[(size_t)i * kD + j] = o;
  }
}

// G = (Q - mu) @ M
__global__ void k_G_r16(const float* __restrict__ Q, const float* __restrict__ mu,
                        const float* __restrict__ M, float* __restrict__ G) {
  __shared__ alignas(16) float As[16][68];
  __shared__ alignas(16) float Bs[16][68];
  int t = threadIdx.x, tx = t & 15, ty = t >> 4;
  int nb = blockIdx.x * 64;
  int mb = blockIdx.y * 64;
  float acc[4][4] = {};
  for (int k0 = 0; k0 < 256; k0 += 16) {
    __syncthreads();
    {
      int kk = t & 15, m0 = t >> 4;
      float muk = mu[k0 + kk];
#pragma unroll
      for (int p = 0; p < 4; ++p) {
        int m = m0 + p * 16;
        As[kk][m] = Q[(size_t)(mb + m) * kD + k0 + kk] - muk;
      }
      int j = t & 63, kr0 = t >> 6;
#pragma unroll
      for (int p = 0; p < 4; ++p) {
        int kr = kr0 + p * 4;
        Bs[kr][j] = M[(size_t)(k0 + kr) * kD + nb + j];
      }
    }
    __syncthreads();
#pragma unroll
    for (int k = 0; k < 16; ++k) {
      float4 a = *(const float4*)&As[k][ty * 4];
      float4 b = *(const float4*)&Bs[k][tx * 4];
      fma16(acc, a, b);
    }
  }
#pragma unroll
  for (int r = 0; r < 4; ++r) {
    int gi = mb + ty * 4 + r;
    float4 o = {acc[r][0], acc[r][1], acc[r][2], acc[r][3]};
    *(float4*)&G[(size_t)gi * kD + nb + tx * 4] = o;
  }
}

// q2p[i] = G_i . (Q_i + mu)
__global__ void k_q2p_r16(const float* __restrict__ G, const float* __restrict__ Q,
                          const float* __restrict__ mu, float* __restrict__ q2p) {
  int w = threadIdx.x >> 6, lane = threadIdx.x & 63;
  int row = blockIdx.x * 4 + w;
  float4 g = *(const float4*)&G[(size_t)row * kD + lane * 4];
  float4 q = *(const float4*)&Q[(size_t)row * kD + lane * 4];
  float4 m = *(const float4*)&mu[lane * 4];
  float ss = waveReduceSum(g.x*(q.x+m.x) + g.y*(q.y+m.y) + g.z*(q.z+m.z) + g.w*(q.w+m.w));
  if (lane == 0) q2p[row] = ss;
}

// s2[j] = (S_j - mu) M (S_j - mu), per 64-row chunk
__global__ void k_s2_r16(const float* __restrict__ S, const float* __restrict__ mu,
                         const float* __restrict__ M, float* __restrict__ s2) {
  __shared__ alignas(16) float As[16][68];
  __shared__ alignas(16) float Bs[16][68];
  __shared__ float red[64][17];
  int t = threadIdx.x, tx = t & 15, ty = t >> 4;
  int mb = blockIdx.x * 64;
  float partial[4] = {0.f, 0.f, 0.f, 0.f};
  for (int ntile = 0; ntile < 4; ++ntile) {
    int nb = ntile * 64;
    float acc[4][4] = {};
    for (int k0 = 0; k0 < 256; k0 += 16) {
      __syncthreads();
      {
        int kk = t & 15, m0 = t >> 4;
        float muk = mu[k0 + kk];
#pragma unroll
        for (int p = 0; p < 4; ++p) {
          int m = m0 + p * 16;
          As[kk][m] = S[(size_t)(mb + m) * kD + k0 + kk] - muk;
        }
        int j = t & 63, kr0 = t >> 6;
#pragma unroll
        for (int p = 0; p < 4; ++p) {
          int kr = kr0 + p * 4;
          Bs[kr][j] = M[(size_t)(k0 + kr) * kD + nb + j];
        }
      }
      __syncthreads();
#pragma unroll
      for (int k = 0; k < 16; ++k) {
        float4 a = *(const float4*)&As[k][ty * 4];
        float4 b = *(const float4*)&Bs[k][tx * 4];
        fma16(acc, a, b);
      }
    }
#pragma unroll
    for (int r = 0; r < 4; ++r) {
      int gi = mb + ty * 4 + r;
#pragma unroll
      for (int c = 0; c < 4; ++c) {
        int gj = nb + tx * 4 + c;
        partial[r] += acc[r][c] * (S[(size_t)gi * kD + gj] - mu[gj]);
      }
    }
  }
  __syncthreads();
#pragma unroll
  for (int r = 0; r < 4; ++r) red[ty * 4 + r][tx] = partial[r];
  __syncthreads();
  if (t < 64) {
    float s = 0.f;
#pragma unroll
    for (int x = 0; x < 16; ++x) s += red[t][x];
    s2[mb + t] = s;
  }
}

// GEMM-tiled sampled-median histogram
__global__ void k_median_r16(const float* __restrict__ G, const float* __restrict__ S,
                             const float* __restrict__ q2p, const float* __restrict__ s2,
                             unsigned int* __restrict__ hist, float* __restrict__ ssum) {
  __shared__ alignas(16) float As[16][68];
  __shared__ alignas(16) float Bs[16][68];
  __shared__ unsigned int h[2048];
  __shared__ float fred[4];
  int t = threadIdx.x, tx = t & 15, ty = t >> 4;
  int stile = blockIdx.x, qtile = blockIdx.y;
  for (int i = t; i < 2048; i += 256) h[i] = 0u;

  float acc[4][4] = {};
  for (int k0 = 0; k0 < 256; k0 += 16) {
    __syncthreads();
    {
      int kk = t & 15, m0 = t >> 4;
#pragma unroll
      for (int p = 0; p < 4; ++p) {
        int m = m0 + p * 16;
        As[kk][m] = G[(size_t)((qtile * 64 + m) * 8) * kD + k0 + kk];
        Bs[kk][m] = S[(size_t)((stile * 64 + m) * 8) * kD + k0 + kk];
      }
    }
    __syncthreads();
#pragma unroll
    for (int k = 0; k < 16; ++k) {
      float4 a = *(const float4*)&As[k][ty * 4];
      float4 b = *(const float4*)&Bs[k][tx * 4];
      fma16(acc, a, b);
    }
  }
  float fsum = 0.f;
#pragma unroll
  for (int r = 0; r < 4; ++r) {
    int qi = (qtile * 64 + ty * 4 + r) * 8;
    float q2v = q2p[qi];
#pragma unroll
    for (int c = 0; c < 4; ++c) {
      int sj = (stile * 64 + tx * 4 + c) * 8;
      float d2 = fmaxf(q2v + s2[sj] - 2.0f * acc[r][c], 0.0f);
      fsum += d2;
      int bin = (int)(d2 * 2.0f);
      bin = bin > 2047 ? 2047 : bin;
      atomicAdd(&h[bin], 1u);
    }
  }
  float wsum = waveReduceSum(fsum);
  if ((t & 63) == 0) fred[t >> 6] = wsum;
  __syncthreads();
  if (t == 0) atomicAdd(ssum, fred[0] + fred[1] + fred[2] + fred[3]);
  for (int i = t; i < 2048; i += 256)
    if (h[i]) atomicAdd(&hist[i], h[i]);
}

// Parallel median + gamma: 256 threads x 8 bins, LDS scan.
__global__ void k_gamma_r16(const unsigned int* __restrict__ hist,
                            const float* __restrict__ ssum, float* __restrict__ gptr) {
  __shared__ unsigned int ps[256];
  __shared__ float v0s, v1s;
  int t = threadIdx.x;
  unsigned int mine[8];
  unsigned int c = 0;
#pragma unroll
  for (int j = 0; j < 8; ++j) { mine[j] = hist[t * 8 + j]; c += mine[j]; }
  ps[t] = c;
  __syncthreads();
  // Hillis-Steele inclusive scan
  for (int off = 1; off < 256; off <<= 1) {
    unsigned int v = (t >= off) ? ps[t - off] : 0u;
    __syncthreads();
    ps[t] += v;
    __syncthreads();
  }
  unsigned int total = ps[255];
  unsigned int before = ps[t] - c;      // exclusive prefix for my 8 bins
  if (t == 0) { v0s = 0.f; v1s = 0.f; }
  __syncthreads();
  unsigned int rr0 = (total - 1) / 2, rr1 = total / 2;
  unsigned int cum = before;
#pragma unroll
  for (int j = 0; j < 8; ++j) {
    unsigned int cc = mine[j];
    if (cc > 0) {
      int bin = t * 8 + j;
      if (cum <= rr0 && rr0 < cum + cc) {
        float frac = (float)(rr0 - cum) + 0.5f;
        v0s = ((float)bin + frac / (float)cc) * 0.5f;
      }
      if (cum <= rr1 && rr1 < cum + cc) {
        float frac = (float)(rr1 - cum) + 0.5f;
        v1s = ((float)bin + frac / (float)cc) * 0.5f;
      }
    }
    cum += cc;
  }
  __syncthreads();
  if (t == 0) {
    float med = 0.5f * (v0s + v1s);
    float mean = (total > 0) ? (ssum[0] / (float)total) : 1.0f;
    float g = (med > 0.f) ? 1.0f / (med + 1e-6f) : 1.0f / (mean + 1e-6f);
    gptr[0] = g;
  }
}

// MAIN (MFMA, swizzled operands, LDS-staged B, R20: 32 q-rows/wave):
// grid (64 q-tiles of 128 rows, 16 s-chunks). Each ds_read_b128 feeds 2 MFMAs.
__global__ void __launch_bounds__(256, 3)
PrototypicalHead_6210522710389_kernel(
    const unsigned short* __restrict__ Gh, const unsigned short* __restrict__ Sh,
    const float* __restrict__ q2p, const float* __restrict__ s2,
    const float* __restrict__ svals, const float* __restrict__ gptr,
    float* __restrict__ part) {
  __shared__ unsigned short Bs[16384];   // 32 KB
  int t = threadIdx.x;
  int w = t >> 6, lane = t & 63;
  int l15 = lane & 15, quad = lane >> 4;
  int qt = blockIdx.x, sc = blockIdx.y;
  int qbase = qt * 128;
  float gamma = gptr[0];
  const float LOG2E = 1.44269504f;
  float c2 = 2.0f * gamma * LOG2E;       // exp2 folding: e^{-g*d2} = 2^{c2*a + cq + cs}

  // two A-fragment sets: rows [w*32, w*32+16) and [w*32+16, w*32+32)
  size_t agrp = (size_t)(qt * 8 + w * 2) * 4096;
  bf16x8 afrag[2][8];
#pragma unroll
  for (int s = 0; s < 2; ++s)
#pragma unroll
    for (int ks = 0; ks < 8; ++ks)
      afrag[s][ks] = *(const bf16x8*)&Gh[agrp + (size_t)s * 4096 + (size_t)ks * 512 + (size_t)lane * 8];

  float cqv[2][4];
#pragma unroll
  for (int s = 0; s < 2; ++s)
#pragma unroll
    for (int r = 0; r < 4; ++r)
      cqv[s][r] = -gamma * LOG2E * q2p[qbase + w * 32 + s * 16 + quad * 4 + r];

  float dAcc[2][4] = {}, nAcc[2][4] = {};

  for (int st = 0; st < 16; ++st) {
    int sbase = sc * 1024 + st * 64;
    const char* src = (const char*)&Sh[(size_t)(sbase >> 4) * 4096];
    __syncthreads();   // previous tile's LDS reads done before overwrite
#pragma unroll
    for (int i = 0; i < 8; ++i) {
      int c = i * 256 + t;               // 2048 chunks x 16 B = 32 KB, linear
      gload_lds16(src + (size_t)c * 16, (char*)Bs + (size_t)c * 16);
    }
    __syncthreads();   // drains vmcnt -> LDS tile ready

    f32x4 acc[2][4];
#pragma unroll
    for (int s = 0; s < 2; ++s)
#pragma unroll
      for (int nt = 0; nt < 4; ++nt)
        acc[s][nt] = (f32x4){0.f, 0.f, 0.f, 0.f};

    const unsigned short* B0 = &Bs[lane * 8];
#pragma unroll
    for (int ks = 0; ks < 8; ++ks) {
      bf16x8 f0 = *(const bf16x8*)(B0 + ks * 512);
      bf16x8 f1 = *(const bf16x8*)(B0 + 4096 + ks * 512);
      bf16x8 f2 = *(const bf16x8*)(B0 + 8192 + ks * 512);
      bf16x8 f3 = *(const bf16x8*)(B0 + 12288 + ks * 512);
      acc[0][0] = __builtin_amdgcn_mfma_f32_16x16x32_bf16(afrag[0][ks], f0, acc[0][0], 0, 0, 0);
      acc[1][0] = __builtin_amdgcn_mfma_f32_16x16x32_bf16(afrag[1][ks], f0, acc[1][0], 0, 0, 0);
      acc[0][1] = __builtin_amdgcn_mfma_f32_16x16x32_bf16(afrag[0][ks], f1, acc[0][1], 0, 0, 0);
      acc[1][1] = __builtin_amdgcn_mfma_f32_16x16x32_bf16(afrag[1][ks], f1, acc[1][1], 0, 0, 0);
      acc[0][2] = __builtin_amdgcn_mfma_f32_16x16x32_bf16(afrag[0][ks], f2, acc[0][2], 0, 0, 0);
      acc[1][2] = __builtin_amdgcn_mfma_f32_16x16x32_bf16(afrag[1][ks], f2, acc[1][2], 0, 0, 0);
      acc[0][3] = __builtin_amdgcn_mfma_f32_16x16x32_bf16(afrag[0][ks], f3, acc[0][3], 0, 0, 0);
      acc[1][3] = __builtin_amdgcn_mfma_f32_16x16x32_bf16(afrag[1][ks], f3, acc[1][3], 0, 0, 0);
    }
#pragma unroll
    for (int nt = 0; nt < 4; ++nt) {
      int scol = sbase + nt * 16 + l15;
      float cs = -gamma * LOG2E * s2[scol];
      float sv = svals[scol];
#pragma unroll
      for (int s = 0; s < 2; ++s)
#pragma unroll
        for (int r = 0; r < 4; ++r) {
          // exponent = log2e * -(gamma*(q2+s2-2a)); min(...,0) == the d2>=0 clamp
          float ex = exp2f(fminf(fmaf(c2, acc[s][nt][r], cqv[s][r] + cs), 0.0f));
          dAcc[s][r] += ex;
          nAcc[s][r] = fmaf(ex, sv, nAcc[s][r]);
        }
    }
  }
#pragma unroll
  for (int off = 8; off >= 1; off >>= 1)
#pragma unroll
    for (int s = 0; s < 2; ++s)
#pragma unroll
      for (int r = 0; r < 4; ++r) {
        dAcc[s][r] += __shfl_xor(dAcc[s][r], off);
        nAcc[s][r] += __shfl_xor(nAcc[s][r], off);
      }
  if (l15 == 0) {
#pragma unroll
    for (int s = 0; s < 2; ++s)
#pragma unroll
      for (int r = 0; r < 4; ++r) {
        size_t q = (size_t)qbase + w * 32 + s * 16 + quad * 4 + r;
        part[(q * 16 + sc) * 2 + 0] = dAcc[s][r];
        part[(q * 16 + sc) * 2 + 1] = nAcc[s][r];
      }
  }
}

__global__ void k_final_r16(const float* __restrict__ part, float* __restrict__ out1) {
  int q = blockIdx.x * 256 + threadIdx.x;
  const float* p = part + (size_t)q * 32;
  float d = 0.f, n = 0.f;
#pragma unroll
  for (int i = 0; i < 16; ++i) { d += p[2 * i]; n += p[2 * i + 1]; }
  out1[q] = n / d;
}

extern "C" void kernel_launch(void* const* d_in, const int* in_sizes, int n_in,
                              void* d_out, int out_size, void* d_ws, size_t ws_size,
                              hipStream_t stream) {
  (void)in_sizes; (void)n_in; (void)out_size; (void)ws_size;
  const float* SF = (const float*)d_in[0];   // fp32
  const int*   SL = (const int*)d_in[1];     // int32
  const float* SV = (const float*)d_in[2];   // fp32
  const float* QF = (const float*)d_in[3];   // fp32

  float* ws = (float*)d_ws;
  float* rnorm = ws + OFF_PSUM;              // r19: 16384 row inv-norms
  float* musum = ws + OFF_MUSUM;
  float* xtx   = ws + OFF_XTX;
  unsigned int* hist = (unsigned int*)(ws + OFF_HIST);
  float* ssum  = ws + OFF_SSUM;
  float* protos= ws + OFF_PROTO;
  float* mu    = ws + OFF_MU;
  float* cov   = ws + OFF_COV;
  float* rows  = ws + OFF_ROWS;
  float* cptr  = ws + OFF_C;
  float* gptr  = ws + OFF_C + 1;
  float* X1 = ws + OFF_Y;  float* T = ws + OFF_T;  float* X2 = ws + OFF_Y2;
  float* s2 = ws + OFF_S2; float* q2p = ws + OFF_Q2P;
  float* part = ws + OFF_PART;
  float* G = ws + OFF_G;
  unsigned short* Sh = (unsigned short*)(ws + OFF_SH);
  unsigned short* Gh = (unsigned short*)(ws + OFF_GH);
  // r19 proto-phase aliases (lifetimes end before G / part are written):
  float* pppart  = G;                        // 128*64*256 = 2,097,152 floats
  float* cntpart = part;                     // 128*64 floats

  float* out0 = (float*)d_out;                   // f32 log_probs [8192 x 64]
  float* out1 = out0 + (size_t)kNQ * kC;         // f32 predictions [8192]

  k_zero_r16<<<(int)((ZERO_FLOATS + 255) / 256), 256, 0, stream>>>(ws);

  // swizzled bf16 copy of support features
  k_swz_r16<<<kNS / 16, 256, 0, stream>>>(SF, Sh);

  // classification (atomic-free)
  k_rnorm_r19<<<kNS / 4, 256, 0, stream>>>(SF, rnorm);
  k_paccum_r19<<<128, 256, 0, stream>>>(SF, SL, rnorm, pppart, cntpart);
  k_proto_fin_r19<<<kC, 256, 0, stream>>>(pppart, cntpart, protos);
  k_logits_r16<<<kNQ, 256, 0, stream>>>(QF, protos, out0);

  // regression: mean, cov
  k_colsum_r16<<<kNS / 64, 256, 0, stream>>>(SF, musum);
  k_mufin_r16<<<1, 256, 0, stream>>>(musum, mu);
  k_xtx_r16<<<dim3(16, 16), 256, 0, stream>>>(SF, xtx);
  k_cov_r16<<<256, 256, 0, stream>>>(xtx, mu, cov);

  // Newton matrix inverse: X <- X (2I - cov X), X0 = I/c, 6 iterations
  k_rowabs_r16<<<256, 64, 0, stream>>>(cov, rows);
  k_cnorm_r16<<<1, 64, 0, stream>>>(rows, cptr);
  k_newt_init_r16<<<256, 256, 0, stream>>>(cptr, X1);
  float *Xc = X1, *T_ = T, *Xn = X2;
  for (int it = 0; it < 6; ++it) {
    k_newt_mm_r17<<<256, 1024, 0, stream>>>(cov, Xc, T_, 1);
    k_newt_mm_r17<<<256, 1024, 0, stream>>>(Xc, T_, Xn, 0);
    float* tmp = Xc; Xc = Xn; Xn = tmp;
  }
  float* M = Xc;   // cov^-1

  // G = (Q - mu) @ M, swizzled bf16 copy, scalar row terms
  k_G_r16<<<dim3(4, kNQ / 64), 256, 0, stream>>>(QF, mu, M, G);
  k_swz_r16<<<kNQ / 16, 256, 0, stream>>>(G, Gh);
  k_q2p_r16<<<kNQ / 4, 256, 0, stream>>>(G, QF, mu, q2p);
  k_s2_r16<<<kNS / 64, 256, 0, stream>>>(SF, mu, M, s2);

  // sampled median -> gamma (parallel)
  k_median_r16<<<dim3(32, 16), 256, 0, stream>>>(G, SF, q2p, s2, hist, ssum);
  k_gamma_r16<<<1, 256, 0, stream>>>(hist, ssum, gptr);

  // MFMA fused cdist^2 + softmax numer/denom, then finalize
  PrototypicalHead_6210522710389_kernel<<<dim3(64, 16), 256, 0, stream>>>(
      Gh, Sh, q2p, s2, SV, gptr, part);
  k_final_r16<<<kNQ / 256, 256, 0, stream>>>(part, out1);
}

// Round 5
// 525.012 us; speedup vs baseline: 1.4295x; 1.0103x over previous
//
#include <hip/hip_runtime.h>
#include <hip/hip_bf16.h>

// Problem dims (fixed by setup_inputs)
constexpr int kNS = 16384;   // support rows
constexpr int kNQ = 8192;    // query rows
constexpr int kD  = 256;     // feature dim
constexpr int kC  = 64;      // classes

// R20 PASSED (530 us, main 97.8 us: MfmaUtil 29%, Occ 23%). Post-mortem:
// LDS-BW halving didn't pay — the serial stage->vmcnt(0)drain->compute
// structure is the critical path (2-phase-no-prefetch anti-pattern).
// R21: double-buffered prefetch: 32 tiles x 32 s-rows (2x16KB LDS), issue
// next tile's global_load_lds BEFORE computing current, ONE barrier/tile.
// Staging latency hides under 32 MFMAs + epilogue.

// ---------------- workspace layout (float offsets into d_ws), ~24.4 MB ----
constexpr size_t OFF_PSUM  = 0;          // r19: rnorm[16384]
constexpr size_t OFF_PCNT  = 16384;
constexpr size_t OFF_MUSUM = 16448;
constexpr size_t OFF_XTX   = 16704;
constexpr size_t OFF_HIST  = 82240;
constexpr size_t OFF_SSUM  = 84288;
constexpr size_t ZERO_FLOATS = 84352;
constexpr size_t OFF_PROTO = 84352;
constexpr size_t OFF_MU    = 100736;
constexpr size_t OFF_COV   = 100992;
constexpr size_t OFF_ROWS  = 166528;
constexpr size_t OFF_C     = 166784;
constexpr size_t OFF_Y     = 166800;     // Newton X ping
constexpr size_t OFF_T     = 297872;     // Newton T
constexpr size_t OFF_Y2    = 363408;     // Newton X pong
constexpr size_t OFF_S2    = 560016;
constexpr size_t OFF_Q2P   = 576400;
constexpr size_t OFF_PART  = 584592;     // r19: also cntpart[128*64] (proto phase)
constexpr size_t OFF_G     = 846736;     // 8192*256 f32; r19: also proto partials
constexpr size_t OFF_SH    = 2943888;    // 16384*256 bf16 swizzled
constexpr size_t OFF_GH    = 5041040;    // 8192*256 bf16 swizzled

typedef __attribute__((ext_vector_type(8))) short bf16x8;
typedef __attribute__((ext_vector_type(4))) float f32x4;

__device__ __forceinline__ unsigned short f2bf(float f) {
  unsigned int w; __builtin_memcpy(&w, &f, 4);
  unsigned int r = (w + 0x7FFFu + ((w >> 16) & 1u)) >> 16;
  return (unsigned short)r;
}

__device__ __forceinline__ float waveReduceSum(float v) {
#pragma unroll
  for (int off = 32; off > 0; off >>= 1) v += __shfl_xor(v, off);
  return v;
}
__device__ __forceinline__ float waveReduceMax(float v) {
#pragma unroll
  for (int off = 32; off > 0; off >>= 1) v = fmaxf(v, __shfl_xor(v, off));
  return v;
}
__device__ __forceinline__ void fma16(float acc[4][4], float4 a, float4 b) {
  acc[0][0] += a.x*b.x; acc[0][1] += a.x*b.y; acc[0][2] += a.x*b.z; acc[0][3] += a.x*b.w;
  acc[1][0] += a.y*b.x; acc[1][1] += a.y*b.y; acc[1][2] += a.y*b.z; acc[1][3] += a.y*b.w;
  acc[2][0] += a.z*b.x; acc[2][1] += a.z*b.y; acc[2][2] += a.z*b.z; acc[2][3] += a.z*b.w;
  acc[3][0] += a.w*b.x; acc[3][1] += a.w*b.y; acc[3][2] += a.w*b.z; acc[3][3] += a.w*b.w;
}

// async global -> LDS, 16 B per lane
__device__ __forceinline__ void gload_lds16(const void* g, void* l) {
  __builtin_amdgcn_global_load_lds(
      (const __attribute__((address_space(1))) unsigned int*)g,
      (__attribute__((address_space(3))) unsigned int*)l, 16, 0, 0);
}

__global__ void k_zero_r16(float* __restrict__ ws) {
  size_t i = (size_t)blockIdx.x * 256 + threadIdx.x;
  if (i < ZERO_FLOATS) ws[i] = 0.f;
}

// f32 [rows x 256] -> bf16 fragment-major swizzle (one block per 16-row group)
__global__ void k_swz_r16(const float* __restrict__ in, unsigned short* __restrict__ out) {
  int g = blockIdx.x, t = threadIdx.x;
  int ks = t >> 5;
  size_t gbase = (size_t)g * 4096;
#pragma unroll
  for (int f = 0; f < 2; ++f) {
    int lane = (2 * t + f) & 63;
    int q = lane >> 4, r = lane & 15;
    const float* src = &in[(size_t)(g * 16 + r) * kD + ks * 32 + q * 8];
    float4 v0 = *(const float4*)src;
    float4 v1 = *(const float4*)(src + 4);
    ushort4 o0, o1;
    o0.x = f2bf(v0.x); o0.y = f2bf(v0.y); o0.z = f2bf(v0.z); o0.w = f2bf(v0.w);
    o1.x = f2bf(v1.x); o1.y = f2bf(v1.y); o1.z = f2bf(v1.z); o1.w = f2bf(v1.w);
    unsigned short* dst = &out[gbase + (size_t)ks * 512 + (size_t)lane * 8];
    *(ushort4*)dst = o0;
    *(ushort4*)(dst + 4) = o1;
  }
}

// ---------------- classification path (atomic-free) ----------------
// wave per row: rnorm[i] = 1 / max(||X_i||, 1e-8)
__global__ void k_rnorm_r19(const float* __restrict__ X, float* __restrict__ rnorm) {
  int w = threadIdx.x >> 6, lane = threadIdx.x & 63;
  int row = blockIdx.x * 4 + w;
  float4 v = *(const float4*)&X[(size_t)row * kD + lane * 4];
  float ss = waveReduceSum(v.x*v.x + v.y*v.y + v.z*v.z + v.w*v.w);
  if (lane == 0) rnorm[row] = 1.0f / fmaxf(sqrtf(ss), 1e-8f);
}

// thread t owns dim t; LDS acc[64][256], no atomics. 128 blocks x 128 rows.
__global__ void k_paccum_r19(const float* __restrict__ X, const int* __restrict__ lab,
                             const float* __restrict__ rnorm,
                             float* __restrict__ partial, float* __restrict__ cntpart) {
  __shared__ float acc[kC * kD];   // 64 KB
  int t = threadIdx.x, b = blockIdx.x;
  for (int i = t; i < kC * kD; i += 256) acc[i] = 0.f;
  __syncthreads();
  int r0 = b * 128;
  float myCnt = 0.f;
  for (int r = 0; r < 128; r += 8) {
    int row = r0 + r;
    int   c0 = lab[row + 0], c1 = lab[row + 1], c2 = lab[row + 2], c3 = lab[row + 3];
    int   c4 = lab[row + 4], c5 = lab[row + 5], c6 = lab[row + 6], c7 = lab[row + 7];
    float n0 = rnorm[row + 0], n1 = rnorm[row + 1], n2 = rnorm[row + 2], n3 = rnorm[row + 3];
    float n4 = rnorm[row + 4], n5 = rnorm[row + 5], n6 = rnorm[row + 6], n7 = rnorm[row + 7];
    float x0 = X[(size_t)(row + 0) * kD + t];
    float x1 = X[(size_t)(row + 1) * kD + t];
    float x2 = X[(size_t)(row + 2) * kD + t];
    float x3 = X[(size_t)(row + 3) * kD + t];
    float x4 = X[(size_t)(row + 4) * kD + t];
    float x5 = X[(size_t)(row + 5) * kD + t];
    float x6 = X[(size_t)(row + 6) * kD + t];
    float x7 = X[(size_t)(row + 7) * kD + t];
    acc[c0 * kD + t] += x0 * n0;
    acc[c1 * kD + t] += x1 * n1;
    acc[c2 * kD + t] += x2 * n2;
    acc[c3 * kD + t] += x3 * n3;
    acc[c4 * kD + t] += x4 * n4;
    acc[c5 * kD + t] += x5 * n5;
    acc[c6 * kD + t] += x6 * n6;
    acc[c7 * kD + t] += x7 * n7;
    myCnt += (t == c0) ? 1.f : 0.f; myCnt += (t == c1) ? 1.f : 0.f;
    myCnt += (t == c2) ? 1.f : 0.f; myCnt += (t == c3) ? 1.f : 0.f;
    myCnt += (t == c4) ? 1.f : 0.f; myCnt += (t == c5) ? 1.f : 0.f;
    myCnt += (t == c6) ? 1.f : 0.f; myCnt += (t == c7) ? 1.f : 0.f;
  }
  __syncthreads();
  float* pb = partial + (size_t)b * (kC * kD);
  for (int c = 0; c < kC; ++c) pb[c * kD + t] = acc[c * kD + t];
  if (t < kC) cntpart[b * kC + t] = myCnt;
}

// one block per class: reduce 128 partials, divide by count, L2-normalize
__global__ void k_proto_fin_r19(const float* __restrict__ partial,
                                const float* __restrict__ cntpart,
                                float* __restrict__ protos) {
  __shared__ float cs[128];
  __shared__ float wred[4];
  __shared__ float cntS, invS;
  int c = blockIdx.x, t = threadIdx.x;
  if (t < 128) cs[t] = cntpart[t * kC + c];
  __syncthreads();
  float s = 0.f;
  const float* p = partial + (size_t)c * kD + t;
  for (int b = 0; b < 128; ++b) s += p[(size_t)b * (kC * kD)];
  if (t < 64) {
    float cv = cs[t] + cs[t + 64];
    cv = waveReduceSum(cv);
    if (t == 0) cntS = fmaxf(cv, 1.0f);
  }
  __syncthreads();
  float v = s / cntS;
  float ss = waveReduceSum(v * v);
  if ((t & 63) == 0) wred[t >> 6] = ss;
  __syncthreads();
  if (t == 0) invS = 1.0f / fmaxf(sqrtf(wred[0] + wred[1] + wred[2] + wred[3]), 1e-8f);
  __syncthreads();
  protos[(size_t)c * kD + t] = v * invS;
}

__global__ void k_logits_r16(const float* __restrict__ Q, const float* __restrict__ protos,
                             float* __restrict__ out0) {
  __shared__ alignas(16) float qs[kD];
  __shared__ float lg[kC];
  __shared__ float wred[4];
  __shared__ float qis;
  int t = threadIdx.x, w = t >> 6, lane = t & 63;
  int qi = blockIdx.x;
  float myv = Q[(size_t)qi * kD + t];
  qs[t] = myv;
  float ss = waveReduceSum(myv * myv);
  if (lane == 0) wred[w] = ss;
  __syncthreads();
  if (t == 0) qis = 1.0f / fmaxf(sqrtf(wred[0] + wred[1] + wred[2] + wred[3]), 1e-8f);
  __syncthreads();
  float4 qv = *(const float4*)&qs[lane * 4];
  for (int cc = w * 16; cc < w * 16 + 16; ++cc) {
    float4 pv = *(const float4*)&protos[(size_t)cc * kD + lane * 4];
    float d = waveReduceSum(qv.x*pv.x + qv.y*pv.y + qv.z*pv.z + qv.w*pv.w);
    if (lane == 0) lg[cc] = d * qis;
  }
  __syncthreads();
  if (t < 64) {
    float v = lg[t];
    float m = waveReduceMax(v);
    float e = expf(v - m);
    float s = waveReduceSum(e);
    float lse = m + logf(s);
    out0[(size_t)qi * kC + t] = v - lse;
  }
}

// ---------------- regression path ----------------
__global__ void k_colsum_r16(const float* __restrict__ X, float* __restrict__ musum) {
  int t = threadIdx.x;
  int r0 = blockIdx.x * 64;
  float s = 0.f;
  for (int r = 0; r < 64; ++r) s += X[(size_t)(r0 + r) * kD + t];
  atomicAdd(&musum[t], s);
}
__global__ void k_mufin_r16(const float* __restrict__ musum, float* __restrict__ mu) {
  int t = threadIdx.x;
  mu[t] = musum[t] * (1.0f / (float)kNS);
}

__global__ void k_xtx_r16(const float* __restrict__ X, float* __restrict__ xtx) {
  __shared__ alignas(16) float As[16][68];
  __shared__ alignas(16) float Bs[16][68];
  int t = threadIdx.x, tx = t & 15, ty = t >> 4;
  int ab = (blockIdx.x >> 2) * 64, bb = (blockIdx.x & 3) * 64;
  int k0b = blockIdx.y * 1024;
  float acc[4][4] = {};
  for (int k0 = 0; k0 < 1024; k0 += 16) {
    __syncthreads();
    int j = t & 63, kr0 = t >> 6;
#pragma unroll
    for (int p = 0; p < 4; ++p) {
      int kr = kr0 + p * 4;
      size_t base = (size_t)(k0b + k0 + kr) * kD;
      As[kr][j] = X[base + ab + j];
      Bs[kr][j] = X[base + bb + j];
    }
    __syncthreads();
#pragma unroll
    for (int k = 0; k < 16; ++k) {
      float4 a = *(const float4*)&As[k][ty * 4];
      float4 b = *(const float4*)&Bs[k][tx * 4];
      fma16(acc, a, b);
    }
  }
#pragma unroll
  for (int r = 0; r < 4; ++r)
#pragma unroll
    for (int c = 0; c < 4; ++c)
      atomicAdd(&xtx[(size_t)(ab + ty * 4 + r) * kD + bb + tx * 4 + c], acc[r][c]);
}

__global__ void k_cov_r16(const float* __restrict__ xtx, const float* __restrict__ mu,
                          float* __restrict__ cov) {
  int i = blockIdx.x, j = threadIdx.x;
  float v = (xtx[(size_t)i * kD + j] - (float)kNS * mu[i] * mu[j]) * (1.0f / (float)(kNS - 1));
  if (i == j) v += 1e-4f;
  cov[(size_t)i * kD + j] = v;
}

__global__ void k_rowabs_r16(const float* __restrict__ cov, float* __restrict__ rows) {
  int row = blockIdx.x, lane = threadIdx.x;
  float4 v = *(const float4*)&cov[(size_t)row * kD + lane * 4];
  float s = waveReduceSum(fabsf(v.x) + fabsf(v.y) + fabsf(v.z) + fabsf(v.w));
  if (lane == 0) rows[row] = s;
}
__global__ void k_cnorm_r16(const float* __restrict__ rows, float* __restrict__ cptr) {
  int lane = threadIdx.x;
  float m = fmaxf(fmaxf(rows[lane], rows[lane + 64]),
                  fmaxf(rows[lane + 128], rows[lane + 192]));
  m = waveReduceMax(m);
  if (lane == 0) cptr[0] = m;
}
// X0 = I / c
__global__ void k_newt_init_r16(const float* __restrict__ cptr, float* __restrict__ X) {
  int i = blockIdx.x, j = threadIdx.x;
  X[(size_t)i * kD + j] = (i == j) ? (1.0f / cptr[0]) : 0.0f;
}

// one 256x256 matmul step, 1024 threads (4-way split-k + LDS reduce).
// isT=1: Out = 2I - A @ Xin.  isT=0: Out = A @ Xin  (A indexed by row).
__global__ void __launch_bounds__(1024)
k_newt_mm_r17(const float* __restrict__ A, const float* __restrict__ Xin,
              float* __restrict__ Out, int isT) {
  __shared__ float a_s[256];
  __shared__ float red[3][256];
  int i = blockIdx.x, t = threadIdx.x;
  int j = t & 255, kq = t >> 8;
  if (t < 256) a_s[t] = A[(size_t)i * kD + t];
  __syncthreads();
  int k0 = kq * 64;
  const float* Xp = &Xin[(size_t)k0 * kD + j];
  float s0 = 0.f, s1 = 0.f, s2 = 0.f, s3 = 0.f;
#pragma unroll 4
  for (int k = 0; k < 64; k += 4) {
    s0 = fmaf(a_s[k0 + k + 0], Xp[0 * kD], s0);
    s1 = fmaf(a_s[k0 + k + 1], Xp[1 * kD], s1);
    s2 = fmaf(a_s[k0 + k + 2], Xp[2 * kD], s2);
    s3 = fmaf(a_s[k0 + k + 3], Xp[3 * kD], s3);
    Xp += 4 * kD;
  }
  float s = (s0 + s1) + (s2 + s3);
  if (kq) red[kq - 1][j] = s;
  __syncthreads();
  if (t < 256) {
    float tot = s + red[0][j] + red[1][j] + red[2][j];
    float o = isT ? ((i == j ? 2.0f : 0.0f) - tot) : tot;
    Out[(size_t)i * kD + j] = o;
  }
}

// G = (Q - mu) @ M
__global__ void k_G_r16(const float* __restrict__ Q, const float* __restrict__ mu,
                        const float* __restrict__ M, float* __restrict__ G) {
  __shared__ alignas(16) float As[16][68];
  __shared__ alignas(16) float Bs[16][68];
  int t = threadIdx.x, tx = t & 15, ty = t >> 4;
  int nb = blockIdx.x * 64;
  int mb = blockIdx.y * 64;
  float acc[4][4] = {};
  for (int k0 = 0; k0 < 256; k0 += 16) {
    __syncthreads();
    {
      int kk = t & 15, m0 = t >> 4;
      float muk = mu[k0 + kk];
#pragma unroll
      for (int p = 0; p < 4; ++p) {
        int m = m0 + p * 16;
        As[kk][m] = Q[(size_t)(mb + m) * kD + k0 + kk] - muk;
      }
      int j = t & 63, kr0 = t >> 6;
#pragma unroll
      for (int p = 0; p < 4; ++p) {
        int kr = kr0 + p * 4;
        Bs[kr][j] = M[(size_t)(k0 + kr) * kD + nb + j];
      }
    }
    __syncthreads();
#pragma unroll
    for (int k = 0; k < 16; ++k) {
      float4 a = *(const float4*)&As[k][ty * 4];
      float4 b = *(const float4*)&Bs[k][tx * 4];
      fma16(acc, a, b);
    }
  }
#pragma unroll
  for (int r = 0; r < 4; ++r) {
    int gi = mb + ty * 4 + r;
    float4 o = {acc[r][0], acc[r][1], acc[r][2], acc[r][3]};
    *(float4*)&G[(size_t)gi * kD + nb + tx * 4] = o;
  }
}

// q2p[i] = G_i . (Q_i + mu)
__global__ void k_q2p_r16(const float* __restrict__ G, const float* __restrict__ Q,
                          const float* __restrict__ mu, float* __restrict__ q2p) {
  int w = threadIdx.x >> 6, lane = threadIdx.x & 63;
  int row = blockIdx.x * 4 + w;
  float4 g = *(const float4*)&G[(size_t)row * kD + lane * 4];
  float4 q = *(const float4*)&Q[(size_t)row * kD + lane * 4];
  float4 m = *(const float4*)&mu[lane * 4];
  float ss = waveReduceSum(g.x*(q.x+m.x) + g.y*(q.y+m.y) + g.z*(q.z+m.z) + g.w*(q.w+m.w));
  if (lane == 0) q2p[row] = ss;
}

// s2[j] = (S_j - mu) M (S_j - mu), per 64-row chunk
__global__ void k_s2_r16(const float* __restrict__ S, const float* __restrict__ mu,
                         const float* __restrict__ M, float* __restrict__ s2) {
  __shared__ alignas(16) float As[16][68];
  __shared__ alignas(16) float Bs[16][68];
  __shared__ float red[64][17];
  int t = threadIdx.x, tx = t & 15, ty = t >> 4;
  int mb = blockIdx.x * 64;
  float partial[4] = {0.f, 0.f, 0.f, 0.f};
  for (int ntile = 0; ntile < 4; ++ntile) {
    int nb = ntile * 64;
    float acc[4][4] = {};
    for (int k0 = 0; k0 < 256; k0 += 16) {
      __syncthreads();
      {
        int kk = t & 15, m0 = t >> 4;
        float muk = mu[k0 + kk];
#pragma unroll
        for (int p = 0; p < 4; ++p) {
          int m = m0 + p * 16;
          As[kk][m] = S[(size_t)(mb + m) * kD + k0 + kk] - muk;
        }
        int j = t & 63, kr0 = t >> 6;
#pragma unroll
        for (int p = 0; p < 4; ++p) {
          int kr = kr0 + p * 4;
          Bs[kr][j] = M[(size_t)(k0 + kr) * kD + nb + j];
        }
      }
      __syncthreads();
#pragma unroll
      for (int k = 0; k < 16; ++k) {
        float4 a = *(const float4*)&As[k][ty * 4];
        float4 b = *(const float4*)&Bs[k][tx * 4];
        fma16(acc, a, b);
      }
    }
#pragma unroll
    for (int r = 0; r < 4; ++r) {
      int gi = mb + ty * 4 + r;
#pragma unroll
      for (int c = 0; c < 4; ++c) {
        int gj = nb + tx * 4 + c;
        partial[r] += acc[r][c] * (S[(size_t)gi * kD + gj] - mu[gj]);
      }
    }
  }
  __syncthreads();
#pragma unroll
  for (int r = 0; r < 4; ++r) red[ty * 4 + r][tx] = partial[r];
  __syncthreads();
  if (t < 64) {
    float s = 0.f;
#pragma unroll
    for (int x = 0; x < 16; ++x) s += red[t][x];
    s2[mb + t] = s;
  }
}

// GEMM-tiled sampled-median histogram
__global__ void k_median_r16(const float* __restrict__ G, const float* __restrict__ S,
                             const float* __restrict__ q2p, const float* __restrict__ s2,
                             unsigned int* __restrict__ hist, float* __restrict__ ssum) {
  __shared__ alignas(16) float As[16][68];
  __shared__ alignas(16) float Bs[16][68];
  __shared__ unsigned int h[2048];
  __shared__ float fred[4];
  int t = threadIdx.x, tx = t & 15, ty = t >> 4;
  int stile = blockIdx.x, qtile = blockIdx.y;
  for (int i = t; i < 2048; i += 256) h[i] = 0u;

  float acc[4][4] = {};
  for (int k0 = 0; k0 < 256; k0 += 16) {
    __syncthreads();
    {
      int kk = t & 15, m0 = t >> 4;
#pragma unroll
      for (int p = 0; p < 4; ++p) {
        int m = m0 + p * 16;
        As[kk][m] = G[(size_t)((qtile * 64 + m) * 8) * kD + k0 + kk];
        Bs[kk][m] = S[(size_t)((stile * 64 + m) * 8) * kD + k0 + kk];
      }
    }
    __syncthreads();
#pragma unroll
    for (int k = 0; k < 16; ++k) {
      float4 a = *(const float4*)&As[k][ty * 4];
      float4 b = *(const float4*)&Bs[k][tx * 4];
      fma16(acc, a, b);
    }
  }
  float fsum = 0.f;
#pragma unroll
  for (int r = 0; r < 4; ++r) {
    int qi = (qtile * 64 + ty * 4 + r) * 8;
    float q2v = q2p[qi];
#pragma unroll
    for (int c = 0; c < 4; ++c) {
      int sj = (stile * 64 + tx * 4 + c) * 8;
      float d2 = fmaxf(q2v + s2[sj] - 2.0f * acc[r][c], 0.0f);
      fsum += d2;
      int bin = (int)(d2 * 2.0f);
      bin = bin > 2047 ? 2047 : bin;
      atomicAdd(&h[bin], 1u);
    }
  }
  float wsum = waveReduceSum(fsum);
  if ((t & 63) == 0) fred[t >> 6] = wsum;
  __syncthreads();
  if (t == 0) atomicAdd(ssum, fred[0] + fred[1] + fred[2] + fred[3]);
  for (int i = t; i < 2048; i += 256)
    if (h[i]) atomicAdd(&hist[i], h[i]);
}

// Parallel median + gamma: 256 threads x 8 bins, LDS scan.
__global__ void k_gamma_r16(const unsigned int* __restrict__ hist,
                            const float* __restrict__ ssum, float* __restrict__ gptr) {
  __shared__ unsigned int ps[256];
  __shared__ float v0s, v1s;
  int t = threadIdx.x;
  unsigned int mine[8];
  unsigned int c = 0;
#pragma unroll
  for (int j = 0; j < 8; ++j) { mine[j] = hist[t * 8 + j]; c += mine[j]; }
  ps[t] = c;
  __syncthreads();
  // Hillis-Steele inclusive scan
  for (int off = 1; off < 256; off <<= 1) {
    unsigned int v = (t >= off) ? ps[t - off] : 0u;
    __syncthreads();
    ps[t] += v;
    __syncthreads();
  }
  unsigned int total = ps[255];
  unsigned int before = ps[t] - c;      // exclusive prefix for my 8 bins
  if (t == 0) { v0s = 0.f; v1s = 0.f; }
  __syncthreads();
  unsigned int rr0 = (total - 1) / 2, rr1 = total / 2;
  unsigned int cum = before;
#pragma unroll
  for (int j = 0; j < 8; ++j) {
    unsigned int cc = mine[j];
    if (cc > 0) {
      int bin = t * 8 + j;
      if (cum <= rr0 && rr0 < cum + cc) {
        float frac = (float)(rr0 - cum) + 0.5f;
        v0s = ((float)bin + frac / (float)cc) * 0.5f;
      }
      if (cum <= rr1 && rr1 < cum + cc) {
        float frac = (float)(rr1 - cum) + 0.5f;
        v1s = ((float)bin + frac / (float)cc) * 0.5f;
      }
    }
    cum += cc;
  }
  __syncthreads();
  if (t == 0) {
    float med = 0.5f * (v0s + v1s);
    float mean = (total > 0) ? (ssum[0] / (float)total) : 1.0f;
    float g = (med > 0.f) ? 1.0f / (med + 1e-6f) : 1.0f / (mean + 1e-6f);
    gptr[0] = g;
  }
}

// MAIN (MFMA, swizzled operands, R21 double-buffered prefetch):
// grid (64 q-tiles of 128 rows, 16 s-chunks); 32 tiles of 32 s-rows,
// LDS 2x16KB; stage tile t+1 BEFORE computing tile t; ONE barrier/tile.
__global__ void __launch_bounds__(256, 4)
PrototypicalHead_6210522710389_kernel(
    const unsigned short* __restrict__ Gh, const unsigned short* __restrict__ Sh,
    const float* __restrict__ q2p, const float* __restrict__ s2,
    const float* __restrict__ svals, const float* __restrict__ gptr,
    float* __restrict__ part) {
  __shared__ unsigned short Bs[2][8192];   // 2 x 16 KB
  int t = threadIdx.x;
  int w = t >> 6, lane = t & 63;
  int l15 = lane & 15, quad = lane >> 4;
  int qt = blockIdx.x, sc = blockIdx.y;
  int qbase = qt * 128;
  float gamma = gptr[0];
  const float LOG2E = 1.44269504f;
  float c2 = 2.0f * gamma * LOG2E;       // exp2 folding: e^{-g*d2} = 2^{c2*a + cq + cs}

  // two A-fragment sets: rows [w*32, w*32+16) and [w*32+16, w*32+32)
  size_t agrp = (size_t)(qt * 8 + w * 2) * 4096;
  bf16x8 afrag[2][8];
#pragma unroll
  for (int s = 0; s < 2; ++s)
#pragma unroll
    for (int ks = 0; ks < 8; ++ks)
      afrag[s][ks] = *(const bf16x8*)&Gh[agrp + (size_t)s * 4096 + (size_t)ks * 512 + (size_t)lane * 8];

  float cqv[2][4];
#pragma unroll
  for (int s = 0; s < 2; ++s)
#pragma unroll
    for (int r = 0; r < 4; ++r)
      cqv[s][r] = -gamma * LOG2E * q2p[qbase + w * 32 + s * 16 + quad * 4 + r];

  float dAcc[2][4] = {}, nAcc[2][4] = {};

  // 32-row tile = 2 fragment groups = 16 KB = 1024 x 16B chunks (4/thread)
  const char* sbase_ptr = (const char*)&Sh[(size_t)(sc * 64) * 4096];
  // prologue: stage tile 0 into buf 0
#pragma unroll
  for (int i = 0; i < 4; ++i) {
    int c = i * 256 + t;
    gload_lds16(sbase_ptr + (size_t)c * 16, (char*)&Bs[0][0] + (size_t)c * 16);
  }
  __syncthreads();   // drains vmcnt(0): tile 0 ready

  for (int st = 0; st < 32; ++st) {
    int cur = st & 1;
    // issue next tile's staging FIRST (overlaps with compute below)
    if (st + 1 < 32) {
      const char* src = sbase_ptr + (size_t)(st + 1) * 16384;
      char* dst = (char*)&Bs[cur ^ 1][0];
#pragma unroll
      for (int i = 0; i < 4; ++i) {
        int c = i * 256 + t;
        gload_lds16(src + (size_t)c * 16, dst + (size_t)c * 16);
      }
    }

    f32x4 acc[2][2];
#pragma unroll
    for (int s = 0; s < 2; ++s)
#pragma unroll
      for (int nt = 0; nt < 2; ++nt)
        acc[s][nt] = (f32x4){0.f, 0.f, 0.f, 0.f};

    const unsigned short* B0 = &Bs[cur][lane * 8];
#pragma unroll
    for (int ks = 0; ks < 8; ++ks) {
      bf16x8 f0 = *(const bf16x8*)(B0 + ks * 512);
      bf16x8 f1 = *(const bf16x8*)(B0 + 4096 + ks * 512);
      acc[0][0] = __builtin_amdgcn_mfma_f32_16x16x32_bf16(afrag[0][ks], f0, acc[0][0], 0, 0, 0);
      acc[1][0] = __builtin_amdgcn_mfma_f32_16x16x32_bf16(afrag[1][ks], f0, acc[1][0], 0, 0, 0);
      acc[0][1] = __builtin_amdgcn_mfma_f32_16x16x32_bf16(afrag[0][ks], f1, acc[0][1], 0, 0, 0);
      acc[1][1] = __builtin_amdgcn_mfma_f32_16x16x32_bf16(afrag[1][ks], f1, acc[1][1], 0, 0, 0);
    }

    int sbase = sc * 1024 + st * 32;
#pragma unroll
    for (int nt = 0; nt < 2; ++nt) {
      int scol = sbase + nt * 16 + l15;
      float cs = -gamma * LOG2E * s2[scol];
      float sv = svals[scol];
#pragma unroll
      for (int s = 0; s < 2; ++s)
#pragma unroll
        for (int r = 0; r < 4; ++r) {
          // exponent = log2e * -(gamma*(q2+s2-2a)); min(...,0) == the d2>=0 clamp
          float ex = exp2f(fminf(fmaf(c2, acc[s][nt][r], cqv[s][r] + cs), 0.0f));
          dAcc[s][r] += ex;
          nAcc[s][r] = fmaf(ex, sv, nAcc[s][r]);
        }
    }
    __syncthreads();   // vmcnt(0)+lgkmcnt(0)+barrier: next tile ready, buf reuse safe
  }
#pragma unroll
  for (int off = 8; off >= 1; off >>= 1)
#pragma unroll
    for (int s = 0; s < 2; ++s)
#pragma unroll
      for (int r = 0; r < 4; ++r) {
        dAcc[s][r] += __shfl_xor(dAcc[s][r], off);
        nAcc[s][r] += __shfl_xor(nAcc[s][r], off);
      }
  if (l15 == 0) {
#pragma unroll
    for (int s = 0; s < 2; ++s)
#pragma unroll
      for (int r = 0; r < 4; ++r) {
        size_t q = (size_t)qbase + w * 32 + s * 16 + quad * 4 + r;
        part[(q * 16 + sc) * 2 + 0] = dAcc[s][r];
        part[(q * 16 + sc) * 2 + 1] = nAcc[s][r];
      }
  }
}

__global__ void k_final_r16(const float* __restrict__ part, float* __restrict__ out1) {
  int q = blockIdx.x * 256 + threadIdx.x;
  const float* p = part + (size_t)q * 32;
  float d = 0.f, n = 0.f;
#pragma unroll
  for (int i = 0; i < 16; ++i) { d += p[2 * i]; n += p[2 * i + 1]; }
  out1[q] = n / d;
}

extern "C" void kernel_launch(void* const* d_in, const int* in_sizes, int n_in,
                              void* d_out, int out_size, void* d_ws, size_t ws_size,
                              hipStream_t stream) {
  (void)in_sizes; (void)n_in; (void)out_size; (void)ws_size;
  const float* SF = (const float*)d_in[0];   // fp32
  const int*   SL = (const int*)d_in[1];     // int32
  const float* SV = (const float*)d_in[2];   // fp32
  const float* QF = (const float*)d_in[3];   // fp32

  float* ws = (float*)d_ws;
  float* rnorm = ws + OFF_PSUM;              // r19: 16384 row inv-norms
  float* musum = ws + OFF_MUSUM;
  float* xtx   = ws + OFF_XTX;
  unsigned int* hist = (unsigned int*)(ws + OFF_HIST);
  float* ssum  = ws + OFF_SSUM;
  float* protos= ws + OFF_PROTO;
  float* mu    = ws + OFF_MU;
  float* cov   = ws + OFF_COV;
  float* rows  = ws + OFF_ROWS;
  float* cptr  = ws + OFF_C;
  float* gptr  = ws + OFF_C + 1;
  float* X1 = ws + OFF_Y;  float* T = ws + OFF_T;  float* X2 = ws + OFF_Y2;
  float* s2 = ws + OFF_S2; float* q2p = ws + OFF_Q2P;
  float* part = ws + OFF_PART;
  float* G = ws + OFF_G;
  unsigned short* Sh = (unsigned short*)(ws + OFF_SH);
  unsigned short* Gh = (unsigned short*)(ws + OFF_GH);
  // proto-phase aliases (lifetimes end before G / part are written):
  float* pppart  = G;                        // 128*64*256 = 2,097,152 floats
  float* cntpart = part;                     // 128*64 floats

  float* out0 = (float*)d_out;                   // f32 log_probs [8192 x 64]
  float* out1 = out0 + (size_t)kNQ * kC;         // f32 predictions [8192]

  k_zero_r16<<<(int)((ZERO_FLOATS + 255) / 256), 256, 0, stream>>>(ws);

  // swizzled bf16 copy of support features
  k_swz_r16<<<kNS / 16, 256, 0, stream>>>(SF, Sh);

  // classification (atomic-free)
  k_rnorm_r19<<<kNS / 4, 256, 0, stream>>>(SF, rnorm);
  k_paccum_r19<<<128, 256, 0, stream>>>(SF, SL, rnorm, pppart, cntpart);
  k_proto_fin_r19<<<kC, 256, 0, stream>>>(pppart, cntpart, protos);
  k_logits_r16<<<kNQ, 256, 0, stream>>>(QF, protos, out0);

  // regression: mean, cov
  k_colsum_r16<<<kNS / 64, 256, 0, stream>>>(SF, musum);
  k_mufin_r16<<<1, 256, 0, stream>>>(musum, mu);
  k_xtx_r16<<<dim3(16, 16), 256, 0, stream>>>(SF, xtx);
  k_cov_r16<<<256, 256, 0, stream>>>(xtx, mu, cov);

  // Newton matrix inverse: X <- X (2I - cov X), X0 = I/c, 6 iterations
  k_rowabs_r16<<<256, 64, 0, stream>>>(cov, rows);
  k_cnorm_r16<<<1, 64, 0, stream>>>(rows, cptr);
  k_newt_init_r16<<<256, 256, 0, stream>>>(cptr, X1);
  float *Xc = X1, *T_ = T, *Xn = X2;
  for (int it = 0; it < 6; ++it) {
    k_newt_mm_r17<<<256, 1024, 0, stream>>>(cov, Xc, T_, 1);
    k_newt_mm_r17<<<256, 1024, 0, stream>>>(Xc, T_, Xn, 0);
    float* tmp = Xc; Xc = Xn; Xn = tmp;
  }
  float* M = Xc;   // cov^-1

  // G = (Q - mu) @ M, swizzled bf16 copy, scalar row terms
  k_G_r16<<<dim3(4, kNQ / 64), 256, 0, stream>>>(QF, mu, M, G);
  k_swz_r16<<<kNQ / 16, 256, 0, stream>>>(G, Gh);
  k_q2p_r16<<<kNQ / 4, 256, 0, stream>>>(G, QF, mu, q2p);
  k_s2_r16<<<kNS / 64, 256, 0, stream>>>(SF, mu, M, s2);

  // sampled median -> gamma (parallel)
  k_median_r16<<<dim3(32, 16), 256, 0, stream>>>(G, SF, q2p, s2, hist, ssum);
  k_gamma_r16<<<1, 256, 0, stream>>>(hist, ssum, gptr);

  // MFMA fused cdist^2 + softmax numer/denom, then finalize
  PrototypicalHead_6210522710389_kernel<<<dim3(64, 16), 256, 0, stream>>>(
      Gh, Sh, q2p, s2, SV, gptr, part);
  k_final_r16<<<kNQ / 256, 256, 0, stream>>>(part, out1);
}

// Round 6
// 514.129 us; speedup vs baseline: 1.4597x; 1.0212x over previous
//
#include <hip/hip_runtime.h>
#include <hip/hip_bf16.h>

// Problem dims (fixed by setup_inputs)
constexpr int kNS = 16384;   // support rows
constexpr int kNQ = 8192;    // query rows
constexpr int kD  = 256;     // feature dim
constexpr int kC  = 64;      // classes

// R21 PASSED (525 us, main 96 us, MfmaUtil 30%, Occ 31%). dbuf didn't pay:
// overlap window too short, 2.5 blocks/CU. Main is only 96/525 — mid-tier
// kernels (xtx, s2 at 1 wave/SIMD; logits 8192 blocks) hold ~430 us.
// R22: (1) main: grid (64,32), 5 blocks/CU, setprio(1) around MFMAs;
// (2) xtx: K-split x32, partials in dead G region, fused reduce+cov;
// (3) s2: ntile->gridDim.y (4 blocks/CU), partials in dead X2 region;
// (4) logits via MFMA (Qh bf16 in Gh region, proto frags, 128 blocks).

// ---------------- workspace layout (float offsets into d_ws), ~24.4 MB ----
constexpr size_t OFF_PSUM  = 0;          // rnorm[16384]
constexpr size_t OFF_MUSUM = 16448;
constexpr size_t OFF_XTX   = 16704;      // (unused in r22)
constexpr size_t OFF_HIST  = 82240;
constexpr size_t OFF_SSUM  = 84288;
constexpr size_t ZERO_FLOATS = 84352;
constexpr size_t OFF_PROTO = 84352;
constexpr size_t OFF_MU    = 100736;
constexpr size_t OFF_COV   = 100992;
constexpr size_t OFF_ROWS  = 166528;
constexpr size_t OFF_C     = 166784;
constexpr size_t OFF_Y     = 166800;     // Newton X ping; r22: qnorm+Ph (proto phase)
constexpr size_t OFF_T     = 297872;     // Newton T
constexpr size_t OFF_Y2    = 363408;     // Newton X pong; r22: s2 partials (post-Newton)
constexpr size_t OFF_S2    = 560016;
constexpr size_t OFF_Q2P   = 576400;
constexpr size_t OFF_PART  = 584592;     // r22: 8192*32*2 floats (overlaps dead G head)
constexpr size_t OFF_G     = 846736;     // 8192*256 f32; also proto/xtx partials
constexpr size_t OFF_SH    = 2943888;    // 16384*256 bf16 swizzled
constexpr size_t OFF_GH    = 5041040;    // 8192*256 bf16 swizzled; r22: Qh (proto phase)

typedef __attribute__((ext_vector_type(8))) short bf16x8;
typedef __attribute__((ext_vector_type(4))) float f32x4;

__device__ __forceinline__ unsigned short f2bf(float f) {
  unsigned int w; __builtin_memcpy(&w, &f, 4);
  unsigned int r = (w + 0x7FFFu + ((w >> 16) & 1u)) >> 16;
  return (unsigned short)r;
}

__device__ __forceinline__ float waveReduceSum(float v) {
#pragma unroll
  for (int off = 32; off > 0; off >>= 1) v += __shfl_xor(v, off);
  return v;
}
__device__ __forceinline__ float waveReduceMax(float v) {
#pragma unroll
  for (int off = 32; off > 0; off >>= 1) v = fmaxf(v, __shfl_xor(v, off));
  return v;
}
__device__ __forceinline__ void fma16(float acc[4][4], float4 a, float4 b) {
  acc[0][0] += a.x*b.x; acc[0][1] += a.x*b.y; acc[0][2] += a.x*b.z; acc[0][3] += a.x*b.w;
  acc[1][0] += a.y*b.x; acc[1][1] += a.y*b.y; acc[1][2] += a.y*b.z; acc[1][3] += a.y*b.w;
  acc[2][0] += a.z*b.x; acc[2][1] += a.z*b.y; acc[2][2] += a.z*b.z; acc[2][3] += a.z*b.w;
  acc[3][0] += a.w*b.x; acc[3][1] += a.w*b.y; acc[3][2] += a.w*b.z; acc[3][3] += a.w*b.w;
}

// async global -> LDS, 16 B per lane
__device__ __forceinline__ void gload_lds16(const void* g, void* l) {
  __builtin_amdgcn_global_load_lds(
      (const __attribute__((address_space(1))) unsigned int*)g,
      (__attribute__((address_space(3))) unsigned int*)l, 16, 0, 0);
}

__global__ void k_zero_r16(float* __restrict__ ws) {
  size_t i = (size_t)blockIdx.x * 256 + threadIdx.x;
  if (i < ZERO_FLOATS) ws[i] = 0.f;
}

// f32 [rows x 256] -> bf16 fragment-major swizzle (one block per 16-row group)
__global__ void k_swz_r16(const float* __restrict__ in, unsigned short* __restrict__ out) {
  int g = blockIdx.x, t = threadIdx.x;
  int ks = t >> 5;
  size_t gbase = (size_t)g * 4096;
#pragma unroll
  for (int f = 0; f < 2; ++f) {
    int lane = (2 * t + f) & 63;
    int q = lane >> 4, r = lane & 15;
    const float* src = &in[(size_t)(g * 16 + r) * kD + ks * 32 + q * 8];
    float4 v0 = *(const float4*)src;
    float4 v1 = *(const float4*)(src + 4);
    ushort4 o0, o1;
    o0.x = f2bf(v0.x); o0.y = f2bf(v0.y); o0.z = f2bf(v0.z); o0.w = f2bf(v0.w);
    o1.x = f2bf(v1.x); o1.y = f2bf(v1.y); o1.z = f2bf(v1.z); o1.w = f2bf(v1.w);
    unsigned short* dst = &out[gbase + (size_t)ks * 512 + (size_t)lane * 8];
    *(ushort4*)dst = o0;
    *(ushort4*)(dst + 4) = o1;
  }
}

// r22: swizzle with per-row scale (row-normalized bf16 copy)
__global__ void k_swzn_r22(const float* __restrict__ in, const float* __restrict__ scale,
                           unsigned short* __restrict__ out) {
  int g = blockIdx.x, t = threadIdx.x;
  int ks = t >> 5;
  size_t gbase = (size_t)g * 4096;
#pragma unroll
  for (int f = 0; f < 2; ++f) {
    int lane = (2 * t + f) & 63;
    int q = lane >> 4, r = lane & 15;
    float n = scale[g * 16 + r];
    const float* src = &in[(size_t)(g * 16 + r) * kD + ks * 32 + q * 8];
    float4 v0 = *(const float4*)src;
    float4 v1 = *(const float4*)(src + 4);
    ushort4 o0, o1;
    o0.x = f2bf(v0.x * n); o0.y = f2bf(v0.y * n); o0.z = f2bf(v0.z * n); o0.w = f2bf(v0.w * n);
    o1.x = f2bf(v1.x * n); o1.y = f2bf(v1.y * n); o1.z = f2bf(v1.z * n); o1.w = f2bf(v1.w * n);
    unsigned short* dst = &out[gbase + (size_t)ks * 512 + (size_t)lane * 8];
    *(ushort4*)dst = o0;
    *(ushort4*)(dst + 4) = o1;
  }
}

// ---------------- classification path (atomic-free) ----------------
// wave per row: rnorm[i] = 1 / max(||X_i||, 1e-8)
__global__ void k_rnorm_r19(const float* __restrict__ X, float* __restrict__ rnorm) {
  int w = threadIdx.x >> 6, lane = threadIdx.x & 63;
  int row = blockIdx.x * 4 + w;
  float4 v = *(const float4*)&X[(size_t)row * kD + lane * 4];
  float ss = waveReduceSum(v.x*v.x + v.y*v.y + v.z*v.z + v.w*v.w);
  if (lane == 0) rnorm[row] = 1.0f / fmaxf(sqrtf(ss), 1e-8f);
}

// thread t owns dim t; LDS acc[64][256], no atomics. 128 blocks x 128 rows.
__global__ void k_paccum_r19(const float* __restrict__ X, const int* __restrict__ lab,
                             const float* __restrict__ rnorm,
                             float* __restrict__ partial, float* __restrict__ cntpart) {
  __shared__ float acc[kC * kD];   // 64 KB
  int t = threadIdx.x, b = blockIdx.x;
  for (int i = t; i < kC * kD; i += 256) acc[i] = 0.f;
  __syncthreads();
  int r0 = b * 128;
  float myCnt = 0.f;
  for (int r = 0; r < 128; r += 8) {
    int row = r0 + r;
    int   c0 = lab[row + 0], c1 = lab[row + 1], c2 = lab[row + 2], c3 = lab[row + 3];
    int   c4 = lab[row + 4], c5 = lab[row + 5], c6 = lab[row + 6], c7 = lab[row + 7];
    float n0 = rnorm[row + 0], n1 = rnorm[row + 1], n2 = rnorm[row + 2], n3 = rnorm[row + 3];
    float n4 = rnorm[row + 4], n5 = rnorm[row + 5], n6 = rnorm[row + 6], n7 = rnorm[row + 7];
    float x0 = X[(size_t)(row + 0) * kD + t];
    float x1 = X[(size_t)(row + 1) * kD + t];
    float x2 = X[(size_t)(row + 2) * kD + t];
    float x3 = X[(size_t)(row + 3) * kD + t];
    float x4 = X[(size_t)(row + 4) * kD + t];
    float x5 = X[(size_t)(row + 5) * kD + t];
    float x6 = X[(size_t)(row + 6) * kD + t];
    float x7 = X[(size_t)(row + 7) * kD + t];
    acc[c0 * kD + t] += x0 * n0;
    acc[c1 * kD + t] += x1 * n1;
    acc[c2 * kD + t] += x2 * n2;
    acc[c3 * kD + t] += x3 * n3;
    acc[c4 * kD + t] += x4 * n4;
    acc[c5 * kD + t] += x5 * n5;
    acc[c6 * kD + t] += x6 * n6;
    acc[c7 * kD + t] += x7 * n7;
    myCnt += (t == c0) ? 1.f : 0.f; myCnt += (t == c1) ? 1.f : 0.f;
    myCnt += (t == c2) ? 1.f : 0.f; myCnt += (t == c3) ? 1.f : 0.f;
    myCnt += (t == c4) ? 1.f : 0.f; myCnt += (t == c5) ? 1.f : 0.f;
    myCnt += (t == c6) ? 1.f : 0.f; myCnt += (t == c7) ? 1.f : 0.f;
  }
  __syncthreads();
  float* pb = partial + (size_t)b * (kC * kD);
  for (int c = 0; c < kC; ++c) pb[c * kD + t] = acc[c * kD + t];
  if (t < kC) cntpart[b * kC + t] = myCnt;
}

// one block per class: reduce 128 partials, divide by count, L2-normalize
__global__ void k_proto_fin_r19(const float* __restrict__ partial,
                                const float* __restrict__ cntpart,
                                float* __restrict__ protos) {
  __shared__ float cs[128];
  __shared__ float wred[4];
  __shared__ float cntS, invS;
  int c = blockIdx.x, t = threadIdx.x;
  if (t < 128) cs[t] = cntpart[t * kC + c];
  __syncthreads();
  float s = 0.f;
  const float* p = partial + (size_t)c * kD + t;
  for (int b = 0; b < 128; ++b) s += p[(size_t)b * (kC * kD)];
  if (t < 64) {
    float cv = cs[t] + cs[t + 64];
    cv = waveReduceSum(cv);
    if (t == 0) cntS = fmaxf(cv, 1.0f);
  }
  __syncthreads();
  float v = s / cntS;
  float ss = waveReduceSum(v * v);
  if ((t & 63) == 0) wred[t >> 6] = ss;
  __syncthreads();
  if (t == 0) invS = 1.0f / fmaxf(sqrtf(wred[0] + wred[1] + wred[2] + wred[3]), 1e-8f);
  __syncthreads();
  protos[(size_t)c * kD + t] = v * invS;
}

// r22: MFMA logits + log-softmax. grid 128 blocks; wave: 16 q-rows x 64 classes.
__global__ void k_logits_mfma_r22(const unsigned short* __restrict__ Qh,
                                  const unsigned short* __restrict__ Ph,
                                  float* __restrict__ out0) {
  int t = threadIdx.x;
  int w = t >> 6, lane = t & 63;
  int l15 = lane & 15, quad = lane >> 4;
  int qb = blockIdx.x * 64;

  size_t agrp = (size_t)(blockIdx.x * 4 + w) * 4096;
  bf16x8 afrag[8];
#pragma unroll
  for (int ks = 0; ks < 8; ++ks)
    afrag[ks] = *(const bf16x8*)&Qh[agrp + (size_t)ks * 512 + (size_t)lane * 8];

  f32x4 acc0 = {0.f,0.f,0.f,0.f}, acc1 = {0.f,0.f,0.f,0.f};
  f32x4 acc2 = {0.f,0.f,0.f,0.f}, acc3 = {0.f,0.f,0.f,0.f};
#pragma unroll
  for (int ks = 0; ks < 8; ++ks) {
    bf16x8 b0 = *(const bf16x8*)&Ph[(size_t)0 * 4096 + ks * 512 + (size_t)lane * 8];
    bf16x8 b1 = *(const bf16x8*)&Ph[(size_t)1 * 4096 + ks * 512 + (size_t)lane * 8];
    bf16x8 b2 = *(const bf16x8*)&Ph[(size_t)2 * 4096 + ks * 512 + (size_t)lane * 8];
    bf16x8 b3 = *(const bf16x8*)&Ph[(size_t)3 * 4096 + ks * 512 + (size_t)lane * 8];
    acc0 = __builtin_amdgcn_mfma_f32_16x16x32_bf16(afrag[ks], b0, acc0, 0, 0, 0);
    acc1 = __builtin_amdgcn_mfma_f32_16x16x32_bf16(afrag[ks], b1, acc1, 0, 0, 0);
    acc2 = __builtin_amdgcn_mfma_f32_16x16x32_bf16(afrag[ks], b2, acc2, 0, 0, 0);
    acc3 = __builtin_amdgcn_mfma_f32_16x16x32_bf16(afrag[ks], b3, acc3, 0, 0, 0);
  }
#pragma unroll
  for (int r = 0; r < 4; ++r) {
    float m = fmaxf(fmaxf(acc0[r], acc1[r]), fmaxf(acc2[r], acc3[r]));
#pragma unroll
    for (int off = 8; off >= 1; off >>= 1) m = fmaxf(m, __shfl_xor(m, off));
    float e = expf(acc0[r] - m) + expf(acc1[r] - m) + expf(acc2[r] - m) + expf(acc3[r] - m);
#pragma unroll
    for (int off = 8; off >= 1; off >>= 1) e += __shfl_xor(e, off);
    float lse = m + logf(e);
    size_t row = (size_t)qb + w * 16 + quad * 4 + r;
    out0[row * kC + 0 * 16 + l15] = acc0[r] - lse;
    out0[row * kC + 1 * 16 + l15] = acc1[r] - lse;
    out0[row * kC + 2 * 16 + l15] = acc2[r] - lse;
    out0[row * kC + 3 * 16 + l15] = acc3[r] - lse;
  }
}

// ---------------- regression path ----------------
__global__ void k_colsum_r16(const float* __restrict__ X, float* __restrict__ musum) {
  int t = threadIdx.x;
  int r0 = blockIdx.x * 64;
  float s = 0.f;
  for (int r = 0; r < 64; ++r) s += X[(size_t)(r0 + r) * kD + t];
  atomicAdd(&musum[t], s);
}
__global__ void k_mufin_r16(const float* __restrict__ musum, float* __restrict__ mu) {
  int t = threadIdx.x;
  mu[t] = musum[t] * (1.0f / (float)kNS);
}

// r22: xtx K-split x32: grid (16 tiles, 32 K-chunks of 512), partials (no atomics)
__global__ void k_xtx_r22(const float* __restrict__ X, float* __restrict__ part) {
  __shared__ alignas(16) float As[16][68];
  __shared__ alignas(16) float Bs[16][68];
  int t = threadIdx.x, tx = t & 15, ty = t >> 4;
  int ab = (blockIdx.x >> 2) * 64, bb = (blockIdx.x & 3) * 64;
  int k0b = blockIdx.y * 512;
  float acc[4][4] = {};
  for (int k0 = 0; k0 < 512; k0 += 16) {
    __syncthreads();
    int j = t & 63, kr0 = t >> 6;
#pragma unroll
    for (int p = 0; p < 4; ++p) {
      int kr = kr0 + p * 4;
      size_t base = (size_t)(k0b + k0 + kr) * kD;
      As[kr][j] = X[base + ab + j];
      Bs[kr][j] = X[base + bb + j];
    }
    __syncthreads();
#pragma unroll
    for (int k = 0; k < 16; ++k) {
      float4 a = *(const float4*)&As[k][ty * 4];
      float4 b = *(const float4*)&Bs[k][tx * 4];
      fma16(acc, a, b);
    }
  }
  float* pb = part + ((size_t)blockIdx.y * 16 + blockIdx.x) * 4096;
#pragma unroll
  for (int r = 0; r < 4; ++r) {
    float4 o = {acc[r][0], acc[r][1], acc[r][2], acc[r][3]};
    *(float4*)&pb[(size_t)(ty * 4 + r) * 64 + tx * 4] = o;
  }
}

// r22: reduce 32 xtx partials + form cov directly
__global__ void k_xtxcov_r22(const float* __restrict__ part, const float* __restrict__ mu,
                             float* __restrict__ cov) {
  int i = blockIdx.x, j = threadIdx.x;
  int tile = (i >> 6) * 4 + (j >> 6);
  int local = (i & 63) * 64 + (j & 63);
  const float* p = part + (size_t)tile * 4096 + local;
  float s = 0.f;
#pragma unroll 8
  for (int ky = 0; ky < 32; ++ky) s += p[(size_t)ky * 65536];
  float v = (s - (float)kNS * mu[i] * mu[j]) * (1.0f / (float)(kNS - 1));
  if (i == j) v += 1e-4f;
  cov[(size_t)i * kD + j] = v;
}

__global__ void k_rowabs_r16(const float* __restrict__ cov, float* __restrict__ rows) {
  int row = blockIdx.x, lane = threadIdx.x;
  float4 v = *(const float4*)&cov[(size_t)row * kD + lane * 4];
  float s = waveReduceSum(fabsf(v.x) + fabsf(v.y) + fabsf(v.z) + fabsf(v.w));
  if (lane == 0) rows[row] = s;
}
__global__ void k_cnorm_r16(const float* __restrict__ rows, float* __restrict__ cptr) {
  int lane = threadIdx.x;
  float m = fmaxf(fmaxf(rows[lane], rows[lane + 64]),
                  fmaxf(rows[lane + 128], rows[lane + 192]));
  m = waveReduceMax(m);
  if (lane == 0) cptr[0] = m;
}
// X0 = I / c
__global__ void k_newt_init_r16(const float* __restrict__ cptr, float* __restrict__ X) {
  int i = blockIdx.x, j = threadIdx.x;
  X[(size_t)i * kD + j] = (i == j) ? (1.0f / cptr[0]) : 0.0f;
}

// one 256x256 matmul step, 1024 threads (4-way split-k + LDS reduce).
// isT=1: Out = 2I - A @ Xin.  isT=0: Out = A @ Xin  (A indexed by row).
__global__ void __launch_bounds__(1024)
k_newt_mm_r17(const float* __restrict__ A, const float* __restrict__ Xin,
              float* __restrict__ Out, int isT) {
  __shared__ float a_s[256];
  __shared__ float red[3][256];
  int i = blockIdx.x, t = threadIdx.x;
  int j = t & 255, kq = t >> 8;
  if (t < 256) a_s[t] = A[(size_t)i * kD + t];
  __syncthreads();
  int k0 = kq * 64;
  const float* Xp = &Xin[(size_t)k0 * kD + j];
  float s0 = 0.f, s1 = 0.f, s2 = 0.f, s3 = 0.f;
#pragma unroll 4
  for (int k = 0; k < 64; k += 4) {
    s0 = fmaf(a_s[k0 + k + 0], Xp[0 * kD], s0);
    s1 = fmaf(a_s[k0 + k + 1], Xp[1 * kD], s1);
    s2 = fmaf(a_s[k0 + k + 2], Xp[2 * kD], s2);
    s3 = fmaf(a_s[k0 + k + 3], Xp[3 * kD], s3);
    Xp += 4 * kD;
  }
  float s = (s0 + s1) + (s2 + s3);
  if (kq) red[kq - 1][j] = s;
  __syncthreads();
  if (t < 256) {
    float tot = s + red[0][j] + red[1][j] + red[2][j];
    float o = isT ? ((i == j ? 2.0f : 0.0f) - tot) : tot;
    Out[(size_t)i * kD + j] = o;
  }
}

// G = (Q - mu) @ M
__global__ void k_G_r16(const float* __restrict__ Q, const float* __restrict__ mu,
                        const float* __restrict__ M, float* __restrict__ G) {
  __shared__ alignas(16) float As[16][68];
  __shared__ alignas(16) float Bs[16][68];
  int t = threadIdx.x, tx = t & 15, ty = t >> 4;
  int nb = blockIdx.x * 64;
  int mb = blockIdx.y * 64;
  float acc[4][4] = {};
  for (int k0 = 0; k0 < 256; k0 += 16) {
    __syncthreads();
    {
      int kk = t & 15, m0 = t >> 4;
      float muk = mu[k0 + kk];
#pragma unroll
      for (int p = 0; p < 4; ++p) {
        int m = m0 + p * 16;
        As[kk][m] = Q[(size_t)(mb + m) * kD + k0 + kk] - muk;
      }
      int j = t & 63, kr0 = t >> 6;
#pragma unroll
      for (int p = 0; p < 4; ++p) {
        int kr = kr0 + p * 4;
        Bs[kr][j] = M[(size_t)(k0 + kr) * kD + nb + j];
      }
    }
    __syncthreads();
#pragma unroll
    for (int k = 0; k < 16; ++k) {
      float4 a = *(const float4*)&As[k][ty * 4];
      float4 b = *(const float4*)&Bs[k][tx * 4];
      fma16(acc, a, b);
    }
  }
#pragma unroll
  for (int r = 0; r < 4; ++r) {
    int gi = mb + ty * 4 + r;
    float4 o = {acc[r][0], acc[r][1], acc[r][2], acc[r][3]};
    *(float4*)&G[(size_t)gi * kD + nb + tx * 4] = o;
  }
}

// q2p[i] = G_i . (Q_i + mu)
__global__ void k_q2p_r16(const float* __restrict__ G, const float* __restrict__ Q,
                          const float* __restrict__ mu, float* __restrict__ q2p) {
  int w = threadIdx.x >> 6, lane = threadIdx.x & 63;
  int row = blockIdx.x * 4 + w;
  float4 g = *(const float4*)&G[(size_t)row * kD + lane * 4];
  float4 q = *(const float4*)&Q[(size_t)row * kD + lane * 4];
  float4 m = *(const float4*)&mu[lane * 4];
  float ss = waveReduceSum(g.x*(q.x+m.x) + g.y*(q.y+m.y) + g.z*(q.z+m.z) + g.w*(q.w+m.w));
  if (lane == 0) q2p[row] = ss;
}

// r22: s2 with ntile = blockIdx.y (grid (256,4)), partials (no atomics)
__global__ void k_s2_r22(const float* __restrict__ S, const float* __restrict__ mu,
                         const float* __restrict__ M, float* __restrict__ s2part) {
  __shared__ alignas(16) float As[16][68];
  __shared__ alignas(16) float Bs[16][68];
  __shared__ float red[64][17];
  int t = threadIdx.x, tx = t & 15, ty = t >> 4;
  int mb = blockIdx.x * 64;
  int nb = blockIdx.y * 64;
  float partial[4] = {0.f, 0.f, 0.f, 0.f};
  float acc[4][4] = {};
  for (int k0 = 0; k0 < 256; k0 += 16) {
    __syncthreads();
    {
      int kk = t & 15, m0 = t >> 4;
      float muk = mu[k0 + kk];
#pragma unroll
      for (int p = 0; p < 4; ++p) {
        int m = m0 + p * 16;
        As[kk][m] = S[(size_t)(mb + m) * kD + k0 + kk] - muk;
      }
      int j = t & 63, kr0 = t >> 6;
#pragma unroll
      for (int p = 0; p < 4; ++p) {
        int kr = kr0 + p * 4;
        Bs[kr][j] = M[(size_t)(k0 + kr) * kD + nb + j];
      }
    }
    __syncthreads();
#pragma unroll
    for (int k = 0; k < 16; ++k) {
      float4 a = *(const float4*)&As[k][ty * 4];
      float4 b = *(const float4*)&Bs[k][tx * 4];
      fma16(acc, a, b);
    }
  }
#pragma unroll
  for (int r = 0; r < 4; ++r) {
    int gi = mb + ty * 4 + r;
#pragma unroll
    for (int c = 0; c < 4; ++c) {
      int gj = nb + tx * 4 + c;
      partial[r] += acc[r][c] * (S[(size_t)gi * kD + gj] - mu[gj]);
    }
  }
  __syncthreads();
#pragma unroll
  for (int r = 0; r < 4; ++r) red[ty * 4 + r][tx] = partial[r];
  __syncthreads();
  if (t < 64) {
    float s = 0.f;
#pragma unroll
    for (int x = 0; x < 16; ++x) s += red[t][x];
    s2part[(size_t)blockIdx.y * kNS + mb + t] = s;
  }
}
__global__ void k_s2fin_r22(const float* __restrict__ sp, float* __restrict__ s2) {
  int i = blockIdx.x * 256 + threadIdx.x;
  s2[i] = sp[i] + sp[kNS + i] + sp[2 * kNS + i] + sp[3 * kNS + i];
}

// GEMM-tiled sampled-median histogram
__global__ void k_median_r16(const float* __restrict__ G, const float* __restrict__ S,
                             const float* __restrict__ q2p, const float* __restrict__ s2,
                             unsigned int* __restrict__ hist, float* __restrict__ ssum) {
  __shared__ alignas(16) float As[16][68];
  __shared__ alignas(16) float Bs[16][68];
  __shared__ unsigned int h[2048];
  __shared__ float fred[4];
  int t = threadIdx.x, tx = t & 15, ty = t >> 4;
  int stile = blockIdx.x, qtile = blockIdx.y;
  for (int i = t; i < 2048; i += 256) h[i] = 0u;

  float acc[4][4] = {};
  for (int k0 = 0; k0 < 256; k0 += 16) {
    __syncthreads();
    {
      int kk = t & 15, m0 = t >> 4;
#pragma unroll
      for (int p = 0; p < 4; ++p) {
        int m = m0 + p * 16;
        As[kk][m] = G[(size_t)((qtile * 64 + m) * 8) * kD + k0 + kk];
        Bs[kk][m] = S[(size_t)((stile * 64 + m) * 8) * kD + k0 + kk];
      }
    }
    __syncthreads();
#pragma unroll
    for (int k = 0; k < 16; ++k) {
      float4 a = *(const float4*)&As[k][ty * 4];
      float4 b = *(const float4*)&Bs[k][tx * 4];
      fma16(acc, a, b);
    }
  }
  float fsum = 0.f;
#pragma unroll
  for (int r = 0; r < 4; ++r) {
    int qi = (qtile * 64 + ty * 4 + r) * 8;
    float q2v = q2p[qi];
#pragma unroll
    for (int c = 0; c < 4; ++c) {
      int sj = (stile * 64 + tx * 4 + c) * 8;
      float d2 = fmaxf(q2v + s2[sj] - 2.0f * acc[r][c], 0.0f);
      fsum += d2;
      int bin = (int)(d2 * 2.0f);
      bin = bin > 2047 ? 2047 : bin;
      atomicAdd(&h[bin], 1u);
    }
  }
  float wsum = waveReduceSum(fsum);
  if ((t & 63) == 0) fred[t >> 6] = wsum;
  __syncthreads();
  if (t == 0) atomicAdd(ssum, fred[0] + fred[1] + fred[2] + fred[3]);
  for (int i = t; i < 2048; i += 256)
    if (h[i]) atomicAdd(&hist[i], h[i]);
}

// Parallel median + gamma: 256 threads x 8 bins, LDS scan.
__global__ void k_gamma_r16(const unsigned int* __restrict__ hist,
                            const float* __restrict__ ssum, float* __restrict__ gptr) {
  __shared__ unsigned int ps[256];
  __shared__ float v0s, v1s;
  int t = threadIdx.x;
  unsigned int mine[8];
  unsigned int c = 0;
#pragma unroll
  for (int j = 0; j < 8; ++j) { mine[j] = hist[t * 8 + j]; c += mine[j]; }
  ps[t] = c;
  __syncthreads();
  // Hillis-Steele inclusive scan
  for (int off = 1; off < 256; off <<= 1) {
    unsigned int v = (t >= off) ? ps[t - off] : 0u;
    __syncthreads();
    ps[t] += v;
    __syncthreads();
  }
  unsigned int total = ps[255];
  unsigned int before = ps[t] - c;      // exclusive prefix for my 8 bins
  if (t == 0) { v0s = 0.f; v1s = 0.f; }
  __syncthreads();
  unsigned int rr0 = (total - 1) / 2, rr1 = total / 2;
  unsigned int cum = before;
#pragma unroll
  for (int j = 0; j < 8; ++j) {
    unsigned int cc = mine[j];
    if (cc > 0) {
      int bin = t * 8 + j;
      if (cum <= rr0 && rr0 < cum + cc) {
        float frac = (float)(rr0 - cum) + 0.5f;
        v0s = ((float)bin + frac / (float)cc) * 0.5f;
      }
      if (cum <= rr1 && rr1 < cum + cc) {
        float frac = (float)(rr1 - cum) + 0.5f;
        v1s = ((float)bin + frac / (float)cc) * 0.5f;
      }
    }
    cum += cc;
  }
  __syncthreads();
  if (t == 0) {
    float med = 0.5f * (v0s + v1s);
    float mean = (total > 0) ? (ssum[0] / (float)total) : 1.0f;
    float g = (med > 0.f) ? 1.0f / (med + 1e-6f) : 1.0f / (mean + 1e-6f);
    gptr[0] = g;
  }
}

// MAIN (MFMA, dbuf prefetch, R22: grid (64,32), 5 blocks/CU, setprio):
__global__ void __launch_bounds__(256, 5)
PrototypicalHead_6210522710389_kernel(
    const unsigned short* __restrict__ Gh, const unsigned short* __restrict__ Sh,
    const float* __restrict__ q2p, const float* __restrict__ s2,
    const float* __restrict__ svals, const float* __restrict__ gptr,
    float* __restrict__ part) {
  __shared__ unsigned short Bs[2][8192];   // 2 x 16 KB
  int t = threadIdx.x;
  int w = t >> 6, lane = t & 63;
  int l15 = lane & 15, quad = lane >> 4;
  int qt = blockIdx.x, sc = blockIdx.y;
  int qbase = qt * 128;
  float gamma = gptr[0];
  const float LOG2E = 1.44269504f;
  float c2 = 2.0f * gamma * LOG2E;       // exp2 folding: e^{-g*d2} = 2^{c2*a + cq + cs}

  // two A-fragment sets: rows [w*32, w*32+16) and [w*32+16, w*32+32)
  size_t agrp = (size_t)(qt * 8 + w * 2) * 4096;
  bf16x8 afrag[2][8];
#pragma unroll
  for (int s = 0; s < 2; ++s)
#pragma unroll
    for (int ks = 0; ks < 8; ++ks)
      afrag[s][ks] = *(const bf16x8*)&Gh[agrp + (size_t)s * 4096 + (size_t)ks * 512 + (size_t)lane * 8];

  float cqv[2][4];
#pragma unroll
  for (int s = 0; s < 2; ++s)
#pragma unroll
    for (int r = 0; r < 4; ++r)
      cqv[s][r] = -gamma * LOG2E * q2p[qbase + w * 32 + s * 16 + quad * 4 + r];

  float dAcc[2][4] = {}, nAcc[2][4] = {};

  // sc chunk = 512 s-rows = 16 tiles of 32 rows (16 KB each)
  const char* sbase_ptr = (const char*)&Sh[(size_t)(sc * 32) * 4096];
  // prologue: stage tile 0 into buf 0
#pragma unroll
  for (int i = 0; i < 4; ++i) {
    int c = i * 256 + t;
    gload_lds16(sbase_ptr + (size_t)c * 16, (char*)&Bs[0][0] + (size_t)c * 16);
  }
  __syncthreads();   // drains vmcnt(0): tile 0 ready

  for (int st = 0; st < 16; ++st) {
    int cur = st & 1;
    // issue next tile's staging FIRST (overlaps with compute below)
    if (st + 1 < 16) {
      const char* src = sbase_ptr + (size_t)(st + 1) * 16384;
      char* dst = (char*)&Bs[cur ^ 1][0];
#pragma unroll
      for (int i = 0; i < 4; ++i) {
        int c = i * 256 + t;
        gload_lds16(src + (size_t)c * 16, dst + (size_t)c * 16);
      }
    }

    f32x4 acc[2][2];
#pragma unroll
    for (int s = 0; s < 2; ++s)
#pragma unroll
      for (int nt = 0; nt < 2; ++nt)
        acc[s][nt] = (f32x4){0.f, 0.f, 0.f, 0.f};

    const unsigned short* B0 = &Bs[cur][lane * 8];
    __builtin_amdgcn_s_setprio(1);
#pragma unroll
    for (int ks = 0; ks < 8; ++ks) {
      bf16x8 f0 = *(const bf16x8*)(B0 + ks * 512);
      bf16x8 f1 = *(const bf16x8*)(B0 + 4096 + ks * 512);
      acc[0][0] = __builtin_amdgcn_mfma_f32_16x16x32_bf16(afrag[0][ks], f0, acc[0][0], 0, 0, 0);
      acc[1][0] = __builtin_amdgcn_mfma_f32_16x16x32_bf16(afrag[1][ks], f0, acc[1][0], 0, 0, 0);
      acc[0][1] = __builtin_amdgcn_mfma_f32_16x16x32_bf16(afrag[0][ks], f1, acc[0][1], 0, 0, 0);
      acc[1][1] = __builtin_amdgcn_mfma_f32_16x16x32_bf16(afrag[1][ks], f1, acc[1][1], 0, 0, 0);
    }
    __builtin_amdgcn_s_setprio(0);

    int sbase = sc * 512 + st * 32;
#pragma unroll
    for (int nt = 0; nt < 2; ++nt) {
      int scol = sbase + nt * 16 + l15;
      float cs = -gamma * LOG2E * s2[scol];
      float sv = svals[scol];
#pragma unroll
      for (int s = 0; s < 2; ++s)
#pragma unroll
        for (int r = 0; r < 4; ++r) {
          // exponent = log2e * -(gamma*(q2+s2-2a)); min(...,0) == the d2>=0 clamp
          float ex = exp2f(fminf(fmaf(c2, acc[s][nt][r], cqv[s][r] + cs), 0.0f));
          dAcc[s][r] += ex;
          nAcc[s][r] = fmaf(ex, sv, nAcc[s][r]);
        }
    }
    __syncthreads();   // vmcnt(0)+lgkmcnt(0)+barrier: next tile ready, buf reuse safe
  }
#pragma unroll
  for (int off = 8; off >= 1; off >>= 1)
#pragma unroll
    for (int s = 0; s < 2; ++s)
#pragma unroll
      for (int r = 0; r < 4; ++r) {
        dAcc[s][r] += __shfl_xor(dAcc[s][r], off);
        nAcc[s][r] += __shfl_xor(nAcc[s][r], off);
      }
  if (l15 == 0) {
#pragma unroll
    for (int s = 0; s < 2; ++s)
#pragma unroll
      for (int r = 0; r < 4; ++r) {
        size_t q = (size_t)qbase + w * 32 + s * 16 + quad * 4 + r;
        part[(q * 32 + sc) * 2 + 0] = dAcc[s][r];
        part[(q * 32 + sc) * 2 + 1] = nAcc[s][r];
      }
  }
}

__global__ void k_final_r22(const float* __restrict__ part, float* __restrict__ out1) {
  int q = blockIdx.x * 256 + threadIdx.x;
  const float* p = part + (size_t)q * 64;
  float d = 0.f, n = 0.f;
#pragma unroll
  for (int i = 0; i < 32; ++i) { d += p[2 * i]; n += p[2 * i + 1]; }
  out1[q] = n / d;
}

extern "C" void kernel_launch(void* const* d_in, const int* in_sizes, int n_in,
                              void* d_out, int out_size, void* d_ws, size_t ws_size,
                              hipStream_t stream) {
  (void)in_sizes; (void)n_in; (void)out_size; (void)ws_size;
  const float* SF = (const float*)d_in[0];   // fp32
  const int*   SL = (const int*)d_in[1];     // int32
  const float* SV = (const float*)d_in[2];   // fp32
  const float* QF = (const float*)d_in[3];   // fp32

  float* ws = (float*)d_ws;
  float* rnorm = ws + OFF_PSUM;              // 16384 row inv-norms (SF)
  float* musum = ws + OFF_MUSUM;
  float* ssum  = ws + OFF_SSUM;
  unsigned int* hist = (unsigned int*)(ws + OFF_HIST);
  float* protos= ws + OFF_PROTO;
  float* mu    = ws + OFF_MU;
  float* cov   = ws + OFF_COV;
  float* rows  = ws + OFF_ROWS;
  float* cptr  = ws + OFF_C;
  float* gptr  = ws + OFF_C + 1;
  float* X1 = ws + OFF_Y;  float* T = ws + OFF_T;  float* X2 = ws + OFF_Y2;
  float* s2 = ws + OFF_S2; float* q2p = ws + OFF_Q2P;
  float* part = ws + OFF_PART;
  float* G = ws + OFF_G;
  unsigned short* Sh = (unsigned short*)(ws + OFF_SH);
  unsigned short* Gh = (unsigned short*)(ws + OFF_GH);
  // proto-phase aliases (lifetimes end before overwriters run):
  float* pppart  = G;                        // proto partials (dead after proto_fin)
  float* cntpart = part;                     // counts (dead after proto_fin)
  float* qnorm   = ws + OFF_Y;               // 8192 Q inv-norms (dead before Newton)
  unsigned short* Ph = (unsigned short*)(ws + OFF_Y + 8192);  // proto frags (32 KB)
  unsigned short* Qh = Gh;                   // bf16 normalized Q (dead before swz(G))
  float* xtxpart = G;                        // xtx partials (dead after xtxcov)
  float* s2part  = X2;                       // s2 partials (X2 free post-Newton)

  float* out0 = (float*)d_out;                   // f32 log_probs [8192 x 64]
  float* out1 = out0 + (size_t)kNQ * kC;         // f32 predictions [8192]

  k_zero_r16<<<(int)((ZERO_FLOATS + 255) / 256), 256, 0, stream>>>(ws);

  // swizzled bf16 copy of support features
  k_swz_r16<<<kNS / 16, 256, 0, stream>>>(SF, Sh);

  // classification (atomic-free, MFMA logits)
  k_rnorm_r19<<<kNS / 4, 256, 0, stream>>>(SF, rnorm);
  k_paccum_r19<<<128, 256, 0, stream>>>(SF, SL, rnorm, pppart, cntpart);
  k_proto_fin_r19<<<kC, 256, 0, stream>>>(pppart, cntpart, protos);
  k_rnorm_r19<<<kNQ / 4, 256, 0, stream>>>(QF, qnorm);
  k_swzn_r22<<<kNQ / 16, 256, 0, stream>>>(QF, qnorm, Qh);
  k_swz_r16<<<kC / 16, 256, 0, stream>>>(protos, Ph);
  k_logits_mfma_r22<<<kNQ / 64, 256, 0, stream>>>(Qh, Ph, out0);

  // regression: mean, cov (K-split xtx, fused reduce+cov)
  k_colsum_r16<<<kNS / 64, 256, 0, stream>>>(SF, musum);
  k_mufin_r16<<<1, 256, 0, stream>>>(musum, mu);
  k_xtx_r22<<<dim3(16, 32), 256, 0, stream>>>(SF, xtxpart);
  k_xtxcov_r22<<<256, 256, 0, stream>>>(xtxpart, mu, cov);

  // Newton matrix inverse: X <- X (2I - cov X), X0 = I/c, 6 iterations
  k_rowabs_r16<<<256, 64, 0, stream>>>(cov, rows);
  k_cnorm_r16<<<1, 64, 0, stream>>>(rows, cptr);
  k_newt_init_r16<<<256, 256, 0, stream>>>(cptr, X1);
  float *Xc = X1, *T_ = T, *Xn = X2;
  for (int it = 0; it < 6; ++it) {
    k_newt_mm_r17<<<256, 1024, 0, stream>>>(cov, Xc, T_, 1);
    k_newt_mm_r17<<<256, 1024, 0, stream>>>(Xc, T_, Xn, 0);
    float* tmp = Xc; Xc = Xn; Xn = tmp;
  }
  float* M = Xc;   // cov^-1 (= X1 after even number of swaps)

  // G = (Q - mu) @ M, swizzled bf16 copy, scalar row terms
  k_G_r16<<<dim3(4, kNQ / 64), 256, 0, stream>>>(QF, mu, M, G);
  k_swz_r16<<<kNQ / 16, 256, 0, stream>>>(G, Gh);
  k_q2p_r16<<<kNQ / 4, 256, 0, stream>>>(G, QF, mu, q2p);
  k_s2_r22<<<dim3(kNS / 64, 4), 256, 0, stream>>>(SF, mu, M, s2part);
  k_s2fin_r22<<<kNS / 256, 256, 0, stream>>>(s2part, s2);

  // sampled median -> gamma (parallel)
  k_median_r16<<<dim3(32, 16), 256, 0, stream>>>(G, SF, q2p, s2, hist, ssum);
  k_gamma_r16<<<1, 256, 0, stream>>>(hist, ssum, gptr);

  // MFMA fused cdist^2 + softmax numer/denom, then finalize
  PrototypicalHead_6210522710389_kernel<<<dim3(64, 32), 256, 0, stream>>>(
      Gh, Sh, q2p, s2, SV, gptr, part);
  k_final_r22<<<kNQ / 256, 256, 0, stream>>>(part, out1);
}

// Round 7
// 420.323 us; speedup vs baseline: 1.7855x; 1.2232x over previous
//
#include <hip/hip_runtime.h>
#include <hip/hip_bf16.h>

// Problem dims (fixed by setup_inputs)
constexpr int kNS = 16384;   // support rows
constexpr int kNQ = 8192;    // query rows
constexpr int kD  = 256;     // feature dim
constexpr int kC  = 64;      // classes

// R22 PASSED (514 us) but main kernel REGRESSED 96->191 us: grid 2048 >
// residency ~1280 desynchronized the tile streams -> L2 sharing collapsed
// (FETCH 35->387 MB, near the 512 MB no-sharing worst case). Side fixes
// (xtx split-K, s2 grid-y, MFMA logits) gained ~100 us and are kept.
// R23: main kernel back to R21 shape — grid (64,16), 1024 blocks (= all
// resident), sc-chunk 1024 rows = 32 tiles, 2x16KB dbuf, lb(256,4) — which
// measured 96 us / 35 MB fetch. setprio kept.

// ---------------- workspace layout (float offsets into d_ws), ~24.4 MB ----
constexpr size_t OFF_PSUM  = 0;          // rnorm[16384]
constexpr size_t OFF_MUSUM = 16448;
constexpr size_t OFF_XTX   = 16704;      // (unused)
constexpr size_t OFF_HIST  = 82240;
constexpr size_t OFF_SSUM  = 84288;
constexpr size_t ZERO_FLOATS = 84352;
constexpr size_t OFF_PROTO = 84352;
constexpr size_t OFF_MU    = 100736;
constexpr size_t OFF_COV   = 100992;
constexpr size_t OFF_ROWS  = 166528;
constexpr size_t OFF_C     = 166784;
constexpr size_t OFF_Y     = 166800;     // Newton X ping; also qnorm+Ph (proto phase)
constexpr size_t OFF_T     = 297872;     // Newton T
constexpr size_t OFF_Y2    = 363408;     // Newton X pong; also s2 partials (post-Newton)
constexpr size_t OFF_S2    = 560016;
constexpr size_t OFF_Q2P   = 576400;
constexpr size_t OFF_PART  = 584592;     // 8192*16*2 floats (ends exactly at OFF_G)
constexpr size_t OFF_G     = 846736;     // 8192*256 f32; also proto/xtx partials
constexpr size_t OFF_SH    = 2943888;    // 16384*256 bf16 swizzled
constexpr size_t OFF_GH    = 5041040;    // 8192*256 bf16 swizzled; also Qh (proto phase)

typedef __attribute__((ext_vector_type(8))) short bf16x8;
typedef __attribute__((ext_vector_type(4))) float f32x4;

__device__ __forceinline__ unsigned short f2bf(float f) {
  unsigned int w; __builtin_memcpy(&w, &f, 4);
  unsigned int r = (w + 0x7FFFu + ((w >> 16) & 1u)) >> 16;
  return (unsigned short)r;
}

__device__ __forceinline__ float waveReduceSum(float v) {
#pragma unroll
  for (int off = 32; off > 0; off >>= 1) v += __shfl_xor(v, off);
  return v;
}
__device__ __forceinline__ float waveReduceMax(float v) {
#pragma unroll
  for (int off = 32; off > 0; off >>= 1) v = fmaxf(v, __shfl_xor(v, off));
  return v;
}
__device__ __forceinline__ void fma16(float acc[4][4], float4 a, float4 b) {
  acc[0][0] += a.x*b.x; acc[0][1] += a.x*b.y; acc[0][2] += a.x*b.z; acc[0][3] += a.x*b.w;
  acc[1][0] += a.y*b.x; acc[1][1] += a.y*b.y; acc[1][2] += a.y*b.z; acc[1][3] += a.y*b.w;
  acc[2][0] += a.z*b.x; acc[2][1] += a.z*b.y; acc[2][2] += a.z*b.z; acc[2][3] += a.z*b.w;
  acc[3][0] += a.w*b.x; acc[3][1] += a.w*b.y; acc[3][2] += a.w*b.z; acc[3][3] += a.w*b.w;
}

// async global -> LDS, 16 B per lane
__device__ __forceinline__ void gload_lds16(const void* g, void* l) {
  __builtin_amdgcn_global_load_lds(
      (const __attribute__((address_space(1))) unsigned int*)g,
      (__attribute__((address_space(3))) unsigned int*)l, 16, 0, 0);
}

__global__ void k_zero_r16(float* __restrict__ ws) {
  size_t i = (size_t)blockIdx.x * 256 + threadIdx.x;
  if (i < ZERO_FLOATS) ws[i] = 0.f;
}

// f32 [rows x 256] -> bf16 fragment-major swizzle (one block per 16-row group)
__global__ void k_swz_r16(const float* __restrict__ in, unsigned short* __restrict__ out) {
  int g = blockIdx.x, t = threadIdx.x;
  int ks = t >> 5;
  size_t gbase = (size_t)g * 4096;
#pragma unroll
  for (int f = 0; f < 2; ++f) {
    int lane = (2 * t + f) & 63;
    int q = lane >> 4, r = lane & 15;
    const float* src = &in[(size_t)(g * 16 + r) * kD + ks * 32 + q * 8];
    float4 v0 = *(const float4*)src;
    float4 v1 = *(const float4*)(src + 4);
    ushort4 o0, o1;
    o0.x = f2bf(v0.x); o0.y = f2bf(v0.y); o0.z = f2bf(v0.z); o0.w = f2bf(v0.w);
    o1.x = f2bf(v1.x); o1.y = f2bf(v1.y); o1.z = f2bf(v1.z); o1.w = f2bf(v1.w);
    unsigned short* dst = &out[gbase + (size_t)ks * 512 + (size_t)lane * 8];
    *(ushort4*)dst = o0;
    *(ushort4*)(dst + 4) = o1;
  }
}

// swizzle with per-row scale (row-normalized bf16 copy)
__global__ void k_swzn_r22(const float* __restrict__ in, const float* __restrict__ scale,
                           unsigned short* __restrict__ out) {
  int g = blockIdx.x, t = threadIdx.x;
  int ks = t >> 5;
  size_t gbase = (size_t)g * 4096;
#pragma unroll
  for (int f = 0; f < 2; ++f) {
    int lane = (2 * t + f) & 63;
    int q = lane >> 4, r = lane & 15;
    float n = scale[g * 16 + r];
    const float* src = &in[(size_t)(g * 16 + r) * kD + ks * 32 + q * 8];
    float4 v0 = *(const float4*)src;
    float4 v1 = *(const float4*)(src + 4);
    ushort4 o0, o1;
    o0.x = f2bf(v0.x * n); o0.y = f2bf(v0.y * n); o0.z = f2bf(v0.z * n); o0.w = f2bf(v0.w * n);
    o1.x = f2bf(v1.x * n); o1.y = f2bf(v1.y * n); o1.z = f2bf(v1.z * n); o1.w = f2bf(v1.w * n);
    unsigned short* dst = &out[gbase + (size_t)ks * 512 + (size_t)lane * 8];
    *(ushort4*)dst = o0;
    *(ushort4*)(dst + 4) = o1;
  }
}

// ---------------- classification path (atomic-free) ----------------
// wave per row: rnorm[i] = 1 / max(||X_i||, 1e-8)
__global__ void k_rnorm_r19(const float* __restrict__ X, float* __restrict__ rnorm) {
  int w = threadIdx.x >> 6, lane = threadIdx.x & 63;
  int row = blockIdx.x * 4 + w;
  float4 v = *(const float4*)&X[(size_t)row * kD + lane * 4];
  float ss = waveReduceSum(v.x*v.x + v.y*v.y + v.z*v.z + v.w*v.w);
  if (lane == 0) rnorm[row] = 1.0f / fmaxf(sqrtf(ss), 1e-8f);
}

// thread t owns dim t; LDS acc[64][256], no atomics. 128 blocks x 128 rows.
__global__ void k_paccum_r19(const float* __restrict__ X, const int* __restrict__ lab,
                             const float* __restrict__ rnorm,
                             float* __restrict__ partial, float* __restrict__ cntpart) {
  __shared__ float acc[kC * kD];   // 64 KB
  int t = threadIdx.x, b = blockIdx.x;
  for (int i = t; i < kC * kD; i += 256) acc[i] = 0.f;
  __syncthreads();
  int r0 = b * 128;
  float myCnt = 0.f;
  for (int r = 0; r < 128; r += 8) {
    int row = r0 + r;
    int   c0 = lab[row + 0], c1 = lab[row + 1], c2 = lab[row + 2], c3 = lab[row + 3];
    int   c4 = lab[row + 4], c5 = lab[row + 5], c6 = lab[row + 6], c7 = lab[row + 7];
    float n0 = rnorm[row + 0], n1 = rnorm[row + 1], n2 = rnorm[row + 2], n3 = rnorm[row + 3];
    float n4 = rnorm[row + 4], n5 = rnorm[row + 5], n6 = rnorm[row + 6], n7 = rnorm[row + 7];
    float x0 = X[(size_t)(row + 0) * kD + t];
    float x1 = X[(size_t)(row + 1) * kD + t];
    float x2 = X[(size_t)(row + 2) * kD + t];
    float x3 = X[(size_t)(row + 3) * kD + t];
    float x4 = X[(size_t)(row + 4) * kD + t];
    float x5 = X[(size_t)(row + 5) * kD + t];
    float x6 = X[(size_t)(row + 6) * kD + t];
    float x7 = X[(size_t)(row + 7) * kD + t];
    acc[c0 * kD + t] += x0 * n0;
    acc[c1 * kD + t] += x1 * n1;
    acc[c2 * kD + t] += x2 * n2;
    acc[c3 * kD + t] += x3 * n3;
    acc[c4 * kD + t] += x4 * n4;
    acc[c5 * kD + t] += x5 * n5;
    acc[c6 * kD + t] += x6 * n6;
    acc[c7 * kD + t] += x7 * n7;
    myCnt += (t == c0) ? 1.f : 0.f; myCnt += (t == c1) ? 1.f : 0.f;
    myCnt += (t == c2) ? 1.f : 0.f; myCnt += (t == c3) ? 1.f : 0.f;
    myCnt += (t == c4) ? 1.f : 0.f; myCnt += (t == c5) ? 1.f : 0.f;
    myCnt += (t == c6) ? 1.f : 0.f; myCnt += (t == c7) ? 1.f : 0.f;
  }
  __syncthreads();
  float* pb = partial + (size_t)b * (kC * kD);
  for (int c = 0; c < kC; ++c) pb[c * kD + t] = acc[c * kD + t];
  if (t < kC) cntpart[b * kC + t] = myCnt;
}

// one block per class: reduce 128 partials, divide by count, L2-normalize
__global__ void k_proto_fin_r19(const float* __restrict__ partial,
                                const float* __restrict__ cntpart,
                                float* __restrict__ protos) {
  __shared__ float cs[128];
  __shared__ float wred[4];
  __shared__ float cntS, invS;
  int c = blockIdx.x, t = threadIdx.x;
  if (t < 128) cs[t] = cntpart[t * kC + c];
  __syncthreads();
  float s = 0.f;
  const float* p = partial + (size_t)c * kD + t;
  for (int b = 0; b < 128; ++b) s += p[(size_t)b * (kC * kD)];
  if (t < 64) {
    float cv = cs[t] + cs[t + 64];
    cv = waveReduceSum(cv);
    if (t == 0) cntS = fmaxf(cv, 1.0f);
  }
  __syncthreads();
  float v = s / cntS;
  float ss = waveReduceSum(v * v);
  if ((t & 63) == 0) wred[t >> 6] = ss;
  __syncthreads();
  if (t == 0) invS = 1.0f / fmaxf(sqrtf(wred[0] + wred[1] + wred[2] + wred[3]), 1e-8f);
  __syncthreads();
  protos[(size_t)c * kD + t] = v * invS;
}

// MFMA logits + log-softmax. grid 128 blocks; wave: 16 q-rows x 64 classes.
__global__ void k_logits_mfma_r22(const unsigned short* __restrict__ Qh,
                                  const unsigned short* __restrict__ Ph,
                                  float* __restrict__ out0) {
  int t = threadIdx.x;
  int w = t >> 6, lane = t & 63;
  int l15 = lane & 15, quad = lane >> 4;
  int qb = blockIdx.x * 64;

  size_t agrp = (size_t)(blockIdx.x * 4 + w) * 4096;
  bf16x8 afrag[8];
#pragma unroll
  for (int ks = 0; ks < 8; ++ks)
    afrag[ks] = *(const bf16x8*)&Qh[agrp + (size_t)ks * 512 + (size_t)lane * 8];

  f32x4 acc0 = {0.f,0.f,0.f,0.f}, acc1 = {0.f,0.f,0.f,0.f};
  f32x4 acc2 = {0.f,0.f,0.f,0.f}, acc3 = {0.f,0.f,0.f,0.f};
#pragma unroll
  for (int ks = 0; ks < 8; ++ks) {
    bf16x8 b0 = *(const bf16x8*)&Ph[(size_t)0 * 4096 + ks * 512 + (size_t)lane * 8];
    bf16x8 b1 = *(const bf16x8*)&Ph[(size_t)1 * 4096 + ks * 512 + (size_t)lane * 8];
    bf16x8 b2 = *(const bf16x8*)&Ph[(size_t)2 * 4096 + ks * 512 + (size_t)lane * 8];
    bf16x8 b3 = *(const bf16x8*)&Ph[(size_t)3 * 4096 + ks * 512 + (size_t)lane * 8];
    acc0 = __builtin_amdgcn_mfma_f32_16x16x32_bf16(afrag[ks], b0, acc0, 0, 0, 0);
    acc1 = __builtin_amdgcn_mfma_f32_16x16x32_bf16(afrag[ks], b1, acc1, 0, 0, 0);
    acc2 = __builtin_amdgcn_mfma_f32_16x16x32_bf16(afrag[ks], b2, acc2, 0, 0, 0);
    acc3 = __builtin_amdgcn_mfma_f32_16x16x32_bf16(afrag[ks], b3, acc3, 0, 0, 0);
  }
#pragma unroll
  for (int r = 0; r < 4; ++r) {
    float m = fmaxf(fmaxf(acc0[r], acc1[r]), fmaxf(acc2[r], acc3[r]));
#pragma unroll
    for (int off = 8; off >= 1; off >>= 1) m = fmaxf(m, __shfl_xor(m, off));
    float e = expf(acc0[r] - m) + expf(acc1[r] - m) + expf(acc2[r] - m) + expf(acc3[r] - m);
#pragma unroll
    for (int off = 8; off >= 1; off >>= 1) e += __shfl_xor(e, off);
    float lse = m + logf(e);
    size_t row = (size_t)qb + w * 16 + quad * 4 + r;
    out0[row * kC + 0 * 16 + l15] = acc0[r] - lse;
    out0[row * kC + 1 * 16 + l15] = acc1[r] - lse;
    out0[row * kC + 2 * 16 + l15] = acc2[r] - lse;
    out0[row * kC + 3 * 16 + l15] = acc3[r] - lse;
  }
}

// ---------------- regression path ----------------
__global__ void k_colsum_r16(const float* __restrict__ X, float* __restrict__ musum) {
  int t = threadIdx.x;
  int r0 = blockIdx.x * 64;
  float s = 0.f;
  for (int r = 0; r < 64; ++r) s += X[(size_t)(r0 + r) * kD + t];
  atomicAdd(&musum[t], s);
}
__global__ void k_mufin_r16(const float* __restrict__ musum, float* __restrict__ mu) {
  int t = threadIdx.x;
  mu[t] = musum[t] * (1.0f / (float)kNS);
}

// xtx K-split x32: grid (16 tiles, 32 K-chunks of 512), partials (no atomics)
__global__ void k_xtx_r22(const float* __restrict__ X, float* __restrict__ part) {
  __shared__ alignas(16) float As[16][68];
  __shared__ alignas(16) float Bs[16][68];
  int t = threadIdx.x, tx = t & 15, ty = t >> 4;
  int ab = (blockIdx.x >> 2) * 64, bb = (blockIdx.x & 3) * 64;
  int k0b = blockIdx.y * 512;
  float acc[4][4] = {};
  for (int k0 = 0; k0 < 512; k0 += 16) {
    __syncthreads();
    int j = t & 63, kr0 = t >> 6;
#pragma unroll
    for (int p = 0; p < 4; ++p) {
      int kr = kr0 + p * 4;
      size_t base = (size_t)(k0b + k0 + kr) * kD;
      As[kr][j] = X[base + ab + j];
      Bs[kr][j] = X[base + bb + j];
    }
    __syncthreads();
#pragma unroll
    for (int k = 0; k < 16; ++k) {
      float4 a = *(const float4*)&As[k][ty * 4];
      float4 b = *(const float4*)&Bs[k][tx * 4];
      fma16(acc, a, b);
    }
  }
  float* pb = part + ((size_t)blockIdx.y * 16 + blockIdx.x) * 4096;
#pragma unroll
  for (int r = 0; r < 4; ++r) {
    float4 o = {acc[r][0], acc[r][1], acc[r][2], acc[r][3]};
    *(float4*)&pb[(size_t)(ty * 4 + r) * 64 + tx * 4] = o;
  }
}

// reduce 32 xtx partials + form cov directly
__global__ void k_xtxcov_r22(const float* __restrict__ part, const float* __restrict__ mu,
                             float* __restrict__ cov) {
  int i = blockIdx.x, j = threadIdx.x;
  int tile = (i >> 6) * 4 + (j >> 6);
  int local = (i & 63) * 64 + (j & 63);
  const float* p = part + (size_t)tile * 4096 + local;
  float s = 0.f;
#pragma unroll 8
  for (int ky = 0; ky < 32; ++ky) s += p[(size_t)ky * 65536];
  float v = (s - (float)kNS * mu[i] * mu[j]) * (1.0f / (float)(kNS - 1));
  if (i == j) v += 1e-4f;
  cov[(size_t)i * kD + j] = v;
}

__global__ void k_rowabs_r16(const float* __restrict__ cov, float* __restrict__ rows) {
  int row = blockIdx.x, lane = threadIdx.x;
  float4 v = *(const float4*)&cov[(size_t)row * kD + lane * 4];
  float s = waveReduceSum(fabsf(v.x) + fabsf(v.y) + fabsf(v.z) + fabsf(v.w));
  if (lane == 0) rows[row] = s;
}
__global__ void k_cnorm_r16(const float* __restrict__ rows, float* __restrict__ cptr) {
  int lane = threadIdx.x;
  float m = fmaxf(fmaxf(rows[lane], rows[lane + 64]),
                  fmaxf(rows[lane + 128], rows[lane + 192]));
  m = waveReduceMax(m);
  if (lane == 0) cptr[0] = m;
}
// X0 = I / c
__global__ void k_newt_init_r16(const float* __restrict__ cptr, float* __restrict__ X) {
  int i = blockIdx.x, j = threadIdx.x;
  X[(size_t)i * kD + j] = (i == j) ? (1.0f / cptr[0]) : 0.0f;
}

// one 256x256 matmul step, 1024 threads (4-way split-k + LDS reduce).
// isT=1: Out = 2I - A @ Xin.  isT=0: Out = A @ Xin  (A indexed by row).
__global__ void __launch_bounds__(1024)
k_newt_mm_r17(const float* __restrict__ A, const float* __restrict__ Xin,
              float* __restrict__ Out, int isT) {
  __shared__ float a_s[256];
  __shared__ float red[3][256];
  int i = blockIdx.x, t = threadIdx.x;
  int j = t & 255, kq = t >> 8;
  if (t < 256) a_s[t] = A[(size_t)i * kD + t];
  __syncthreads();
  int k0 = kq * 64;
  const float* Xp = &Xin[(size_t)k0 * kD + j];
  float s0 = 0.f, s1 = 0.f, s2 = 0.f, s3 = 0.f;
#pragma unroll 4
  for (int k = 0; k < 64; k += 4) {
    s0 = fmaf(a_s[k0 + k + 0], Xp[0 * kD], s0);
    s1 = fmaf(a_s[k0 + k + 1], Xp[1 * kD], s1);
    s2 = fmaf(a_s[k0 + k + 2], Xp[2 * kD], s2);
    s3 = fmaf(a_s[k0 + k + 3], Xp[3 * kD], s3);
    Xp += 4 * kD;
  }
  float s = (s0 + s1) + (s2 + s3);
  if (kq) red[kq - 1][j] = s;
  __syncthreads();
  if (t < 256) {
    float tot = s + red[0][j] + red[1][j] + red[2][j];
    float o = isT ? ((i == j ? 2.0f : 0.0f) - tot) : tot;
    Out[(size_t)i * kD + j] = o;
  }
}

// G = (Q - mu) @ M
__global__ void k_G_r16(const float* __restrict__ Q, const float* __restrict__ mu,
                        const float* __restrict__ M, float* __restrict__ G) {
  __shared__ alignas(16) float As[16][68];
  __shared__ alignas(16) float Bs[16][68];
  int t = threadIdx.x, tx = t & 15, ty = t >> 4;
  int nb = blockIdx.x * 64;
  int mb = blockIdx.y * 64;
  float acc[4][4] = {};
  for (int k0 = 0; k0 < 256; k0 += 16) {
    __syncthreads();
    {
      int kk = t & 15, m0 = t >> 4;
      float muk = mu[k0 + kk];
#pragma unroll
      for (int p = 0; p < 4; ++p) {
        int m = m0 + p * 16;
        As[kk][m] = Q[(size_t)(mb + m) * kD + k0 + kk] - muk;
      }
      int j = t & 63, kr0 = t >> 6;
#pragma unroll
      for (int p = 0; p < 4; ++p) {
        int kr = kr0 + p * 4;
        Bs[kr][j] = M[(size_t)(k0 + kr) * kD + nb + j];
      }
    }
    __syncthreads();
#pragma unroll
    for (int k = 0; k < 16; ++k) {
      float4 a = *(const float4*)&As[k][ty * 4];
      float4 b = *(const float4*)&Bs[k][tx * 4];
      fma16(acc, a, b);
    }
  }
#pragma unroll
  for (int r = 0; r < 4; ++r) {
    int gi = mb + ty * 4 + r;
    float4 o = {acc[r][0], acc[r][1], acc[r][2], acc[r][3]};
    *(float4*)&G[(size_t)gi * kD + nb + tx * 4] = o;
  }
}

// q2p[i] = G_i . (Q_i + mu)
__global__ void k_q2p_r16(const float* __restrict__ G, const float* __restrict__ Q,
                          const float* __restrict__ mu, float* __restrict__ q2p) {
  int w = threadIdx.x >> 6, lane = threadIdx.x & 63;
  int row = blockIdx.x * 4 + w;
  float4 g = *(const float4*)&G[(size_t)row * kD + lane * 4];
  float4 q = *(const float4*)&Q[(size_t)row * kD + lane * 4];
  float4 m = *(const float4*)&mu[lane * 4];
  float ss = waveReduceSum(g.x*(q.x+m.x) + g.y*(q.y+m.y) + g.z*(q.z+m.z) + g.w*(q.w+m.w));
  if (lane == 0) q2p[row] = ss;
}

// s2 with ntile = blockIdx.y (grid (256,4)), partials (no atomics)
__global__ void k_s2_r22(const float* __restrict__ S, const float* __restrict__ mu,
                         const float* __restrict__ M, float* __restrict__ s2part) {
  __shared__ alignas(16) float As[16][68];
  __shared__ alignas(16) float Bs[16][68];
  __shared__ float red[64][17];
  int t = threadIdx.x, tx = t & 15, ty = t >> 4;
  int mb = blockIdx.x * 64;
  int nb = blockIdx.y * 64;
  float partial[4] = {0.f, 0.f, 0.f, 0.f};
  float acc[4][4] = {};
  for (int k0 = 0; k0 < 256; k0 += 16) {
    __syncthreads();
    {
      int kk = t & 15, m0 = t >> 4;
      float muk = mu[k0 + kk];
#pragma unroll
      for (int p = 0; p < 4; ++p) {
        int m = m0 + p * 16;
        As[kk][m] = S[(size_t)(mb + m) * kD + k0 + kk] - muk;
      }
      int j = t & 63, kr0 = t >> 6;
#pragma unroll
      for (int p = 0; p < 4; ++p) {
        int kr = kr0 + p * 4;
        Bs[kr][j] = M[(size_t)(k0 + kr) * kD + nb + j];
      }
    }
    __syncthreads();
#pragma unroll
    for (int k = 0; k < 16; ++k) {
      float4 a = *(const float4*)&As[k][ty * 4];
      float4 b = *(const float4*)&Bs[k][tx * 4];
      fma16(acc, a, b);
    }
  }
#pragma unroll
  for (int r = 0; r < 4; ++r) {
    int gi = mb + ty * 4 + r;
#pragma unroll
    for (int c = 0; c < 4; ++c) {
      int gj = nb + tx * 4 + c;
      partial[r] += acc[r][c] * (S[(size_t)gi * kD + gj] - mu[gj]);
    }
  }
  __syncthreads();
#pragma unroll
  for (int r = 0; r < 4; ++r) red[ty * 4 + r][tx] = partial[r];
  __syncthreads();
  if (t < 64) {
    float s = 0.f;
#pragma unroll
    for (int x = 0; x < 16; ++x) s += red[t][x];
    s2part[(size_t)blockIdx.y * kNS + mb + t] = s;
  }
}
__global__ void k_s2fin_r22(const float* __restrict__ sp, float* __restrict__ s2) {
  int i = blockIdx.x * 256 + threadIdx.x;
  s2[i] = sp[i] + sp[kNS + i] + sp[2 * kNS + i] + sp[3 * kNS + i];
}

// GEMM-tiled sampled-median histogram
__global__ void k_median_r16(const float* __restrict__ G, const float* __restrict__ S,
                             const float* __restrict__ q2p, const float* __restrict__ s2,
                             unsigned int* __restrict__ hist, float* __restrict__ ssum) {
  __shared__ alignas(16) float As[16][68];
  __shared__ alignas(16) float Bs[16][68];
  __shared__ unsigned int h[2048];
  __shared__ float fred[4];
  int t = threadIdx.x, tx = t & 15, ty = t >> 4;
  int stile = blockIdx.x, qtile = blockIdx.y;
  for (int i = t; i < 2048; i += 256) h[i] = 0u;

  float acc[4][4] = {};
  for (int k0 = 0; k0 < 256; k0 += 16) {
    __syncthreads();
    {
      int kk = t & 15, m0 = t >> 4;
#pragma unroll
      for (int p = 0; p < 4; ++p) {
        int m = m0 + p * 16;
        As[kk][m] = G[(size_t)((qtile * 64 + m) * 8) * kD + k0 + kk];
        Bs[kk][m] = S[(size_t)((stile * 64 + m) * 8) * kD + k0 + kk];
      }
    }
    __syncthreads();
#pragma unroll
    for (int k = 0; k < 16; ++k) {
      float4 a = *(const float4*)&As[k][ty * 4];
      float4 b = *(const float4*)&Bs[k][tx * 4];
      fma16(acc, a, b);
    }
  }
  float fsum = 0.f;
#pragma unroll
  for (int r = 0; r < 4; ++r) {
    int qi = (qtile * 64 + ty * 4 + r) * 8;
    float q2v = q2p[qi];
#pragma unroll
    for (int c = 0; c < 4; ++c) {
      int sj = (stile * 64 + tx * 4 + c) * 8;
      float d2 = fmaxf(q2v + s2[sj] - 2.0f * acc[r][c], 0.0f);
      fsum += d2;
      int bin = (int)(d2 * 2.0f);
      bin = bin > 2047 ? 2047 : bin;
      atomicAdd(&h[bin], 1u);
    }
  }
  float wsum = waveReduceSum(fsum);
  if ((t & 63) == 0) fred[t >> 6] = wsum;
  __syncthreads();
  if (t == 0) atomicAdd(ssum, fred[0] + fred[1] + fred[2] + fred[3]);
  for (int i = t; i < 2048; i += 256)
    if (h[i]) atomicAdd(&hist[i], h[i]);
}

// Parallel median + gamma: 256 threads x 8 bins, LDS scan.
__global__ void k_gamma_r16(const unsigned int* __restrict__ hist,
                            const float* __restrict__ ssum, float* __restrict__ gptr) {
  __shared__ unsigned int ps[256];
  __shared__ float v0s, v1s;
  int t = threadIdx.x;
  unsigned int mine[8];
  unsigned int c = 0;
#pragma unroll
  for (int j = 0; j < 8; ++j) { mine[j] = hist[t * 8 + j]; c += mine[j]; }
  ps[t] = c;
  __syncthreads();
  // Hillis-Steele inclusive scan
  for (int off = 1; off < 256; off <<= 1) {
    unsigned int v = (t >= off) ? ps[t - off] : 0u;
    __syncthreads();
    ps[t] += v;
    __syncthreads();
  }
  unsigned int total = ps[255];
  unsigned int before = ps[t] - c;      // exclusive prefix for my 8 bins
  if (t == 0) { v0s = 0.f; v1s = 0.f; }
  __syncthreads();
  unsigned int rr0 = (total - 1) / 2, rr1 = total / 2;
  unsigned int cum = before;
#pragma unroll
  for (int j = 0; j < 8; ++j) {
    unsigned int cc = mine[j];
    if (cc > 0) {
      int bin = t * 8 + j;
      if (cum <= rr0 && rr0 < cum + cc) {
        float frac = (float)(rr0 - cum) + 0.5f;
        v0s = ((float)bin + frac / (float)cc) * 0.5f;
      }
      if (cum <= rr1 && rr1 < cum + cc) {
        float frac = (float)(rr1 - cum) + 0.5f;
        v1s = ((float)bin + frac / (float)cc) * 0.5f;
      }
    }
    cum += cc;
  }
  __syncthreads();
  if (t == 0) {
    float med = 0.5f * (v0s + v1s);
    float mean = (total > 0) ? (ssum[0] / (float)total) : 1.0f;
    float g = (med > 0.f) ? 1.0f / (med + 1e-6f) : 1.0f / (mean + 1e-6f);
    gptr[0] = g;
  }
}

// MAIN (MFMA, dbuf prefetch, R23: back to grid (64,16), 1024 blocks = all
// resident -> synchronized tile streams share L2; setprio kept):
__global__ void __launch_bounds__(256, 4)
PrototypicalHead_6210522710389_kernel(
    const unsigned short* __restrict__ Gh, const unsigned short* __restrict__ Sh,
    const float* __restrict__ q2p, const float* __restrict__ s2,
    const float* __restrict__ svals, const float* __restrict__ gptr,
    float* __restrict__ part) {
  __shared__ unsigned short Bs[2][8192];   // 2 x 16 KB
  int t = threadIdx.x;
  int w = t >> 6, lane = t & 63;
  int l15 = lane & 15, quad = lane >> 4;
  int qt = blockIdx.x, sc = blockIdx.y;
  int qbase = qt * 128;
  float gamma = gptr[0];
  const float LOG2E = 1.44269504f;
  float c2 = 2.0f * gamma * LOG2E;       // exp2 folding: e^{-g*d2} = 2^{c2*a + cq + cs}

  // two A-fragment sets: rows [w*32, w*32+16) and [w*32+16, w*32+32)
  size_t agrp = (size_t)(qt * 8 + w * 2) * 4096;
  bf16x8 afrag[2][8];
#pragma unroll
  for (int s = 0; s < 2; ++s)
#pragma unroll
    for (int ks = 0; ks < 8; ++ks)
      afrag[s][ks] = *(const bf16x8*)&Gh[agrp + (size_t)s * 4096 + (size_t)ks * 512 + (size_t)lane * 8];

  float cqv[2][4];
#pragma unroll
  for (int s = 0; s < 2; ++s)
#pragma unroll
    for (int r = 0; r < 4; ++r)
      cqv[s][r] = -gamma * LOG2E * q2p[qbase + w * 32 + s * 16 + quad * 4 + r];

  float dAcc[2][4] = {}, nAcc[2][4] = {};

  // sc chunk = 1024 s-rows = 32 tiles of 32 rows (16 KB each)
  const char* sbase_ptr = (const char*)&Sh[(size_t)(sc * 64) * 4096];
  // prologue: stage tile 0 into buf 0
#pragma unroll
  for (int i = 0; i < 4; ++i) {
    int c = i * 256 + t;
    gload_lds16(sbase_ptr + (size_t)c * 16, (char*)&Bs[0][0] + (size_t)c * 16);
  }
  __syncthreads();   // drains vmcnt(0): tile 0 ready

  for (int st = 0; st < 32; ++st) {
    int cur = st & 1;
    // issue next tile's staging FIRST (overlaps with compute below)
    if (st + 1 < 32) {
      const char* src = sbase_ptr + (size_t)(st + 1) * 16384;
      char* dst = (char*)&Bs[cur ^ 1][0];
#pragma unroll
      for (int i = 0; i < 4; ++i) {
        int c = i * 256 + t;
        gload_lds16(src + (size_t)c * 16, dst + (size_t)c * 16);
      }
    }

    f32x4 acc[2][2];
#pragma unroll
    for (int s = 0; s < 2; ++s)
#pragma unroll
      for (int nt = 0; nt < 2; ++nt)
        acc[s][nt] = (f32x4){0.f, 0.f, 0.f, 0.f};

    const unsigned short* B0 = &Bs[cur][lane * 8];
    __builtin_amdgcn_s_setprio(1);
#pragma unroll
    for (int ks = 0; ks < 8; ++ks) {
      bf16x8 f0 = *(const bf16x8*)(B0 + ks * 512);
      bf16x8 f1 = *(const bf16x8*)(B0 + 4096 + ks * 512);
      acc[0][0] = __builtin_amdgcn_mfma_f32_16x16x32_bf16(afrag[0][ks], f0, acc[0][0], 0, 0, 0);
      acc[1][0] = __builtin_amdgcn_mfma_f32_16x16x32_bf16(afrag[1][ks], f0, acc[1][0], 0, 0, 0);
      acc[0][1] = __builtin_amdgcn_mfma_f32_16x16x32_bf16(afrag[0][ks], f1, acc[0][1], 0, 0, 0);
      acc[1][1] = __builtin_amdgcn_mfma_f32_16x16x32_bf16(afrag[1][ks], f1, acc[1][1], 0, 0, 0);
    }
    __builtin_amdgcn_s_setprio(0);

    int sbase = sc * 1024 + st * 32;
#pragma unroll
    for (int nt = 0; nt < 2; ++nt) {
      int scol = sbase + nt * 16 + l15;
      float cs = -gamma * LOG2E * s2[scol];
      float sv = svals[scol];
#pragma unroll
      for (int s = 0; s < 2; ++s)
#pragma unroll
        for (int r = 0; r < 4; ++r) {
          // exponent = log2e * -(gamma*(q2+s2-2a)); min(...,0) == the d2>=0 clamp
          float ex = exp2f(fminf(fmaf(c2, acc[s][nt][r], cqv[s][r] + cs), 0.0f));
          dAcc[s][r] += ex;
          nAcc[s][r] = fmaf(ex, sv, nAcc[s][r]);
        }
    }
    __syncthreads();   // vmcnt(0)+lgkmcnt(0)+barrier: next tile ready, buf reuse safe
  }
#pragma unroll
  for (int off = 8; off >= 1; off >>= 1)
#pragma unroll
    for (int s = 0; s < 2; ++s)
#pragma unroll
      for (int r = 0; r < 4; ++r) {
        dAcc[s][r] += __shfl_xor(dAcc[s][r], off);
        nAcc[s][r] += __shfl_xor(nAcc[s][r], off);
      }
  if (l15 == 0) {
#pragma unroll
    for (int s = 0; s < 2; ++s)
#pragma unroll
      for (int r = 0; r < 4; ++r) {
        size_t q = (size_t)qbase + w * 32 + s * 16 + quad * 4 + r;
        part[(q * 16 + sc) * 2 + 0] = dAcc[s][r];
        part[(q * 16 + sc) * 2 + 1] = nAcc[s][r];
      }
  }
}

__global__ void k_final_r16(const float* __restrict__ part, float* __restrict__ out1) {
  int q = blockIdx.x * 256 + threadIdx.x;
  const float* p = part + (size_t)q * 32;
  float d = 0.f, n = 0.f;
#pragma unroll
  for (int i = 0; i < 16; ++i) { d += p[2 * i]; n += p[2 * i + 1]; }
  out1[q] = n / d;
}

extern "C" void kernel_launch(void* const* d_in, const int* in_sizes, int n_in,
                              void* d_out, int out_size, void* d_ws, size_t ws_size,
                              hipStream_t stream) {
  (void)in_sizes; (void)n_in; (void)out_size; (void)ws_size;
  const float* SF = (const float*)d_in[0];   // fp32
  const int*   SL = (const int*)d_in[1];     // int32
  const float* SV = (const float*)d_in[2];   // fp32
  const float* QF = (const float*)d_in[3];   // fp32

  float* ws = (float*)d_ws;
  float* rnorm = ws + OFF_PSUM;              // 16384 row inv-norms (SF)
  float* musum = ws + OFF_MUSUM;
  float* ssum  = ws + OFF_SSUM;
  unsigned int* hist = (unsigned int*)(ws + OFF_HIST);
  float* protos= ws + OFF_PROTO;
  float* mu    = ws + OFF_MU;
  float* cov   = ws + OFF_COV;
  float* rows  = ws + OFF_ROWS;
  float* cptr  = ws + OFF_C;
  float* gptr  = ws + OFF_C + 1;
  float* X1 = ws + OFF_Y;  float* T = ws + OFF_T;  float* X2 = ws + OFF_Y2;
  float* s2 = ws + OFF_S2; float* q2p = ws + OFF_Q2P;
  float* part = ws + OFF_PART;
  float* G = ws + OFF_G;
  unsigned short* Sh = (unsigned short*)(ws + OFF_SH);
  unsigned short* Gh = (unsigned short*)(ws + OFF_GH);
  // proto-phase aliases (lifetimes end before overwriters run):
  float* pppart  = G;                        // proto partials (dead after proto_fin)
  float* cntpart = part;                     // counts (dead after proto_fin)
  float* qnorm   = ws + OFF_Y;               // 8192 Q inv-norms (dead before Newton)
  unsigned short* Ph = (unsigned short*)(ws + OFF_Y + 8192);  // proto frags (32 KB)
  unsigned short* Qh = Gh;                   // bf16 normalized Q (dead before swz(G))
  float* xtxpart = G;                        // xtx partials (dead after xtxcov)
  float* s2part  = X2;                       // s2 partials (X2 free post-Newton)

  float* out0 = (float*)d_out;                   // f32 log_probs [8192 x 64]
  float* out1 = out0 + (size_t)kNQ * kC;         // f32 predictions [8192]

  k_zero_r16<<<(int)((ZERO_FLOATS + 255) / 256), 256, 0, stream>>>(ws);

  // swizzled bf16 copy of support features
  k_swz_r16<<<kNS / 16, 256, 0, stream>>>(SF, Sh);

  // classification (atomic-free, MFMA logits)
  k_rnorm_r19<<<kNS / 4, 256, 0, stream>>>(SF, rnorm);
  k_paccum_r19<<<128, 256, 0, stream>>>(SF, SL, rnorm, pppart, cntpart);
  k_proto_fin_r19<<<kC, 256, 0, stream>>>(pppart, cntpart, protos);
  k_rnorm_r19<<<kNQ / 4, 256, 0, stream>>>(QF, qnorm);
  k_swzn_r22<<<kNQ / 16, 256, 0, stream>>>(QF, qnorm, Qh);
  k_swz_r16<<<kC / 16, 256, 0, stream>>>(protos, Ph);
  k_logits_mfma_r22<<<kNQ / 64, 256, 0, stream>>>(Qh, Ph, out0);

  // regression: mean, cov (K-split xtx, fused reduce+cov)
  k_colsum_r16<<<kNS / 64, 256, 0, stream>>>(SF, musum);
  k_mufin_r16<<<1, 256, 0, stream>>>(musum, mu);
  k_xtx_r22<<<dim3(16, 32), 256, 0, stream>>>(SF, xtxpart);
  k_xtxcov_r22<<<256, 256, 0, stream>>>(xtxpart, mu, cov);

  // Newton matrix inverse: X <- X (2I - cov X), X0 = I/c, 6 iterations
  k_rowabs_r16<<<256, 64, 0, stream>>>(cov, rows);
  k_cnorm_r16<<<1, 64, 0, stream>>>(rows, cptr);
  k_newt_init_r16<<<256, 256, 0, stream>>>(cptr, X1);
  float *Xc = X1, *T_ = T, *Xn = X2;
  for (int it = 0; it < 6; ++it) {
    k_newt_mm_r17<<<256, 1024, 0, stream>>>(cov, Xc, T_, 1);
    k_newt_mm_r17<<<256, 1024, 0, stream>>>(Xc, T_, Xn, 0);
    float* tmp = Xc; Xc = Xn; Xn = tmp;
  }
  float* M = Xc;   // cov^-1 (= X1 after even number of swaps)

  // G = (Q - mu) @ M, swizzled bf16 copy, scalar row terms
  k_G_r16<<<dim3(4, kNQ / 64), 256, 0, stream>>>(QF, mu, M, G);
  k_swz_r16<<<kNQ / 16, 256, 0, stream>>>(G, Gh);
  k_q2p_r16<<<kNQ / 4, 256, 0, stream>>>(G, QF, mu, q2p);
  k_s2_r22<<<dim3(kNS / 64, 4), 256, 0, stream>>>(SF, mu, M, s2part);
  k_s2fin_r22<<<kNS / 256, 256, 0, stream>>>(s2part, s2);

  // sampled median -> gamma (parallel)
  k_median_r16<<<dim3(32, 16), 256, 0, stream>>>(G, SF, q2p, s2, hist, ssum);
  k_gamma_r16<<<1, 256, 0, stream>>>(hist, ssum, gptr);

  // MFMA fused cdist^2 + softmax numer/denom, then finalize
  PrototypicalHead_6210522710389_kernel<<<dim3(64, 16), 256, 0, stream>>>(
      Gh, Sh, q2p, s2, SV, gptr, part);
  k_final_r16<<<kNQ / 256, 256, 0, stream>>>(part, out1);
}